// Round 6
// baseline (1808.411 us; speedup 1.0000x reference)
//
#include <hip/hip_runtime.h>
#include <math.h>

#define LDIM 384
#define NPIX (LDIM*LDIM)
#define NBINS 63

typedef __attribute__((ext_vector_type(8))) __bf16 bf16x8;
typedef __attribute__((ext_vector_type(4))) float floatx4;

__device__ __forceinline__ float sigf(float x){ return 1.f/(1.f+expf(-x)); }

// Prepped weight fragment layout (bf16): [tap][kc][nt][lane(64)][j(8)]
//   B-frag: n = nt*16 + (lane&15), k = kc*32 + (lane>>4)*8 + j
// WF arena offsets (bf16 units):
//   main conv slot s (0..11): s=2i conv1[i], s=2i+1 conv2[i], at s*36864
//   dist: 442368 ; cf1: 479232 ; cf2: 497664 ;
//   wg: 506880 (4096) ; wo: 510976 (2048) ; wq: 513024 (2048) ; total 515072
__global__ __launch_bounds__(256) void prep_kernel(
    const float* __restrict__ c1w, const float* __restrict__ c2w,
    const float* __restrict__ dw, const float* __restrict__ cf1w,
    const float* __restrict__ cf2w, const float* __restrict__ wg,
    const float* __restrict__ wo, const float* __restrict__ wq,
    __bf16* __restrict__ Wf){
  int idx = blockIdx.x*256 + threadIdx.x;
  if (idx >= 515072) return;
  if (idx >= 506880){
    int rel, NT, NDIM; const float* src;
    if (idx < 510976){ rel = idx - 506880; src = wg; NT=4; NDIM=64; }
    else if (idx < 513024){ rel = idx - 510976; src = wo; NT=4; NDIM=64; }
    else { rel = idx - 513024; src = wq; NT=2; NDIM=32; }
    int j = rel & 7, lane = (rel>>3) & 63;
    int r2 = rel >> 9;
    int nt = r2 % NT, kc = r2 / NT;
    int k = kc*32 + (lane>>4)*8 + j;
    int n = nt*16 + (lane&15);
    Wf[idx] = (__bf16)src[(size_t)k*NDIM + n];
    return;
  }
  const float* src; int ICreal, OCreal, ICP, NT, rel;
  if (idx < 442368){
    int layer = idx / 36864; rel = idx - layer*36864;
    int i = layer >> 1;
    src = (layer & 1) ? (c2w + (size_t)i*36864) : (c1w + (size_t)i*36864);
    ICreal=64; OCreal=64; ICP=64; NT=4;
  } else if (idx < 479232){
    rel = idx - 442368; src = dw;   ICreal=64; OCreal=63; ICP=64; NT=4;
  } else if (idx < 497664){
    rel = idx - 479232; src = cf1w; ICreal=63; OCreal=32; ICP=64; NT=2;
  } else {
    rel = idx - 497664; src = cf2w; ICreal=32; OCreal=32; ICP=32; NT=2;
  }
  int j = rel & 7, lane = (rel>>3) & 63;
  int r2 = rel >> 9;
  int nt = r2 % NT; int r3 = r2 / NT;
  int KC = ICP/32;
  int kc = r3 % KC; int tap = r3 / KC;
  int k = kc*32 + (lane>>4)*8 + j;
  int n = nt*16 + (lane&15);
  float v = 0.f;
  if (k < ICreal && n < OCreal) v = src[((size_t)n*ICreal + k)*9 + tap];
  Wf[idx] = (__bf16)v;
}

// ---------- MFMA implicit-GEMM 3x3 dilated conv, direct loads + reg dbuf ----------
// Barrier-free. Per-ky register buffers AH/AL[2][3][KC]; rows ky=0,1 loaded
// upfront, ky=2 loads overlap ky=0's MFMAs. sched_barrier(0) pins each load
// phase ahead of compute so the scheduler cannot re-sink loads to their uses
// (the round-5 failure: VGPR=48, one load at a time, ~500cy each).

#define ZERO_BUF(S) \
  _Pragma("unroll") \
  for (int kx_=0;kx_<3;kx_++){ \
    _Pragma("unroll") \
    for (int kc_=0;kc_<KC;kc_++){ AH[S][kx_][kc_]=zv; AL[S][kx_][kc_]=zv; } }

#define LOAD_ROW(KY, S) { \
  const int yr_ = y + ((KY)-1)*D; \
  if ((unsigned)yr_ < LDIM){ \
    const char* rowb_ = (const char*)Ain + (size_t)yr_*LDIM*REC_B + q*16; \
    _Pragma("unroll") \
    for (int kx_=0;kx_<3;kx_++){ \
      const int gx_ = gx0 + (kx_-1)*D; \
      if ((unsigned)gx_ < LDIM){ \
        const char* p_ = rowb_ + (size_t)gx_*REC_B; \
        _Pragma("unroll") \
        for (int kc_=0;kc_<KC;kc_++){ \
          AH[S][kx_][kc_] = *(const bf16x8*)(p_ + kc_*64); \
          AL[S][kx_][kc_] = *(const bf16x8*)(p_ + kc_*64 + ICP*2); \
        } } } } }

#define MFMA_ROW(KY, S) \
  _Pragma("unroll") \
  for (int kx_=0;kx_<3;kx_++){ \
    _Pragma("unroll") \
    for (int kc_=0;kc_<KC;kc_++){ \
      const __bf16* wkc_ = Wf + (size_t)(((KY)*3+kx_)*KC + kc_)*NT*512 + lane*8; \
      _Pragma("unroll") \
      for (int nt_=0; nt_<NT; nt_++){ \
        bf16x8 bfrag_ = *(const bf16x8*)(wkc_ + (size_t)nt_*512); \
        acc[nt_] = __builtin_amdgcn_mfma_f32_16x16x32_bf16(AH[S][kx_][kc_], bfrag_, acc[nt_], 0,0,0); \
        acc[nt_] = __builtin_amdgcn_mfma_f32_16x16x32_bf16(AL[S][kx_][kc_], bfrag_, acc[nt_], 0,0,0); \
      } } }

template<int ICP, int NT, int D, int WAVES>
__global__ __launch_bounds__(WAVES*64) void mfma_conv(
    const __bf16* __restrict__ Ain, const __bf16* __restrict__ Wf,
    const float* __restrict__ bias, int OC_real,
    float* __restrict__ outF, __bf16* __restrict__ outP,
    int relu, float* __restrict__ ostats){
  constexpr int KC = ICP/32;
  constexpr int OCS = NT*16;
  constexpr int REC_B = ICP*4;          // bytes per px record (hi+lo)
  __shared__ float red[OCS*WAVES*2];
  const int t = threadIdx.x;
  const int wave = t>>6, lane = t&63;
  const int q = lane>>4, col16 = lane&15;
  const int y = blockIdx.y;
  const int x0 = blockIdx.x*(WAVES*16);
  const int gx0 = x0 + wave*16 + col16;

  floatx4 acc[NT];
  #pragma unroll
  for (int b=0;b<NT;b++){ floatx4 z = {0.f,0.f,0.f,0.f}; acc[b]=z; }

  bf16x8 zv;
  #pragma unroll
  for (int j=0;j<8;j++) zv[j]=(__bf16)0.f;

  bf16x8 AH[2][3][KC], AL[2][3][KC];

  ZERO_BUF(0) LOAD_ROW(0, 0)
  ZERO_BUF(1) LOAD_ROW(1, 1)
  __builtin_amdgcn_sched_barrier(0);
  MFMA_ROW(0, 0)
  ZERO_BUF(0) LOAD_ROW(2, 0)
  __builtin_amdgcn_sched_barrier(0);
  MFMA_ROW(1, 1)
  MFMA_ROW(2, 0)

  #pragma unroll
  for (int nt=0; nt<NT; nt++){
    int oc = nt*16 + col16;
    float bv = (oc < OC_real) ? bias[oc] : 0.f;
    int pxb = x0 + wave*16 + q*4;
    float s=0.f, sq=0.f;
    #pragma unroll
    for (int r=0; r<4; r++){
      float vv = acc[nt][r] + bv;
      if (relu) vv = fmaxf(vv, 0.f);
      size_t pix = (size_t)y*LDIM + pxb + r;
      if (outF) outF[pix*OCS + oc] = vv;
      if (outP){
        __bf16 h = (__bf16)vv;
        __bf16* rec = outP + pix*(size_t)(OCS*2);
        rec[oc] = h; rec[OCS+oc] = (__bf16)(vv - (float)h);
      }
      s += vv; sq += vv*vv;
    }
    if (ostats){
      s  += __shfl_xor(s, 16);  s  += __shfl_xor(s, 32);
      sq += __shfl_xor(sq, 16); sq += __shfl_xor(sq, 32);
      if (q == 0){
        red[oc*WAVES + wave] = s;
        red[OCS*WAVES + oc*WAVES + wave] = sq;
      }
    }
  }
  if (ostats){
    __syncthreads();
    float* oslot = ostats + ((blockIdx.y & 7) << 7);
    if (t < OCS){
      float s=0.f, sq=0.f;
      #pragma unroll
      for (int w=0; w<WAVES; w++){
        s  += red[t*WAVES + w];
        sq += red[OCS*WAVES + t*WAVES + w];
      }
      atomicAdd(&oslot[t], s);
      atomicAdd(&oslot[64+t], sq);
    }
  }
}

// ---------------- input 1x1 conv: NHWC(41) -> hi/lo records(64) ----------------
__global__ __launch_bounds__(256) void in_proj_kernel(
    const float* __restrict__ feat, const float* __restrict__ w,
    const float* __restrict__ b, __bf16* __restrict__ PX){
  __shared__ float sf[16][41];
  __shared__ float sw[64*41];
  int t = threadIdx.x;
  size_t p0 = (size_t)blockIdx.x*16;
  float wv[11];
  #pragma unroll
  for (int k=0;k<11;k++){ int idx=t+k*256; wv[k] = (idx<2624) ? w[idx] : 0.f; }
  float fv[3];
  #pragma unroll
  for (int k=0;k<3;k++){ int idx=t+k*256; fv[k] = (idx<656) ? feat[p0*41 + idx] : 0.f; }
  #pragma unroll
  for (int k=0;k<11;k++){ int idx=t+k*256; if (idx<2624) sw[idx]=wv[k]; }
  #pragma unroll
  for (int k=0;k<3;k++){
    int idx=t+k*256;
    if (idx<656){ int p = idx/41, k2 = idx - p*41; sf[p][k2]=fv[k]; }
  }
  __syncthreads();
  #pragma unroll
  for (int k=0;k<4;k++){
    int item = t + k*256;
    int c = item&63, p = item>>6;
    float acc = b[c];
    #pragma unroll
    for (int kk=0;kk<41;kk++) acc += sf[p][kk]*sw[c*41+kk];
    __bf16 h = (__bf16)acc;
    __bf16* rec = PX + (p0+p)*128;
    rec[c] = h; rec[64+c] = (__bf16)(acc - (float)h);
  }
}

// norm(U records, 8-replica stats) -> ELU -> U in place (no residual)
__global__ __launch_bounds__(256) void norm_elu_planes(
    __bf16* __restrict__ U, const float* __restrict__ stats){
  size_t idx = (size_t)blockIdx.x*256 + threadIdx.x;
  size_t px = idx>>3; int c0 = (int)(idx&7)*8;
  __bf16* ur = U + px*128;
  uint4 uh = *(const uint4*)(ur + c0);
  uint4 ul = *(const uint4*)(ur + 64 + c0);
  __bf16* uhp=(__bf16*)&uh; __bf16* ulp=(__bf16*)&ul;
  float mu[8], rs[8];
  #pragma unroll
  for (int k=0;k<8;k++){
    int c = c0+k;
    float s=0.f, sq=0.f;
    #pragma unroll
    for (int rp=0;rp<8;rp++){ s += stats[rp*128 + c]; sq += stats[rp*128 + 64 + c]; }
    float m = s*(1.f/NPIX);
    mu[k]=m; rs[k]=rsqrtf(sq*(1.f/NPIX) - m*m + 1e-5f);
  }
  #pragma unroll
  for (int k=0;k<8;k++){
    float v = ((float)uhp[k] + (float)ulp[k] - mu[k])*rs[k];
    v = v>0.f ? v : expm1f(v);
    __bf16 h = (__bf16)v; uhp[k]=h; ulp[k]=(__bf16)(v-(float)h);
  }
  *(uint4*)(ur + c0) = uh;
  *(uint4*)(ur + 64 + c0) = ul;
}

// norm(conv2raw U, 8-replica stats) + residual(PX) -> ELU -> PX (records)
__global__ __launch_bounds__(256) void norm_res_elu_planes(
    const __bf16* __restrict__ U, __bf16* __restrict__ PX,
    const float* __restrict__ stats){
  size_t idx = (size_t)blockIdx.x*256 + threadIdx.x;
  size_t px = idx>>3; int c0 = (int)(idx&7)*8;
  const __bf16* ur = U + px*128;
  __bf16* xr = PX + px*128;
  uint4 uh = *(const uint4*)(ur + c0);
  uint4 ul = *(const uint4*)(ur + 64 + c0);
  uint4 xh = *(uint4*)(xr + c0);
  uint4 xl = *(uint4*)(xr + 64 + c0);
  __bf16* uhp=(__bf16*)&uh; __bf16* ulp=(__bf16*)&ul;
  __bf16* xhp=(__bf16*)&xh; __bf16* xlp=(__bf16*)&xl;
  float mu[8], rs[8];
  #pragma unroll
  for (int k=0;k<8;k++){
    int c = c0+k;
    float s=0.f, sq=0.f;
    #pragma unroll
    for (int rp=0;rp<8;rp++){ s += stats[rp*128 + c]; sq += stats[rp*128 + 64 + c]; }
    float m = s*(1.f/NPIX);
    mu[k]=m; rs[k]=rsqrtf(sq*(1.f/NPIX) - m*m + 1e-5f);
  }
  #pragma unroll
  for (int k=0;k<8;k++){
    float v = ((float)uhp[k] + (float)ulp[k] - mu[k])*rs[k]
            + ((float)xhp[k] + (float)xlp[k]);
    v = v>0.f ? v : expm1f(v);
    __bf16 h = (__bf16)v; xhp[k]=h; xlp[k]=(__bf16)(v-(float)h);
  }
  *(uint4*)(xr + c0) = xh;
  *(uint4*)(xr + 64 + c0) = xl;
}

// ---------------- attention ----------------
__global__ __launch_bounds__(256) void g_partial_kernel(
    const float* __restrict__ td, float* __restrict__ GC){
  size_t base = (size_t)blockIdx.x*256;
  float cnt = (td[base + threadIdx.x] > 0.f) ? 1.f : 0.f;
  __shared__ float red[256];
  red[threadIdx.x]=cnt; __syncthreads();
  for (int st=128; st; st>>=1){
    if (threadIdx.x<st) red[threadIdx.x]+=red[threadIdx.x+st];
    __syncthreads();
  }
  if (threadIdx.x==0) atomicAdd(GC, red[0]);
}

__global__ void g_final_kernel(
    const float* __restrict__ GC, const float* __restrict__ tq,
    const float* __restrict__ w1, const float* __restrict__ b1,
    const float* __restrict__ w2, const float* __restrict__ b2,
    float* __restrict__ G){
  if (threadIdx.x==0){
    float f0 = GC[0]*(1.f/NPIX), f1 = tq[0], f2 = (float)LDIM/512.f;
    float z = b2[0];
    for (int j=0;j<16;j++){
      float h = f0*w1[j] + f1*w1[16+j] + f2*w1[32+j] + b1[j];
      z += (h>0.f?h:0.f)*w2[j];
    }
    G[0] = sigf(z);
  }
}

// q = X @ wq via MFMA; writes Qb bf16 [i][j][32]
__global__ __launch_bounds__(256) void qproj_mfma_kernel(
    const __bf16* __restrict__ PX, const __bf16* __restrict__ WqF,
    __bf16* __restrict__ Qb){
  const int t=threadIdx.x, wave=t>>6, lane=t&63, q=lane>>4, col16=lane&15;
  const size_t p0=(size_t)blockIdx.x*128;
  __shared__ __bf16 Xhi[128*72];
  __shared__ __bf16 Xlo[128*72];
  uint4 sv[8];
  #pragma unroll
  for (int k=0;k<8;k++){
    int c=t+k*256;
    sv[k] = *(const uint4*)((const char*)PX + (p0 + (c>>4))*256 + (c&15)*16);
  }
  #pragma unroll
  for (int k=0;k<8;k++){
    int c=t+k*256; int px=c>>4, sub=c&15;
    *(uint4*)(((sub<8)?Xhi:Xlo) + px*72 + (sub&7)*8) = sv[k];
  }
  __syncthreads();
  floatx4 acc[2][2];
  #pragma unroll
  for (int a=0;a<2;a++)
    #pragma unroll
    for (int b=0;b<2;b++){ floatx4 z={0.f,0.f,0.f,0.f}; acc[a][b]=z; }
  #pragma unroll
  for (int kc=0;kc<2;kc++){
    bf16x8 ah[2], al[2];
    #pragma unroll
    for (int mt=0;mt<2;mt++){
      int row = wave*32 + mt*16 + col16;
      ah[mt] = *(const bf16x8*)(Xhi + row*72 + kc*32 + q*8);
      al[mt] = *(const bf16x8*)(Xlo + row*72 + kc*32 + q*8);
    }
    #pragma unroll
    for (int nt=0;nt<2;nt++){
      bf16x8 b = *(const bf16x8*)(WqF + (kc*2+nt)*512 + lane*8);
      acc[0][nt] = __builtin_amdgcn_mfma_f32_16x16x32_bf16(ah[0], b, acc[0][nt], 0,0,0);
      acc[1][nt] = __builtin_amdgcn_mfma_f32_16x16x32_bf16(ah[1], b, acc[1][nt], 0,0,0);
      acc[0][nt] = __builtin_amdgcn_mfma_f32_16x16x32_bf16(al[0], b, acc[0][nt], 0,0,0);
      acc[1][nt] = __builtin_amdgcn_mfma_f32_16x16x32_bf16(al[1], b, acc[1][nt], 0,0,0);
    }
  }
  #pragma unroll
  for (int mt=0;mt<2;mt++){
    size_t pxb = p0 + wave*32 + mt*16 + q*4;
    #pragma unroll
    for (int nt=0;nt<2;nt++){
      int oc = nt*16 + col16;
      #pragma unroll
      for (int r=0;r<4;r++)
        Qb[(pxb+r)*32 + oc] = (__bf16)acc[mt][nt][r];
    }
  }
}

// leftb bf16 [i][a][n]; vleftTb bf16 [i][n][a]
__global__ __launch_bounds__(256) void proj_left_kernel(
    const __bf16* __restrict__ PX, const float* __restrict__ wl, const float* __restrict__ wvl,
    __bf16* __restrict__ leftb, __bf16* __restrict__ vleftTb){
  int i = blockIdx.x;
  __shared__ float xa[32][65];
  __shared__ float w1s[2048], w2s[2048];
  int c = threadIdx.x & 63;
  for (int a = threadIdx.x>>6; a<32; a+=4){
    const __bf16* rec = PX + ((size_t)i*LDIM + 12*a)*128;
    xa[a][c] = (float)rec[c] + (float)rec[64+c];
  }
  for (int idx=threadIdx.x; idx<2048; idx+=256){ w1s[idx]=wl[idx]; w2s[idx]=wvl[idx]; }
  __syncthreads();
  #pragma unroll
  for (int k=0;k<4;k++){
    int idx = threadIdx.x + k*256;
    int a = idx>>5, n = idx&31;
    float a1=0.f, a2=0.f;
    #pragma unroll
    for (int cc=0;cc<64;cc++){ float v=xa[a][cc]; a1+=v*w1s[cc*32+n]; a2+=v*w2s[cc*32+n]; }
    leftb  [(size_t)i*1024 + a*32 + n] = (__bf16)a1;
    vleftTb[(size_t)i*1024 + n*32 + a] = (__bf16)a2;
  }
}

// grid (12, 32): j0 = bx*32, a = by ; rightb [j][a][n] ; vrightTb [j][n][a]
__global__ __launch_bounds__(256) void proj_right_kernel(
    const __bf16* __restrict__ PX, const float* __restrict__ wr, const float* __restrict__ wvr,
    __bf16* __restrict__ rightb, __bf16* __restrict__ vrightTb){
  int a = blockIdx.y; int row = 12*a;
  int j0 = blockIdx.x*32;
  __shared__ float xr[32][65];
  __shared__ float w1s[2048], w2s[2048];
  for (int idx=threadIdx.x; idx<2048; idx+=256){ w1s[idx]=wr[idx]; w2s[idx]=wvr[idx]; }
  int c = threadIdx.x & 63;
  for (int jl = threadIdx.x>>6; jl<32; jl+=4){
    const __bf16* rec = PX + ((size_t)row*LDIM + j0 + jl)*128;
    xr[jl][c] = (float)rec[c] + (float)rec[64+c];
  }
  __syncthreads();
  #pragma unroll
  for (int k=0;k<4;k++){
    int idx=threadIdx.x+k*256; int jl=idx>>5, n=idx&31;
    float a1=0.f, a2=0.f;
    #pragma unroll
    for (int cc=0;cc<64;cc++){ float v=xr[jl][cc]; a1+=v*w1s[cc*32+n]; a2+=v*w2s[cc*32+n]; }
    rightb  [(size_t)(j0+jl)*1024 + a*32 + n] = (__bf16)a1;
    vrightTb[(size_t)(j0+jl)*1024 + n*32 + a] = (__bf16)a2;
  }
}

// S1: per-i GEMM  S[i,j,a] = Q[i,j,:] . left[i,a,:]
__global__ __launch_bounds__(256) void attn_s1_kernel(
    const __bf16* __restrict__ Qb, const __bf16* __restrict__ leftb,
    float* __restrict__ S){
  const int t=threadIdx.x, wave=t>>6, lane=t&63, q=lane>>4, col16=lane&15;
  const int i = blockIdx.y, j0 = blockIdx.x*128;
  bf16x8 bfrag[2];
  #pragma unroll
  for (int nt=0;nt<2;nt++)
    bfrag[nt] = *(const bf16x8*)(leftb + (size_t)i*1024 + (nt*16+col16)*32 + q*8);
  bf16x8 ah[2];
  #pragma unroll
  for (int mt=0;mt<2;mt++){
    int row = j0 + wave*32 + mt*16 + col16;
    ah[mt] = *(const bf16x8*)(Qb + ((size_t)i*LDIM + row)*32 + q*8);
  }
  floatx4 acc[2][2];
  #pragma unroll
  for (int a=0;a<2;a++)
    #pragma unroll
    for (int b=0;b<2;b++){ floatx4 z={0.f,0.f,0.f,0.f}; acc[a][b]=z; }
  #pragma unroll
  for (int mt=0;mt<2;mt++)
    #pragma unroll
    for (int nt=0;nt<2;nt++)
      acc[mt][nt] = __builtin_amdgcn_mfma_f32_16x16x32_bf16(ah[mt], bfrag[nt], acc[mt][nt], 0,0,0);
  #pragma unroll
  for (int mt=0;mt<2;mt++){
    int jb = j0 + wave*32 + mt*16 + q*4;
    #pragma unroll
    for (int nt=0;nt<2;nt++){
      int a = nt*16 + col16;
      #pragma unroll
      for (int r=0;r<4;r++)
        S[((size_t)i*LDIM + jb + r)*32 + a] = acc[mt][nt][r];
    }
  }
}

// S2: per-j GEMM  S[i,j,a] += Q[i,j,:] . right[j,a,:]
__global__ __launch_bounds__(256) void attn_s2_kernel(
    const __bf16* __restrict__ Qb, const __bf16* __restrict__ rightb,
    float* __restrict__ S){
  const int t=threadIdx.x, wave=t>>6, lane=t&63, q=lane>>4, col16=lane&15;
  const int j = blockIdx.y, i0 = blockIdx.x*128;
  bf16x8 bfrag[2];
  #pragma unroll
  for (int nt=0;nt<2;nt++)
    bfrag[nt] = *(const bf16x8*)(rightb + (size_t)j*1024 + (nt*16+col16)*32 + q*8);
  bf16x8 ah[2];
  #pragma unroll
  for (int mt=0;mt<2;mt++){
    int row = i0 + wave*32 + mt*16 + col16;
    ah[mt] = *(const bf16x8*)(Qb + ((size_t)row*LDIM + j)*32 + q*8);
  }
  floatx4 acc[2][2];
  #pragma unroll
  for (int a=0;a<2;a++)
    #pragma unroll
    for (int b=0;b<2;b++){ floatx4 z={0.f,0.f,0.f,0.f}; acc[a][b]=z; }
  #pragma unroll
  for (int mt=0;mt<2;mt++)
    #pragma unroll
    for (int nt=0;nt<2;nt++)
      acc[mt][nt] = __builtin_amdgcn_mfma_f32_16x16x32_bf16(ah[mt], bfrag[nt], acc[mt][nt], 0,0,0);
  #pragma unroll
  for (int mt=0;mt<2;mt++){
    int ib = i0 + wave*32 + mt*16 + q*4;
    #pragma unroll
    for (int nt=0;nt<2;nt++){
      int a = nt*16 + col16;
      #pragma unroll
      for (int r=0;r<4;r++){
        size_t idx = ((size_t)(ib+r)*LDIM + j)*32 + a;
        S[idx] += acc[mt][nt][r];
      }
    }
  }
}

// softmax(S*scale + g*bias) -> attnb/attnTb
__global__ __launch_bounds__(128) void attn_soft_kernel(
    const float* __restrict__ S, const float* __restrict__ td,
    const float* __restrict__ gp, __bf16* __restrict__ attnb,
    __bf16* __restrict__ attnTb){
  int i = blockIdx.y;
  int j0 = blockIdx.x*128;
  int t = threadIdx.x;
  int j = j0 + t;
  __shared__ float tl[32];
  __shared__ float trS[32*128];
  {
    #pragma unroll
    for (int v=0; v<8; v++){
      int f = t + v*128;
      int a = f>>5, jl4 = (f&31)*4;
      *(floatx4*)(trS + a*128 + jl4) = *(const floatx4*)(td + (size_t)(12*a)*LDIM + j0 + jl4);
    }
    if (t<32) tl[t] = td[(size_t)i*LDIM + 12*t];
  }
  __syncthreads();
  float g = gp[0];
  float tdij = td[(size_t)i*LDIM+j];
  float s[32];
  const floatx4* sp4 = (const floatx4*)(S + ((size_t)i*LDIM+j)*32);
  #pragma unroll
  for (int v=0;v<8;v++){
    floatx4 sv = sp4[v];
    #pragma unroll
    for (int e=0;e<4;e++) s[v*4+e] = sv[e];
  }
  float m = -1e30f;
  #pragma unroll
  for (int a=0;a<32;a++){
    float acc = s[a]*0.17677669529663687f;
    float bias = -fabsf(tl[a] + trS[a*128 + t] - tdij) * (1.0f/12.0f);
    acc += g*bias;
    s[a]=acc;
    m = fmaxf(m, acc);
  }
  float sum=0.f;
  #pragma unroll
  for (int a=0;a<32;a++){ s[a]=expf(s[a]-m); sum+=s[a]; }
  float inv = 1.f/sum;
  bf16x8 pk[4];
  #pragma unroll
  for (int v=0;v<4;v++){
    #pragma unroll
    for (int e=0;e<8;e++) pk[v][e] = (__bf16)(s[v*8+e]*inv);
  }
  bf16x8* op = (bf16x8*)(attnb + ((size_t)i*LDIM+j)*32);
  bf16x8* opT = (bf16x8*)(attnTb + ((size_t)j*LDIM+i)*32);
  #pragma unroll
  for (int v=0;v<4;v++){ op[v]=pk[v]; opT[v]=pk[v]; }
}

// U1: per-i GEMM  UPD[i,j,c] = attn[i,j,:] . vleftT[i,c,:]
__global__ __launch_bounds__(256) void attn_u1_kernel(
    const __bf16* __restrict__ attnb, const __bf16* __restrict__ vleftTb,
    float* __restrict__ UPD){
  const int t=threadIdx.x, wave=t>>6, lane=t&63, q=lane>>4, col16=lane&15;
  const int i = blockIdx.y, j0 = blockIdx.x*128;
  bf16x8 bfrag[2];
  #pragma unroll
  for (int nt=0;nt<2;nt++)
    bfrag[nt] = *(const bf16x8*)(vleftTb + (size_t)i*1024 + (nt*16+col16)*32 + q*8);
  bf16x8 ah[2];
  #pragma unroll
  for (int mt=0;mt<2;mt++){
    int row = j0 + wave*32 + mt*16 + col16;
    ah[mt] = *(const bf16x8*)(attnb + ((size_t)i*LDIM + row)*32 + q*8);
  }
  floatx4 acc[2][2];
  #pragma unroll
  for (int a=0;a<2;a++)
    #pragma unroll
    for (int b=0;b<2;b++){ floatx4 z={0.f,0.f,0.f,0.f}; acc[a][b]=z; }
  #pragma unroll
  for (int mt=0;mt<2;mt++)
    #pragma unroll
    for (int nt=0;nt<2;nt++)
      acc[mt][nt] = __builtin_amdgcn_mfma_f32_16x16x32_bf16(ah[mt], bfrag[nt], acc[mt][nt], 0,0,0);
  #pragma unroll
  for (int mt=0;mt<2;mt++){
    int jb = j0 + wave*32 + mt*16 + q*4;
    #pragma unroll
    for (int nt=0;nt<2;nt++){
      int c = nt*16 + col16;
      #pragma unroll
      for (int r=0;r<4;r++)
        UPD[((size_t)i*LDIM + jb + r)*32 + c] = acc[mt][nt][r];
    }
  }
}

// U2: per-j GEMM  UPD[i,j,c] += attnT[j,i,:] . vrightT[j,c,:]
__global__ __launch_bounds__(256) void attn_u2_kernel(
    const __bf16* __restrict__ attnTb, const __bf16* __restrict__ vrightTb,
    float* __restrict__ UPD){
  const int t=threadIdx.x, wave=t>>6, lane=t&63, q=lane>>4, col16=lane&15;
  const int j = blockIdx.y, i0 = blockIdx.x*128;
  bf16x8 bfrag[2];
  #pragma unroll
  for (int nt=0;nt<2;nt++)
    bfrag[nt] = *(const bf16x8*)(vrightTb + (size_t)j*1024 + (nt*16+col16)*32 + q*8);
  bf16x8 ah[2];
  #pragma unroll
  for (int mt=0;mt<2;mt++){
    int row = i0 + wave*32 + mt*16 + col16;
    ah[mt] = *(const bf16x8*)(attnTb + ((size_t)j*LDIM + row)*32 + q*8);
  }
  floatx4 acc[2][2];
  #pragma unroll
  for (int a=0;a<2;a++)
    #pragma unroll
    for (int b=0;b<2;b++){ floatx4 z={0.f,0.f,0.f,0.f}; acc[a][b]=z; }
  #pragma unroll
  for (int mt=0;mt<2;mt++)
    #pragma unroll
    for (int nt=0;nt<2;nt++)
      acc[mt][nt] = __builtin_amdgcn_mfma_f32_16x16x32_bf16(ah[mt], bfrag[nt], acc[mt][nt], 0,0,0);
  #pragma unroll
  for (int mt=0;mt<2;mt++){
    int ib = i0 + wave*32 + mt*16 + q*4;
    #pragma unroll
    for (int nt=0;nt<2;nt++){
      int c = nt*16 + col16;
      #pragma unroll
      for (int r=0;r<4;r++){
        size_t idx = ((size_t)(ib+r)*LDIM + j)*32 + c;
        UPD[idx] += acc[mt][nt][r];
      }
    }
  }
}

// PX += sigmoid(X@Wg+bg) * (UPD@Wo), in-place on records, via MFMA
__global__ __launch_bounds__(256) void gate_mfma_kernel(
    __bf16* __restrict__ PX, const float* __restrict__ UPD,
    const __bf16* __restrict__ WgF, const __bf16* __restrict__ WoF,
    const float* __restrict__ bg){
  const int t=threadIdx.x, wave=t>>6, lane=t&63, q=lane>>4, col16=lane&15;
  const size_t p0=(size_t)blockIdx.x*128;
  __shared__ __bf16 Xhi[128*72];
  __shared__ __bf16 Xlo[128*72];
  __shared__ __bf16 Ub[128*40];
  uint4 sv[8];
  #pragma unroll
  for (int k=0;k<8;k++){
    int c=t+k*256;
    sv[k] = *(const uint4*)((const char*)PX + (p0 + (c>>4))*256 + (c&15)*16);
  }
  floatx4 uv[4];
  #pragma unroll
  for (int k=0;k<4;k++){
    int p = (t>>3) + k*32;
    uv[k] = *(const floatx4*)(UPD + (p0+p)*32 + (t&7)*4);
  }
  #pragma unroll
  for (int k=0;k<8;k++){
    int c=t+k*256; int px=c>>4, sub=c&15;
    *(uint4*)(((sub<8)?Xhi:Xlo) + px*72 + (sub&7)*8) = sv[k];
  }
  #pragma unroll
  for (int k=0;k<4;k++){
    int p = (t>>3) + k*32;
    __bf16* pu = Ub + p*40 + (t&7)*4;
    #pragma unroll
    for (int kk=0;kk<4;kk++) pu[kk]=(__bf16)uv[k][kk];
  }
  __syncthreads();
  floatx4 accg[2][4], accu[2][4];
  #pragma unroll
  for (int a=0;a<2;a++)
    #pragma unroll
    for (int b=0;b<4;b++){ floatx4 z={0.f,0.f,0.f,0.f}; accg[a][b]=z; accu[a][b]=z; }
  #pragma unroll
  for (int kc=0;kc<2;kc++){
    bf16x8 ah[2], al[2];
    #pragma unroll
    for (int mt=0;mt<2;mt++){
      int row = wave*32 + mt*16 + col16;
      ah[mt] = *(const bf16x8*)(Xhi + row*72 + kc*32 + q*8);
      al[mt] = *(const bf16x8*)(Xlo + row*72 + kc*32 + q*8);
    }
    #pragma unroll
    for (int nt=0;nt<4;nt++){
      bf16x8 b = *(const bf16x8*)(WgF + (kc*4+nt)*512 + lane*8);
      accg[0][nt] = __builtin_amdgcn_mfma_f32_16x16x32_bf16(ah[0], b, accg[0][nt], 0,0,0);
      accg[1][nt] = __builtin_amdgcn_mfma_f32_16x16x32_bf16(ah[1], b, accg[1][nt], 0,0,0);
      accg[0][nt] = __builtin_amdgcn_mfma_f32_16x16x32_bf16(al[0], b, accg[0][nt], 0,0,0);
      accg[1][nt] = __builtin_amdgcn_mfma_f32_16x16x32_bf16(al[1], b, accg[1][nt], 0,0,0);
    }
  }
  {
    bf16x8 au[2];
    #pragma unroll
    for (int mt=0;mt<2;mt++){
      int row = wave*32 + mt*16 + col16;
      au[mt] = *(const bf16x8*)(Ub + row*40 + q*8);
    }
    #pragma unroll
    for (int nt=0;nt<4;nt++){
      bf16x8 b = *(const bf16x8*)(WoF + nt*512 + lane*8);
      accu[0][nt] = __builtin_amdgcn_mfma_f32_16x16x32_bf16(au[0], b, accu[0][nt], 0,0,0);
      accu[1][nt] = __builtin_amdgcn_mfma_f32_16x16x32_bf16(au[1], b, accu[1][nt], 0,0,0);
    }
  }
  #pragma unroll
  for (int mt=0;mt<2;mt++){
    size_t pxb = p0 + wave*32 + mt*16 + q*4;
    #pragma unroll
    for (int nt=0;nt<4;nt++){
      int oc = nt*16 + col16;
      float bgv = bg[oc];
      #pragma unroll
      for (int r=0;r<4;r++){
        __bf16* rec = PX + (pxb+r)*128;
        float xv = (float)rec[oc] + (float)rec[64+oc];
        float g = sigf(accg[mt][nt][r] + bgv);
        float xn = xv + g*accu[mt][nt][r];
        __bf16 h = (__bf16)xn;
        rec[oc] = h; rec[64+oc] = (__bf16)(xn - (float)h);
      }
    }
  }
}

// ---------------- heads ----------------
__global__ __launch_bounds__(256) void sym_kernel(
    const float* __restrict__ lg, __bf16* __restrict__ PS, float* __restrict__ dout){
  int i = blockIdx.y;
  int j = blockIdx.x*4 + (threadIdx.x>>6);
  int o = threadIdx.x & 63;
  float v = 0.5f*(lg[((size_t)i*LDIM+j)*64+o] + lg[((size_t)j*LDIM+i)*64+o]);
  size_t pix = (size_t)i*LDIM+j;
  __bf16 h = (__bf16)v;
  __bf16* rec = PS + pix*128;
  rec[o] = h; rec[64+o] = (__bf16)(v - (float)h);
  if (o<63) dout[pix*63+o] = v;
}

__global__ __launch_bounds__(256) void conf_kernel(
    const float* __restrict__ c2, const float* __restrict__ w,
    const float* __restrict__ b, float* __restrict__ out){
  int t = threadIdx.x;
  size_t pix = (size_t)blockIdx.x*8 + (t>>5);
  int c = t&31;
  float v = c2[pix*32 + c]*w[c];
  #pragma unroll
  for (int off=16; off; off>>=1) v += __shfl_xor(v, off);
  if (c==0) out[pix] = sigf(v + b[0]);
}

extern "C" void kernel_launch(void* const* d_in, const int* in_sizes, int n_in,
                              void* d_out, int out_size, void* d_ws, size_t ws_size,
                              hipStream_t stream){
  const float* feat = (const float*)d_in[0];
  const float* td   = (const float*)d_in[1];
  const float* tq   = (const float*)d_in[2];
  const float* in_w = (const float*)d_in[3];
  const float* in_b = (const float*)d_in[4];
  const float* c1w  = (const float*)d_in[5];
  const float* c1b  = (const float*)d_in[6];
  const float* c2w  = (const float*)d_in[7];
  const float* c2b  = (const float*)d_in[8];
  const float* wq   = (const float*)d_in[9];
  const float* wl   = (const float*)d_in[10];
  const float* wr   = (const float*)d_in[11];
  const float* wvl  = (const float*)d_in[12];
  const float* wvr  = (const float*)d_in[13];
  const float* wo   = (const float*)d_in[14];
  const float* wg   = (const float*)d_in[15];
  const float* bg   = (const float*)d_in[16];
  const float* tgw1 = (const float*)d_in[17];
  const float* tgb1 = (const float*)d_in[18];
  const float* tgw2 = (const float*)d_in[19];
  const float* tgb2 = (const float*)d_in[20];
  const float* dw   = (const float*)d_in[21];
  const float* db   = (const float*)d_in[22];
  const float* cf1w = (const float*)d_in[23];
  const float* cf1b = (const float*)d_in[24];
  const float* cf2w = (const float*)d_in[25];
  const float* cf2b = (const float*)d_in[26];
  const float* cf3w = (const float*)d_in[27];
  const float* cf3b = (const float*)d_in[28];

  float* ws = (float*)d_ws;
  const size_t BUF = (size_t)64*NPIX;
  float* R1 = ws;
  float* R2 = ws + BUF;
  float* R3 = ws + 2*BUF;
  float* STATS = ws + 3*BUF;             // 12 slots x 8 replicas x 128
  float* G     = STATS + 12288;
  float* GC    = G + 1;
  __bf16* WF   = (__bf16*)(G + 16);
  __bf16* WGF  = WF + 506880;
  __bf16* WOF  = WF + 510976;
  __bf16* WQF  = WF + 513024;

  __bf16* PX = (__bf16*)R1;
  __bf16* PT = (__bf16*)R2;
  __bf16* PU = (__bf16*)R3;
  // attention buffers (R2/R3 free during attention)
  char* R2c = (char*)R2;
  __bf16* Qb       = (__bf16*)R2c;                  // 9,437,184 B
  __bf16* ATTNB    = (__bf16*)(R2c +  9437184);     // 9,437,184 B
  __bf16* ATTNTB   = (__bf16*)(R2c + 18874368);     // 9,437,184 B
  __bf16* LEFTB    = (__bf16*)(R2c + 28311552);     //   786,432 B
  __bf16* RIGHTB   = (__bf16*)(R2c + 29097984);
  __bf16* VLEFTTB  = (__bf16*)(R2c + 29884416);
  __bf16* VRIGHTTB = (__bf16*)(R2c + 30670848);
  float* S   = R3;                                  // 18.9 MB
  float* UPD = R3 + (size_t)32*NPIX;                // 18.9 MB

  hipMemsetAsync(STATS, 0, (12288 + 16)*sizeof(float), stream);
  prep_kernel<<<2012, 256, 0, stream>>>(c1w, c2w, dw, cf1w, cf2w, wg, wo, wq, WF);
  g_partial_kernel<<<576, 256, 0, stream>>>(td, GC);
  g_final_kernel<<<1, 64, 0, stream>>>(GC, tq, tgw1, tgb1, tgw2, tgb2, G);

  in_proj_kernel<<<9216, 256, 0, stream>>>(feat, in_w, in_b, PX);

#define CONV2_NORM(i) \
  norm_elu_planes<<<4608, 256, 0, stream>>>(PT, STATS + (2*(i))*1024); \
  mfma_conv<64,4,1,4><<<dim3(6,LDIM), 256, 0, stream>>>( \
      PT, WF + (size_t)(2*(i)+1)*36864, c2b + (i)*64, 64, \
      nullptr, PU, 0, STATS + (2*(i)+1)*1024); \
  norm_res_elu_planes<<<4608, 256, 0, stream>>>(PU, PX, STATS + (2*(i)+1)*1024);

#define CONV1(i, DD) \
  mfma_conv<64,4,DD,4><<<dim3(6,LDIM), 256, 0, stream>>>( \
      PX, WF + (size_t)(2*(i))*36864, c1b + (i)*64, 64, \
      nullptr, PT, 0, STATS + (2*(i))*1024);

#define ATTN_BLOCK \
  qproj_mfma_kernel<<<1152, 256, 0, stream>>>(PX, WQF, Qb); \
  proj_left_kernel<<<384, 256, 0, stream>>>(PX, wl, wvl, LEFTB, VLEFTTB); \
  proj_right_kernel<<<dim3(12,32), 256, 0, stream>>>(PX, wr, wvr, RIGHTB, VRIGHTTB); \
  attn_s1_kernel<<<dim3(3,LDIM), 256, 0, stream>>>(Qb, LEFTB, S); \
  attn_s2_kernel<<<dim3(3,LDIM), 256, 0, stream>>>(Qb, RIGHTB, S); \
  attn_soft_kernel<<<dim3(3,LDIM), 128, 0, stream>>>(S, td, G, ATTNB, ATTNTB); \
  attn_u1_kernel<<<dim3(3,LDIM), 256, 0, stream>>>(ATTNB, VLEFTTB, UPD); \
  attn_u2_kernel<<<dim3(3,LDIM), 256, 0, stream>>>(ATTNTB, VRIGHTTB, UPD); \
  gate_mfma_kernel<<<1152, 256, 0, stream>>>(PX, UPD, WGF, WOF, bg);

  CONV1(0, 1)   CONV2_NORM(0)
  CONV1(1, 2)   CONV2_NORM(1)  ATTN_BLOCK
  CONV1(2, 4)   CONV2_NORM(2)
  CONV1(3, 8)   CONV2_NORM(3)  ATTN_BLOCK
  CONV1(4, 16)  CONV2_NORM(4)
  CONV1(5, 1)   CONV2_NORM(5)  ATTN_BLOCK

  // distance head: PX -> fp32 logits in R3
  mfma_conv<64,4,1,4><<<dim3(6,LDIM), 256, 0, stream>>>(
      PX, WF + 442368, db, 63, R3, nullptr, 0, nullptr);
  sym_kernel<<<dim3(96,LDIM), 256, 0, stream>>>(R3, PT, (float*)d_out);
  // confidence head: PT(64rec) -> PX(32rec, relu) -> R3
  mfma_conv<64,2,1,4><<<dim3(6,LDIM), 256, 0, stream>>>(
      PT, WF + 479232, cf1b, 32, nullptr, PX, 1, nullptr);
  mfma_conv<32,2,1,4><<<dim3(6,LDIM), 256, 0, stream>>>(
      PX, WF + 497664, cf2b, 32, R3, nullptr, 1, nullptr);
  conf_kernel<<<18432, 256, 0, stream>>>(R3, cf3w, cf3b, (float*)d_out + (size_t)NPIX*NBINS);
}

// Round 7
// 1694.020 us; speedup vs baseline: 1.0675x; 1.0675x over previous
//
#include <hip/hip_runtime.h>
#include <math.h>

#define LDIM 384
#define NPIX (LDIM*LDIM)
#define NBINS 63

typedef __attribute__((ext_vector_type(8))) __bf16 bf16x8;
typedef __attribute__((ext_vector_type(4))) float floatx4;

__device__ __forceinline__ float sigf(float x){ return 1.f/(1.f+expf(-x)); }

// Prepped weight fragment layout (bf16): [tap][kc][nt][lane(64)][j(8)]
//   B-frag: n = nt*16 + (lane&15), k = kc*32 + (lane>>4)*8 + j
// WF arena offsets (bf16 units):
//   main conv slot s (0..11): s=2i conv1[i], s=2i+1 conv2[i], at s*36864
//   dist: 442368 ; cf1: 479232 ; cf2: 497664 ;
//   wg: 506880 (4096) ; wo: 510976 (2048) ; wq: 513024 (2048) ; total 515072
__global__ __launch_bounds__(256) void prep_kernel(
    const float* __restrict__ c1w, const float* __restrict__ c2w,
    const float* __restrict__ dw, const float* __restrict__ cf1w,
    const float* __restrict__ cf2w, const float* __restrict__ wg,
    const float* __restrict__ wo, const float* __restrict__ wq,
    __bf16* __restrict__ Wf){
  int idx = blockIdx.x*256 + threadIdx.x;
  if (idx >= 515072) return;
  if (idx >= 506880){
    int rel, NT, NDIM; const float* src;
    if (idx < 510976){ rel = idx - 506880; src = wg; NT=4; NDIM=64; }
    else if (idx < 513024){ rel = idx - 510976; src = wo; NT=4; NDIM=64; }
    else { rel = idx - 513024; src = wq; NT=2; NDIM=32; }
    int j = rel & 7, lane = (rel>>3) & 63;
    int r2 = rel >> 9;
    int nt = r2 % NT, kc = r2 / NT;
    int k = kc*32 + (lane>>4)*8 + j;
    int n = nt*16 + (lane&15);
    Wf[idx] = (__bf16)src[(size_t)k*NDIM + n];
    return;
  }
  const float* src; int ICreal, OCreal, ICP, NT, rel;
  if (idx < 442368){
    int layer = idx / 36864; rel = idx - layer*36864;
    int i = layer >> 1;
    src = (layer & 1) ? (c2w + (size_t)i*36864) : (c1w + (size_t)i*36864);
    ICreal=64; OCreal=64; ICP=64; NT=4;
  } else if (idx < 479232){
    rel = idx - 442368; src = dw;   ICreal=64; OCreal=63; ICP=64; NT=4;
  } else if (idx < 497664){
    rel = idx - 479232; src = cf1w; ICreal=63; OCreal=32; ICP=64; NT=2;
  } else {
    rel = idx - 497664; src = cf2w; ICreal=32; OCreal=32; ICP=32; NT=2;
  }
  int j = rel & 7, lane = (rel>>3) & 63;
  int r2 = rel >> 9;
  int nt = r2 % NT; int r3 = r2 / NT;
  int KC = ICP/32;
  int kc = r3 % KC; int tap = r3 / KC;
  int k = kc*32 + (lane>>4)*8 + j;
  int n = nt*16 + (lane&15);
  float v = 0.f;
  if (k < ICreal && n < OCreal) v = src[((size_t)n*ICreal + k)*9 + tap];
  Wf[idx] = (__bf16)v;
}

// ---------- MFMA implicit-GEMM 3x3 dilated conv, direct loads, R rows/wave ----------
// Barrier-free (round-5 structure). Each wave computes R output rows for its
// 16-px column strip; per tap (ky,kx) the weight fragments are loaded ONCE
// and reused across all R rows -> per-row load count drops from 108 to ~72
// (D>1) / ~60 (D=1, L1 dedups overlapping A-rows). Loads stay 16B direct
// from the pixel records (layout matches the MFMA A-fragment exactly).
template<int ICP, int NT, int D, int WAVES, int R>
__global__ __launch_bounds__(WAVES*64) void mfma_conv(
    const __bf16* __restrict__ Ain, const __bf16* __restrict__ Wf,
    const float* __restrict__ bias, int OC_real,
    float* __restrict__ outF, __bf16* __restrict__ outP,
    int relu, float* __restrict__ ostats){
  constexpr int KC = ICP/32;
  constexpr int OCS = NT*16;
  constexpr int REC_B = ICP*4;          // bytes per px record (hi+lo)
  __shared__ float red[OCS*WAVES*2];
  const int t = threadIdx.x;
  const int wave = t>>6, lane = t&63;
  const int q = lane>>4, col16 = lane&15;
  const int y0 = blockIdx.y*R;
  const int x0 = blockIdx.x*(WAVES*16);
  const int gx0 = x0 + wave*16 + col16;

  floatx4 acc[R][NT];
  #pragma unroll
  for (int r=0;r<R;r++)
    #pragma unroll
    for (int b=0;b<NT;b++){ floatx4 z = {0.f,0.f,0.f,0.f}; acc[r][b]=z; }

  bf16x8 zv;
  #pragma unroll
  for (int j=0;j<8;j++) zv[j]=(__bf16)0.f;

  #pragma unroll
  for (int ky=0; ky<3; ky++){
    #pragma unroll
    for (int kx=0; kx<3; kx++){
      const int gx = gx0 + (kx-1)*D;
      const bool xok = ((unsigned)gx < LDIM);
      // weight fragments for this tap: loaded once, reused by all R rows
      bf16x8 wf[KC][NT];
      #pragma unroll
      for (int kc=0;kc<KC;kc++){
        const __bf16* wkc = Wf + (size_t)((ky*3+kx)*KC + kc)*NT*512 + lane*8;
        #pragma unroll
        for (int nt=0;nt<NT;nt++)
          wf[kc][nt] = *(const bf16x8*)(wkc + (size_t)nt*512);
      }
      #pragma unroll
      for (int r=0;r<R;r++){
        const int yr = y0 + r + (ky-1)*D;
        bf16x8 ah[KC], al[KC];
        #pragma unroll
        for (int kc=0;kc<KC;kc++){ ah[kc]=zv; al[kc]=zv; }
        if (xok && (unsigned)yr < LDIM){
          const char* p = (const char*)Ain + ((size_t)yr*LDIM + gx)*REC_B + q*16;
          #pragma unroll
          for (int kc=0;kc<KC;kc++){
            ah[kc] = *(const bf16x8*)(p + kc*64);
            al[kc] = *(const bf16x8*)(p + kc*64 + ICP*2);
          }
        }
        #pragma unroll
        for (int kc=0;kc<KC;kc++){
          #pragma unroll
          for (int nt=0; nt<NT; nt++){
            acc[r][nt] = __builtin_amdgcn_mfma_f32_16x16x32_bf16(ah[kc], wf[kc][nt], acc[r][nt], 0,0,0);
            acc[r][nt] = __builtin_amdgcn_mfma_f32_16x16x32_bf16(al[kc], wf[kc][nt], acc[r][nt], 0,0,0);
          }
        }
      }
    }
  }

  float sAcc[NT], sqAcc[NT];
  #pragma unroll
  for (int nt=0;nt<NT;nt++){ sAcc[nt]=0.f; sqAcc[nt]=0.f; }
  #pragma unroll
  for (int r=0;r<R;r++){
    const int y = y0 + r;
    #pragma unroll
    for (int nt=0; nt<NT; nt++){
      int oc = nt*16 + col16;
      float bv = (oc < OC_real) ? bias[oc] : 0.f;
      int pxb = x0 + wave*16 + q*4;
      #pragma unroll
      for (int rr=0; rr<4; rr++){
        float vv = acc[r][nt][rr] + bv;
        if (relu) vv = fmaxf(vv, 0.f);
        size_t pix = (size_t)y*LDIM + pxb + rr;
        if (outF) outF[pix*OCS + oc] = vv;
        if (outP){
          __bf16 h = (__bf16)vv;
          __bf16* rec = outP + pix*(size_t)(OCS*2);
          rec[oc] = h; rec[OCS+oc] = (__bf16)(vv - (float)h);
        }
        sAcc[nt] += vv; sqAcc[nt] += vv*vv;
      }
    }
  }
  if (ostats){
    #pragma unroll
    for (int nt=0; nt<NT; nt++){
      int oc = nt*16 + col16;
      float s = sAcc[nt], sq = sqAcc[nt];
      s  += __shfl_xor(s, 16);  s  += __shfl_xor(s, 32);
      sq += __shfl_xor(sq, 16); sq += __shfl_xor(sq, 32);
      if (q == 0){
        red[oc*WAVES + wave] = s;
        red[OCS*WAVES + oc*WAVES + wave] = sq;
      }
    }
    __syncthreads();
    float* oslot = ostats + ((blockIdx.y & 7) << 7);
    if (t < OCS){
      float s=0.f, sq=0.f;
      #pragma unroll
      for (int w=0; w<WAVES; w++){
        s  += red[t*WAVES + w];
        sq += red[OCS*WAVES + t*WAVES + w];
      }
      atomicAdd(&oslot[t], s);
      atomicAdd(&oslot[64+t], sq);
    }
  }
}

// ---------------- input 1x1 conv: NHWC(41) -> hi/lo records(64) ----------------
__global__ __launch_bounds__(256) void in_proj_kernel(
    const float* __restrict__ feat, const float* __restrict__ w,
    const float* __restrict__ b, __bf16* __restrict__ PX){
  __shared__ float sf[16][41];
  __shared__ float sw[64*41];
  int t = threadIdx.x;
  size_t p0 = (size_t)blockIdx.x*16;
  float wv[11];
  #pragma unroll
  for (int k=0;k<11;k++){ int idx=t+k*256; wv[k] = (idx<2624) ? w[idx] : 0.f; }
  float fv[3];
  #pragma unroll
  for (int k=0;k<3;k++){ int idx=t+k*256; fv[k] = (idx<656) ? feat[p0*41 + idx] : 0.f; }
  #pragma unroll
  for (int k=0;k<11;k++){ int idx=t+k*256; if (idx<2624) sw[idx]=wv[k]; }
  #pragma unroll
  for (int k=0;k<3;k++){
    int idx=t+k*256;
    if (idx<656){ int p = idx/41, k2 = idx - p*41; sf[p][k2]=fv[k]; }
  }
  __syncthreads();
  #pragma unroll
  for (int k=0;k<4;k++){
    int item = t + k*256;
    int c = item&63, p = item>>6;
    float acc = b[c];
    #pragma unroll
    for (int kk=0;kk<41;kk++) acc += sf[p][kk]*sw[c*41+kk];
    __bf16 h = (__bf16)acc;
    __bf16* rec = PX + (p0+p)*128;
    rec[c] = h; rec[64+c] = (__bf16)(acc - (float)h);
  }
}

// norm(U records, 8-replica stats) -> ELU -> U in place (no residual)
__global__ __launch_bounds__(256) void norm_elu_planes(
    __bf16* __restrict__ U, const float* __restrict__ stats){
  size_t idx = (size_t)blockIdx.x*256 + threadIdx.x;
  size_t px = idx>>3; int c0 = (int)(idx&7)*8;
  __bf16* ur = U + px*128;
  uint4 uh = *(const uint4*)(ur + c0);
  uint4 ul = *(const uint4*)(ur + 64 + c0);
  __bf16* uhp=(__bf16*)&uh; __bf16* ulp=(__bf16*)&ul;
  float mu[8], rs[8];
  #pragma unroll
  for (int k=0;k<8;k++){
    int c = c0+k;
    float s=0.f, sq=0.f;
    #pragma unroll
    for (int rp=0;rp<8;rp++){ s += stats[rp*128 + c]; sq += stats[rp*128 + 64 + c]; }
    float m = s*(1.f/NPIX);
    mu[k]=m; rs[k]=rsqrtf(sq*(1.f/NPIX) - m*m + 1e-5f);
  }
  #pragma unroll
  for (int k=0;k<8;k++){
    float v = ((float)uhp[k] + (float)ulp[k] - mu[k])*rs[k];
    v = v>0.f ? v : expm1f(v);
    __bf16 h = (__bf16)v; uhp[k]=h; ulp[k]=(__bf16)(v-(float)h);
  }
  *(uint4*)(ur + c0) = uh;
  *(uint4*)(ur + 64 + c0) = ul;
}

// norm(conv2raw U, 8-replica stats) + residual(PX) -> ELU -> PX (records)
__global__ __launch_bounds__(256) void norm_res_elu_planes(
    const __bf16* __restrict__ U, __bf16* __restrict__ PX,
    const float* __restrict__ stats){
  size_t idx = (size_t)blockIdx.x*256 + threadIdx.x;
  size_t px = idx>>3; int c0 = (int)(idx&7)*8;
  const __bf16* ur = U + px*128;
  __bf16* xr = PX + px*128;
  uint4 uh = *(const uint4*)(ur + c0);
  uint4 ul = *(const uint4*)(ur + 64 + c0);
  uint4 xh = *(uint4*)(xr + c0);
  uint4 xl = *(uint4*)(xr + 64 + c0);
  __bf16* uhp=(__bf16*)&uh; __bf16* ulp=(__bf16*)&ul;
  __bf16* xhp=(__bf16*)&xh; __bf16* xlp=(__bf16*)&xl;
  float mu[8], rs[8];
  #pragma unroll
  for (int k=0;k<8;k++){
    int c = c0+k;
    float s=0.f, sq=0.f;
    #pragma unroll
    for (int rp=0;rp<8;rp++){ s += stats[rp*128 + c]; sq += stats[rp*128 + 64 + c]; }
    float m = s*(1.f/NPIX);
    mu[k]=m; rs[k]=rsqrtf(sq*(1.f/NPIX) - m*m + 1e-5f);
  }
  #pragma unroll
  for (int k=0;k<8;k++){
    float v = ((float)uhp[k] + (float)ulp[k] - mu[k])*rs[k]
            + ((float)xhp[k] + (float)xlp[k]);
    v = v>0.f ? v : expm1f(v);
    __bf16 h = (__bf16)v; xhp[k]=h; xlp[k]=(__bf16)(v-(float)h);
  }
  *(uint4*)(xr + c0) = xh;
  *(uint4*)(xr + 64 + c0) = xl;
}

// ---------------- attention ----------------
__global__ __launch_bounds__(256) void g_partial_kernel(
    const float* __restrict__ td, float* __restrict__ GC){
  size_t base = (size_t)blockIdx.x*256;
  float cnt = (td[base + threadIdx.x] > 0.f) ? 1.f : 0.f;
  __shared__ float red[256];
  red[threadIdx.x]=cnt; __syncthreads();
  for (int st=128; st; st>>=1){
    if (threadIdx.x<st) red[threadIdx.x]+=red[threadIdx.x+st];
    __syncthreads();
  }
  if (threadIdx.x==0) atomicAdd(GC, red[0]);
}

__global__ void g_final_kernel(
    const float* __restrict__ GC, const float* __restrict__ tq,
    const float* __restrict__ w1, const float* __restrict__ b1,
    const float* __restrict__ w2, const float* __restrict__ b2,
    float* __restrict__ G){
  if (threadIdx.x==0){
    float f0 = GC[0]*(1.f/NPIX), f1 = tq[0], f2 = (float)LDIM/512.f;
    float z = b2[0];
    for (int j=0;j<16;j++){
      float h = f0*w1[j] + f1*w1[16+j] + f2*w1[32+j] + b1[j];
      z += (h>0.f?h:0.f)*w2[j];
    }
    G[0] = sigf(z);
  }
}

// q = X @ wq via MFMA; writes Qb bf16 [i][j][32]
__global__ __launch_bounds__(256) void qproj_mfma_kernel(
    const __bf16* __restrict__ PX, const __bf16* __restrict__ WqF,
    __bf16* __restrict__ Qb){
  const int t=threadIdx.x, wave=t>>6, lane=t&63, q=lane>>4, col16=lane&15;
  const size_t p0=(size_t)blockIdx.x*128;
  __shared__ __bf16 Xhi[128*72];
  __shared__ __bf16 Xlo[128*72];
  uint4 sv[8];
  #pragma unroll
  for (int k=0;k<8;k++){
    int c=t+k*256;
    sv[k] = *(const uint4*)((const char*)PX + (p0 + (c>>4))*256 + (c&15)*16);
  }
  #pragma unroll
  for (int k=0;k<8;k++){
    int c=t+k*256; int px=c>>4, sub=c&15;
    *(uint4*)(((sub<8)?Xhi:Xlo) + px*72 + (sub&7)*8) = sv[k];
  }
  __syncthreads();
  floatx4 acc[2][2];
  #pragma unroll
  for (int a=0;a<2;a++)
    #pragma unroll
    for (int b=0;b<2;b++){ floatx4 z={0.f,0.f,0.f,0.f}; acc[a][b]=z; }
  #pragma unroll
  for (int kc=0;kc<2;kc++){
    bf16x8 ah[2], al[2];
    #pragma unroll
    for (int mt=0;mt<2;mt++){
      int row = wave*32 + mt*16 + col16;
      ah[mt] = *(const bf16x8*)(Xhi + row*72 + kc*32 + q*8);
      al[mt] = *(const bf16x8*)(Xlo + row*72 + kc*32 + q*8);
    }
    #pragma unroll
    for (int nt=0;nt<2;nt++){
      bf16x8 b = *(const bf16x8*)(WqF + (kc*2+nt)*512 + lane*8);
      acc[0][nt] = __builtin_amdgcn_mfma_f32_16x16x32_bf16(ah[0], b, acc[0][nt], 0,0,0);
      acc[1][nt] = __builtin_amdgcn_mfma_f32_16x16x32_bf16(ah[1], b, acc[1][nt], 0,0,0);
      acc[0][nt] = __builtin_amdgcn_mfma_f32_16x16x32_bf16(al[0], b, acc[0][nt], 0,0,0);
      acc[1][nt] = __builtin_amdgcn_mfma_f32_16x16x32_bf16(al[1], b, acc[1][nt], 0,0,0);
    }
  }
  #pragma unroll
  for (int mt=0;mt<2;mt++){
    size_t pxb = p0 + wave*32 + mt*16 + q*4;
    #pragma unroll
    for (int nt=0;nt<2;nt++){
      int oc = nt*16 + col16;
      #pragma unroll
      for (int r=0;r<4;r++)
        Qb[(pxb+r)*32 + oc] = (__bf16)acc[mt][nt][r];
    }
  }
}

// leftb bf16 [i][a][n]; vleftTb bf16 [i][n][a]
__global__ __launch_bounds__(256) void proj_left_kernel(
    const __bf16* __restrict__ PX, const float* __restrict__ wl, const float* __restrict__ wvl,
    __bf16* __restrict__ leftb, __bf16* __restrict__ vleftTb){
  int i = blockIdx.x;
  __shared__ float xa[32][65];
  __shared__ float w1s[2048], w2s[2048];
  int c = threadIdx.x & 63;
  for (int a = threadIdx.x>>6; a<32; a+=4){
    const __bf16* rec = PX + ((size_t)i*LDIM + 12*a)*128;
    xa[a][c] = (float)rec[c] + (float)rec[64+c];
  }
  for (int idx=threadIdx.x; idx<2048; idx+=256){ w1s[idx]=wl[idx]; w2s[idx]=wvl[idx]; }
  __syncthreads();
  #pragma unroll
  for (int k=0;k<4;k++){
    int idx = threadIdx.x + k*256;
    int a = idx>>5, n = idx&31;
    float a1=0.f, a2=0.f;
    #pragma unroll
    for (int cc=0;cc<64;cc++){ float v=xa[a][cc]; a1+=v*w1s[cc*32+n]; a2+=v*w2s[cc*32+n]; }
    leftb  [(size_t)i*1024 + a*32 + n] = (__bf16)a1;
    vleftTb[(size_t)i*1024 + n*32 + a] = (__bf16)a2;
  }
}

// grid (12, 32): j0 = bx*32, a = by ; rightb [j][a][n] ; vrightTb [j][n][a]
__global__ __launch_bounds__(256) void proj_right_kernel(
    const __bf16* __restrict__ PX, const float* __restrict__ wr, const float* __restrict__ wvr,
    __bf16* __restrict__ rightb, __bf16* __restrict__ vrightTb){
  int a = blockIdx.y; int row = 12*a;
  int j0 = blockIdx.x*32;
  __shared__ float xr[32][65];
  __shared__ float w1s[2048], w2s[2048];
  for (int idx=threadIdx.x; idx<2048; idx+=256){ w1s[idx]=wr[idx]; w2s[idx]=wvr[idx]; }
  int c = threadIdx.x & 63;
  for (int jl = threadIdx.x>>6; jl<32; jl+=4){
    const __bf16* rec = PX + ((size_t)row*LDIM + j0 + jl)*128;
    xr[jl][c] = (float)rec[c] + (float)rec[64+c];
  }
  __syncthreads();
  #pragma unroll
  for (int k=0;k<4;k++){
    int idx=threadIdx.x+k*256; int jl=idx>>5, n=idx&31;
    float a1=0.f, a2=0.f;
    #pragma unroll
    for (int cc=0;cc<64;cc++){ float v=xr[jl][cc]; a1+=v*w1s[cc*32+n]; a2+=v*w2s[cc*32+n]; }
    rightb  [(size_t)(j0+jl)*1024 + a*32 + n] = (__bf16)a1;
    vrightTb[(size_t)(j0+jl)*1024 + n*32 + a] = (__bf16)a2;
  }
}

// S1: per-i GEMM  S[i,j,a] = Q[i,j,:] . left[i,a,:]
__global__ __launch_bounds__(256) void attn_s1_kernel(
    const __bf16* __restrict__ Qb, const __bf16* __restrict__ leftb,
    float* __restrict__ S){
  const int t=threadIdx.x, wave=t>>6, lane=t&63, q=lane>>4, col16=lane&15;
  const int i = blockIdx.y, j0 = blockIdx.x*128;
  bf16x8 bfrag[2];
  #pragma unroll
  for (int nt=0;nt<2;nt++)
    bfrag[nt] = *(const bf16x8*)(leftb + (size_t)i*1024 + (nt*16+col16)*32 + q*8);
  bf16x8 ah[2];
  #pragma unroll
  for (int mt=0;mt<2;mt++){
    int row = j0 + wave*32 + mt*16 + col16;
    ah[mt] = *(const bf16x8*)(Qb + ((size_t)i*LDIM + row)*32 + q*8);
  }
  floatx4 acc[2][2];
  #pragma unroll
  for (int a=0;a<2;a++)
    #pragma unroll
    for (int b=0;b<2;b++){ floatx4 z={0.f,0.f,0.f,0.f}; acc[a][b]=z; }
  #pragma unroll
  for (int mt=0;mt<2;mt++)
    #pragma unroll
    for (int nt=0;nt<2;nt++)
      acc[mt][nt] = __builtin_amdgcn_mfma_f32_16x16x32_bf16(ah[mt], bfrag[nt], acc[mt][nt], 0,0,0);
  #pragma unroll
  for (int mt=0;mt<2;mt++){
    int jb = j0 + wave*32 + mt*16 + q*4;
    #pragma unroll
    for (int nt=0;nt<2;nt++){
      int a = nt*16 + col16;
      #pragma unroll
      for (int r=0;r<4;r++)
        S[((size_t)i*LDIM + jb + r)*32 + a] = acc[mt][nt][r];
    }
  }
}

// S2: per-j GEMM  S[i,j,a] += Q[i,j,:] . right[j,a,:]
__global__ __launch_bounds__(256) void attn_s2_kernel(
    const __bf16* __restrict__ Qb, const __bf16* __restrict__ rightb,
    float* __restrict__ S){
  const int t=threadIdx.x, wave=t>>6, lane=t&63, q=lane>>4, col16=lane&15;
  const int j = blockIdx.y, i0 = blockIdx.x*128;
  bf16x8 bfrag[2];
  #pragma unroll
  for (int nt=0;nt<2;nt++)
    bfrag[nt] = *(const bf16x8*)(rightb + (size_t)j*1024 + (nt*16+col16)*32 + q*8);
  bf16x8 ah[2];
  #pragma unroll
  for (int mt=0;mt<2;mt++){
    int row = i0 + wave*32 + mt*16 + col16;
    ah[mt] = *(const bf16x8*)(Qb + ((size_t)row*LDIM + j)*32 + q*8);
  }
  floatx4 acc[2][2];
  #pragma unroll
  for (int a=0;a<2;a++)
    #pragma unroll
    for (int b=0;b<2;b++){ floatx4 z={0.f,0.f,0.f,0.f}; acc[a][b]=z; }
  #pragma unroll
  for (int mt=0;mt<2;mt++)
    #pragma unroll
    for (int nt=0;nt<2;nt++)
      acc[mt][nt] = __builtin_amdgcn_mfma_f32_16x16x32_bf16(ah[mt], bfrag[nt], acc[mt][nt], 0,0,0);
  #pragma unroll
  for (int mt=0;mt<2;mt++){
    int ib = i0 + wave*32 + mt*16 + q*4;
    #pragma unroll
    for (int nt=0;nt<2;nt++){
      int a = nt*16 + col16;
      #pragma unroll
      for (int r=0;r<4;r++){
        size_t idx = ((size_t)(ib+r)*LDIM + j)*32 + a;
        S[idx] += acc[mt][nt][r];
      }
    }
  }
}

// softmax(S*scale + g*bias) -> attnb/attnTb
__global__ __launch_bounds__(128) void attn_soft_kernel(
    const float* __restrict__ S, const float* __restrict__ td,
    const float* __restrict__ gp, __bf16* __restrict__ attnb,
    __bf16* __restrict__ attnTb){
  int i = blockIdx.y;
  int j0 = blockIdx.x*128;
  int t = threadIdx.x;
  int j = j0 + t;
  __shared__ float tl[32];
  __shared__ float trS[32*128];
  {
    #pragma unroll
    for (int v=0; v<8; v++){
      int f = t + v*128;
      int a = f>>5, jl4 = (f&31)*4;
      *(floatx4*)(trS + a*128 + jl4) = *(const floatx4*)(td + (size_t)(12*a)*LDIM + j0 + jl4);
    }
    if (t<32) tl[t] = td[(size_t)i*LDIM + 12*t];
  }
  __syncthreads();
  float g = gp[0];
  float tdij = td[(size_t)i*LDIM+j];
  float s[32];
  const floatx4* sp4 = (const floatx4*)(S + ((size_t)i*LDIM+j)*32);
  #pragma unroll
  for (int v=0;v<8;v++){
    floatx4 sv = sp4[v];
    #pragma unroll
    for (int e=0;e<4;e++) s[v*4+e] = sv[e];
  }
  float m = -1e30f;
  #pragma unroll
  for (int a=0;a<32;a++){
    float acc = s[a]*0.17677669529663687f;
    float bias = -fabsf(tl[a] + trS[a*128 + t] - tdij) * (1.0f/12.0f);
    acc += g*bias;
    s[a]=acc;
    m = fmaxf(m, acc);
  }
  float sum=0.f;
  #pragma unroll
  for (int a=0;a<32;a++){ s[a]=expf(s[a]-m); sum+=s[a]; }
  float inv = 1.f/sum;
  bf16x8 pk[4];
  #pragma unroll
  for (int v=0;v<4;v++){
    #pragma unroll
    for (int e=0;e<8;e++) pk[v][e] = (__bf16)(s[v*8+e]*inv);
  }
  bf16x8* op = (bf16x8*)(attnb + ((size_t)i*LDIM+j)*32);
  bf16x8* opT = (bf16x8*)(attnTb + ((size_t)j*LDIM+i)*32);
  #pragma unroll
  for (int v=0;v<4;v++){ op[v]=pk[v]; opT[v]=pk[v]; }
}

// U1: per-i GEMM  UPD[i,j,c] = attn[i,j,:] . vleftT[i,c,:]
__global__ __launch_bounds__(256) void attn_u1_kernel(
    const __bf16* __restrict__ attnb, const __bf16* __restrict__ vleftTb,
    float* __restrict__ UPD){
  const int t=threadIdx.x, wave=t>>6, lane=t&63, q=lane>>4, col16=lane&15;
  const int i = blockIdx.y, j0 = blockIdx.x*128;
  bf16x8 bfrag[2];
  #pragma unroll
  for (int nt=0;nt<2;nt++)
    bfrag[nt] = *(const bf16x8*)(vleftTb + (size_t)i*1024 + (nt*16+col16)*32 + q*8);
  bf16x8 ah[2];
  #pragma unroll
  for (int mt=0;mt<2;mt++){
    int row = j0 + wave*32 + mt*16 + col16;
    ah[mt] = *(const bf16x8*)(attnb + ((size_t)i*LDIM + row)*32 + q*8);
  }
  floatx4 acc[2][2];
  #pragma unroll
  for (int a=0;a<2;a++)
    #pragma unroll
    for (int b=0;b<2;b++){ floatx4 z={0.f,0.f,0.f,0.f}; acc[a][b]=z; }
  #pragma unroll
  for (int mt=0;mt<2;mt++)
    #pragma unroll
    for (int nt=0;nt<2;nt++)
      acc[mt][nt] = __builtin_amdgcn_mfma_f32_16x16x32_bf16(ah[mt], bfrag[nt], acc[mt][nt], 0,0,0);
  #pragma unroll
  for (int mt=0;mt<2;mt++){
    int jb = j0 + wave*32 + mt*16 + q*4;
    #pragma unroll
    for (int nt=0;nt<2;nt++){
      int c = nt*16 + col16;
      #pragma unroll
      for (int r=0;r<4;r++)
        UPD[((size_t)i*LDIM + jb + r)*32 + c] = acc[mt][nt][r];
    }
  }
}

// U2: per-j GEMM  UPD[i,j,c] += attnT[j,i,:] . vrightT[j,c,:]
__global__ __launch_bounds__(256) void attn_u2_kernel(
    const __bf16* __restrict__ attnTb, const __bf16* __restrict__ vrightTb,
    float* __restrict__ UPD){
  const int t=threadIdx.x, wave=t>>6, lane=t&63, q=lane>>4, col16=lane&15;
  const int j = blockIdx.y, i0 = blockIdx.x*128;
  bf16x8 bfrag[2];
  #pragma unroll
  for (int nt=0;nt<2;nt++)
    bfrag[nt] = *(const bf16x8*)(vrightTb + (size_t)j*1024 + (nt*16+col16)*32 + q*8);
  bf16x8 ah[2];
  #pragma unroll
  for (int mt=0;mt<2;mt++){
    int row = i0 + wave*32 + mt*16 + col16;
    ah[mt] = *(const bf16x8*)(attnTb + ((size_t)j*LDIM + row)*32 + q*8);
  }
  floatx4 acc[2][2];
  #pragma unroll
  for (int a=0;a<2;a++)
    #pragma unroll
    for (int b=0;b<2;b++){ floatx4 z={0.f,0.f,0.f,0.f}; acc[a][b]=z; }
  #pragma unroll
  for (int mt=0;mt<2;mt++)
    #pragma unroll
    for (int nt=0;nt<2;nt++)
      acc[mt][nt] = __builtin_amdgcn_mfma_f32_16x16x32_bf16(ah[mt], bfrag[nt], acc[mt][nt], 0,0,0);
  #pragma unroll
  for (int mt=0;mt<2;mt++){
    int ib = i0 + wave*32 + mt*16 + q*4;
    #pragma unroll
    for (int nt=0;nt<2;nt++){
      int c = nt*16 + col16;
      #pragma unroll
      for (int r=0;r<4;r++){
        size_t idx = ((size_t)(ib+r)*LDIM + j)*32 + c;
        UPD[idx] += acc[mt][nt][r];
      }
    }
  }
}

// PX += sigmoid(X@Wg+bg) * (UPD@Wo), in-place on records, via MFMA
__global__ __launch_bounds__(256) void gate_mfma_kernel(
    __bf16* __restrict__ PX, const float* __restrict__ UPD,
    const __bf16* __restrict__ WgF, const __bf16* __restrict__ WoF,
    const float* __restrict__ bg){
  const int t=threadIdx.x, wave=t>>6, lane=t&63, q=lane>>4, col16=lane&15;
  const size_t p0=(size_t)blockIdx.x*128;
  __shared__ __bf16 Xhi[128*72];
  __shared__ __bf16 Xlo[128*72];
  __shared__ __bf16 Ub[128*40];
  uint4 sv[8];
  #pragma unroll
  for (int k=0;k<8;k++){
    int c=t+k*256;
    sv[k] = *(const uint4*)((const char*)PX + (p0 + (c>>4))*256 + (c&15)*16);
  }
  floatx4 uv[4];
  #pragma unroll
  for (int k=0;k<4;k++){
    int p = (t>>3) + k*32;
    uv[k] = *(const floatx4*)(UPD + (p0+p)*32 + (t&7)*4);
  }
  #pragma unroll
  for (int k=0;k<8;k++){
    int c=t+k*256; int px=c>>4, sub=c&15;
    *(uint4*)(((sub<8)?Xhi:Xlo) + px*72 + (sub&7)*8) = sv[k];
  }
  #pragma unroll
  for (int k=0;k<4;k++){
    int p = (t>>3) + k*32;
    __bf16* pu = Ub + p*40 + (t&7)*4;
    #pragma unroll
    for (int kk=0;kk<4;kk++) pu[kk]=(__bf16)uv[k][kk];
  }
  __syncthreads();
  floatx4 accg[2][4], accu[2][4];
  #pragma unroll
  for (int a=0;a<2;a++)
    #pragma unroll
    for (int b=0;b<4;b++){ floatx4 z={0.f,0.f,0.f,0.f}; accg[a][b]=z; accu[a][b]=z; }
  #pragma unroll
  for (int kc=0;kc<2;kc++){
    bf16x8 ah[2], al[2];
    #pragma unroll
    for (int mt=0;mt<2;mt++){
      int row = wave*32 + mt*16 + col16;
      ah[mt] = *(const bf16x8*)(Xhi + row*72 + kc*32 + q*8);
      al[mt] = *(const bf16x8*)(Xlo + row*72 + kc*32 + q*8);
    }
    #pragma unroll
    for (int nt=0;nt<4;nt++){
      bf16x8 b = *(const bf16x8*)(WgF + (kc*4+nt)*512 + lane*8);
      accg[0][nt] = __builtin_amdgcn_mfma_f32_16x16x32_bf16(ah[0], b, accg[0][nt], 0,0,0);
      accg[1][nt] = __builtin_amdgcn_mfma_f32_16x16x32_bf16(ah[1], b, accg[1][nt], 0,0,0);
      accg[0][nt] = __builtin_amdgcn_mfma_f32_16x16x32_bf16(al[0], b, accg[0][nt], 0,0,0);
      accg[1][nt] = __builtin_amdgcn_mfma_f32_16x16x32_bf16(al[1], b, accg[1][nt], 0,0,0);
    }
  }
  {
    bf16x8 au[2];
    #pragma unroll
    for (int mt=0;mt<2;mt++){
      int row = wave*32 + mt*16 + col16;
      au[mt] = *(const bf16x8*)(Ub + row*40 + q*8);
    }
    #pragma unroll
    for (int nt=0;nt<4;nt++){
      bf16x8 b = *(const bf16x8*)(WoF + nt*512 + lane*8);
      accu[0][nt] = __builtin_amdgcn_mfma_f32_16x16x32_bf16(au[0], b, accu[0][nt], 0,0,0);
      accu[1][nt] = __builtin_amdgcn_mfma_f32_16x16x32_bf16(au[1], b, accu[1][nt], 0,0,0);
    }
  }
  #pragma unroll
  for (int mt=0;mt<2;mt++){
    size_t pxb = p0 + wave*32 + mt*16 + q*4;
    #pragma unroll
    for (int nt=0;nt<4;nt++){
      int oc = nt*16 + col16;
      float bgv = bg[oc];
      #pragma unroll
      for (int r=0;r<4;r++){
        __bf16* rec = PX + (pxb+r)*128;
        float xv = (float)rec[oc] + (float)rec[64+oc];
        float g = sigf(accg[mt][nt][r] + bgv);
        float xn = xv + g*accu[mt][nt][r];
        __bf16 h = (__bf16)xn;
        rec[oc] = h; rec[64+oc] = (__bf16)(xn - (float)h);
      }
    }
  }
}

// ---------------- heads ----------------
__global__ __launch_bounds__(256) void sym_kernel(
    const float* __restrict__ lg, __bf16* __restrict__ PS, float* __restrict__ dout){
  int i = blockIdx.y;
  int j = blockIdx.x*4 + (threadIdx.x>>6);
  int o = threadIdx.x & 63;
  float v = 0.5f*(lg[((size_t)i*LDIM+j)*64+o] + lg[((size_t)j*LDIM+i)*64+o]);
  size_t pix = (size_t)i*LDIM+j;
  __bf16 h = (__bf16)v;
  __bf16* rec = PS + pix*128;
  rec[o] = h; rec[64+o] = (__bf16)(v - (float)h);
  if (o<63) dout[pix*63+o] = v;
}

__global__ __launch_bounds__(256) void conf_kernel(
    const float* __restrict__ c2, const float* __restrict__ w,
    const float* __restrict__ b, float* __restrict__ out){
  int t = threadIdx.x;
  size_t pix = (size_t)blockIdx.x*8 + (t>>5);
  int c = t&31;
  float v = c2[pix*32 + c]*w[c];
  #pragma unroll
  for (int off=16; off; off>>=1) v += __shfl_xor(v, off);
  if (c==0) out[pix] = sigf(v + b[0]);
}

extern "C" void kernel_launch(void* const* d_in, const int* in_sizes, int n_in,
                              void* d_out, int out_size, void* d_ws, size_t ws_size,
                              hipStream_t stream){
  const float* feat = (const float*)d_in[0];
  const float* td   = (const float*)d_in[1];
  const float* tq   = (const float*)d_in[2];
  const float* in_w = (const float*)d_in[3];
  const float* in_b = (const float*)d_in[4];
  const float* c1w  = (const float*)d_in[5];
  const float* c1b  = (const float*)d_in[6];
  const float* c2w  = (const float*)d_in[7];
  const float* c2b  = (const float*)d_in[8];
  const float* wq   = (const float*)d_in[9];
  const float* wl   = (const float*)d_in[10];
  const float* wr   = (const float*)d_in[11];
  const float* wvl  = (const float*)d_in[12];
  const float* wvr  = (const float*)d_in[13];
  const float* wo   = (const float*)d_in[14];
  const float* wg   = (const float*)d_in[15];
  const float* bg   = (const float*)d_in[16];
  const float* tgw1 = (const float*)d_in[17];
  const float* tgb1 = (const float*)d_in[18];
  const float* tgw2 = (const float*)d_in[19];
  const float* tgb2 = (const float*)d_in[20];
  const float* dw   = (const float*)d_in[21];
  const float* db   = (const float*)d_in[22];
  const float* cf1w = (const float*)d_in[23];
  const float* cf1b = (const float*)d_in[24];
  const float* cf2w = (const float*)d_in[25];
  const float* cf2b = (const float*)d_in[26];
  const float* cf3w = (const float*)d_in[27];
  const float* cf3b = (const float*)d_in[28];

  float* ws = (float*)d_ws;
  const size_t BUF = (size_t)64*NPIX;
  float* R1 = ws;
  float* R2 = ws + BUF;
  float* R3 = ws + 2*BUF;
  float* STATS = ws + 3*BUF;             // 12 slots x 8 replicas x 128
  float* G     = STATS + 12288;
  float* GC    = G + 1;
  __bf16* WF   = (__bf16*)(G + 16);
  __bf16* WGF  = WF + 506880;
  __bf16* WOF  = WF + 510976;
  __bf16* WQF  = WF + 513024;

  __bf16* PX = (__bf16*)R1;
  __bf16* PT = (__bf16*)R2;
  __bf16* PU = (__bf16*)R3;
  // attention buffers (R2/R3 free during attention)
  char* R2c = (char*)R2;
  __bf16* Qb       = (__bf16*)R2c;                  // 9,437,184 B
  __bf16* ATTNB    = (__bf16*)(R2c +  9437184);     // 9,437,184 B
  __bf16* ATTNTB   = (__bf16*)(R2c + 18874368);     // 9,437,184 B
  __bf16* LEFTB    = (__bf16*)(R2c + 28311552);     //   786,432 B
  __bf16* RIGHTB   = (__bf16*)(R2c + 29097984);
  __bf16* VLEFTTB  = (__bf16*)(R2c + 29884416);
  __bf16* VRIGHTTB = (__bf16*)(R2c + 30670848);
  float* S   = R3;                                  // 18.9 MB
  float* UPD = R3 + (size_t)32*NPIX;                // 18.9 MB

  hipMemsetAsync(STATS, 0, (12288 + 16)*sizeof(float), stream);
  prep_kernel<<<2012, 256, 0, stream>>>(c1w, c2w, dw, cf1w, cf2w, wg, wo, wq, WF);
  g_partial_kernel<<<576, 256, 0, stream>>>(td, GC);
  g_final_kernel<<<1, 64, 0, stream>>>(GC, tq, tgw1, tgb1, tgw2, tgb2, G);

  in_proj_kernel<<<9216, 256, 0, stream>>>(feat, in_w, in_b, PX);

#define CONV2_NORM(i) \
  norm_elu_planes<<<4608, 256, 0, stream>>>(PT, STATS + (2*(i))*1024); \
  mfma_conv<64,4,1,4,2><<<dim3(6,192), 256, 0, stream>>>( \
      PT, WF + (size_t)(2*(i)+1)*36864, c2b + (i)*64, 64, \
      nullptr, PU, 0, STATS + (2*(i)+1)*1024); \
  norm_res_elu_planes<<<4608, 256, 0, stream>>>(PU, PX, STATS + (2*(i)+1)*1024);

#define CONV1(i, DD) \
  mfma_conv<64,4,DD,4,2><<<dim3(6,192), 256, 0, stream>>>( \
      PX, WF + (size_t)(2*(i))*36864, c1b + (i)*64, 64, \
      nullptr, PT, 0, STATS + (2*(i))*1024);

#define ATTN_BLOCK \
  qproj_mfma_kernel<<<1152, 256, 0, stream>>>(PX, WQF, Qb); \
  proj_left_kernel<<<384, 256, 0, stream>>>(PX, wl, wvl, LEFTB, VLEFTTB); \
  proj_right_kernel<<<dim3(12,32), 256, 0, stream>>>(PX, wr, wvr, RIGHTB, VRIGHTTB); \
  attn_s1_kernel<<<dim3(3,LDIM), 256, 0, stream>>>(Qb, LEFTB, S); \
  attn_s2_kernel<<<dim3(3,LDIM), 256, 0, stream>>>(Qb, RIGHTB, S); \
  attn_soft_kernel<<<dim3(3,LDIM), 128, 0, stream>>>(S, td, G, ATTNB, ATTNTB); \
  attn_u1_kernel<<<dim3(3,LDIM), 256, 0, stream>>>(ATTNB, VLEFTTB, UPD); \
  attn_u2_kernel<<<dim3(3,LDIM), 256, 0, stream>>>(ATTNTB, VRIGHTTB, UPD); \
  gate_mfma_kernel<<<1152, 256, 0, stream>>>(PX, UPD, WGF, WOF, bg);

  CONV1(0, 1)   CONV2_NORM(0)
  CONV1(1, 2)   CONV2_NORM(1)  ATTN_BLOCK
  CONV1(2, 4)   CONV2_NORM(2)
  CONV1(3, 8)   CONV2_NORM(3)  ATTN_BLOCK
  CONV1(4, 16)  CONV2_NORM(4)
  CONV1(5, 1)   CONV2_NORM(5)  ATTN_BLOCK

  // distance head: PX -> fp32 logits in R3
  mfma_conv<64,4,1,4,2><<<dim3(6,192), 256, 0, stream>>>(
      PX, WF + 442368, db, 63, R3, nullptr, 0, nullptr);
  sym_kernel<<<dim3(96,LDIM), 256, 0, stream>>>(R3, PT, (float*)d_out);
  // confidence head: PT(64rec) -> PX(32rec, relu) -> R3
  mfma_conv<64,2,1,4,2><<<dim3(6,192), 256, 0, stream>>>(
      PT, WF + 479232, cf1b, 32, nullptr, PX, 1, nullptr);
  mfma_conv<32,2,1,4,2><<<dim3(6,192), 256, 0, stream>>>(
      PX, WF + 497664, cf2b, 32, R3, nullptr, 1, nullptr);
  conf_kernel<<<18432, 256, 0, stream>>>(R3, cf3w, cf3b, (float*)d_out + (size_t)NPIX*NBINS);
}

// Round 8
// 1477.285 us; speedup vs baseline: 1.2241x; 1.1467x over previous
//
#include <hip/hip_runtime.h>
#include <math.h>

#define LDIM 384
#define NPIX (LDIM*LDIM)
#define NBINS 63

typedef __attribute__((ext_vector_type(8))) __bf16 bf16x8;
typedef __attribute__((ext_vector_type(4))) float floatx4;

__device__ __forceinline__ float sigf(float x){ return 1.f/(1.f+expf(-x)); }

// Prepped weight fragment layout (bf16): [tap][kc][nt][lane(64)][j(8)]
//   B-frag: n = nt*16 + (lane&15), k = kc*32 + (lane>>4)*8 + j
// WF arena offsets (bf16 units):
//   main conv slot s (0..11): s=2i conv1[i], s=2i+1 conv2[i], at s*36864
//   dist: 442368 ; cf1: 479232 ; cf2: 497664 ;
//   wg: 506880 (4096) ; wo: 510976 (2048) ; wq: 513024 (2048) ; total 515072
__global__ __launch_bounds__(256) void prep_kernel(
    const float* __restrict__ c1w, const float* __restrict__ c2w,
    const float* __restrict__ dw, const float* __restrict__ cf1w,
    const float* __restrict__ cf2w, const float* __restrict__ wg,
    const float* __restrict__ wo, const float* __restrict__ wq,
    __bf16* __restrict__ Wf){
  int idx = blockIdx.x*256 + threadIdx.x;
  if (idx >= 515072) return;
  if (idx >= 506880){
    int rel, NT, NDIM; const float* src;
    if (idx < 510976){ rel = idx - 506880; src = wg; NT=4; NDIM=64; }
    else if (idx < 513024){ rel = idx - 510976; src = wo; NT=4; NDIM=64; }
    else { rel = idx - 513024; src = wq; NT=2; NDIM=32; }
    int j = rel & 7, lane = (rel>>3) & 63;
    int r2 = rel >> 9;
    int nt = r2 % NT, kc = r2 / NT;
    int k = kc*32 + (lane>>4)*8 + j;
    int n = nt*16 + (lane&15);
    Wf[idx] = (__bf16)src[(size_t)k*NDIM + n];
    return;
  }
  const float* src; int ICreal, OCreal, ICP, NT, rel;
  if (idx < 442368){
    int layer = idx / 36864; rel = idx - layer*36864;
    int i = layer >> 1;
    src = (layer & 1) ? (c2w + (size_t)i*36864) : (c1w + (size_t)i*36864);
    ICreal=64; OCreal=64; ICP=64; NT=4;
  } else if (idx < 479232){
    rel = idx - 442368; src = dw;   ICreal=64; OCreal=63; ICP=64; NT=4;
  } else if (idx < 497664){
    rel = idx - 479232; src = cf1w; ICreal=63; OCreal=32; ICP=64; NT=2;
  } else {
    rel = idx - 497664; src = cf2w; ICreal=32; OCreal=32; ICP=32; NT=2;
  }
  int j = rel & 7, lane = (rel>>3) & 63;
  int r2 = rel >> 9;
  int nt = r2 % NT; int r3 = r2 / NT;
  int KC = ICP/32;
  int kc = r3 % KC; int tap = r3 / KC;
  int k = kc*32 + (lane>>4)*8 + j;
  int n = nt*16 + (lane&15);
  float v = 0.f;
  if (k < ICreal && n < OCreal) v = src[((size_t)n*ICreal + k)*9 + tap];
  Wf[idx] = (__bf16)v;
}

// ---------- MFMA implicit-GEMM 3x3 dilated conv, async LDS staging ----------
// ky-phase loop, 2 LDS row buffers. Staging via global_load_lds (width 16):
// coalesced 1KB/wave-instruction, no staging VGPRs, no ds_writes. Counted
// s_waitcnt vmcnt(N) + raw s_barrier keep the next row's loads in flight
// across barriers (guide T3/T4). XOR swizzle (both-sides, rule #21): LDS dest
// linear, global source chunk = sub^(px&7), read applies the same XOR ->
// 256B-stride record reads go from 16-way bank conflict to free 2-way.
#define VMCNT(N) asm volatile("s_waitcnt vmcnt(%0)" :: "n"(N) : "memory")
#define LGKM0()  asm volatile("s_waitcnt lgkmcnt(0)" ::: "memory")
#define BARS()   { __builtin_amdgcn_s_barrier(); __builtin_amdgcn_sched_barrier(0); }

template<int ICP, int NT, int D, int WAVES>
__global__ __launch_bounds__(WAVES*64) void mfma_conv(
    const __bf16* __restrict__ Ain, const __bf16* __restrict__ Wf,
    const float* __restrict__ bias, int OC_real,
    float* __restrict__ outF, __bf16* __restrict__ outP,
    int relu, float* __restrict__ ostats){
  constexpr int KC = ICP/32;
  constexpr int OCS = NT*16;
  constexpr int REC_B = ICP*4;          // bytes per px record (hi+lo)
  constexpr int PPX = REC_B/16;         // 16B chunks per record (16 or 8)
  constexpr int HALF = PPX/2;           // first lo chunk
  constexpr int W = WAVES*16;
  constexpr int T = WAVES*64;
  constexpr int SW = W + 2*D;
  constexpr int TOT1 = SW*PPX;          // chunks per staged row
  constexpr int NITER = (TOT1 + T - 1)/T;
  constexpr int BUFB = NITER*T*16;      // bytes per buffer (padded)
  extern __shared__ __align__(16) char smem[];
  char* buf0 = smem;
  char* buf1 = smem + BUFB;
  const int t = threadIdx.x;
  const int wave = t>>6, lane = t&63;
  const int q = lane>>4, col16 = lane&15;
  const int y = blockIdx.y;
  const int x0 = blockIdx.x*W;

  // per-thread staging slots (slot s = k*T + t; LDS byte = s*16)
  int srcoff[NITER];   // byte offset within row base (record + swizzled chunk)
  bool oob[NITER];     // x-OOB -> zero after landing
  #pragma unroll
  for (int k=0;k<NITER;k++){
    int s = k*T + t;
    int px = s / PPX;
    int sub = s % PPX;
    int cg = sub ^ (px & 7);            // inverse swizzle on source chunk
    int gx = x0 - D + px;
    oob[k] = (px < SW) && ((unsigned)gx >= LDIM);
    int gxc = min(max(gx,0), LDIM-1);
    srcoff[k] = gxc*REC_B + cg*16;
  }

  auto STAGE = [&](char* buf, int ky){
    int yr = y + (ky-1)*D;
    int yc = min(max(yr,0), LDIM-1);
    const char* rb = (const char*)Ain + (size_t)yc*LDIM*REC_B;
    #pragma unroll
    for (int k=0;k<NITER;k++){
      char* ldsb = buf + ((size_t)k*T + wave*64)*16;   // wave-uniform base
      const char* src = rb + srcoff[k];
      __builtin_amdgcn_global_load_lds(
          (const __attribute__((address_space(1))) void*)src,
          (__attribute__((address_space(3))) void*)ldsb, 16, 0, 0);
    }
  };
  auto ZOOB = [&](char* buf){
    #pragma unroll
    for (int k=0;k<NITER;k++)
      if (oob[k]){ uint4 z={0u,0u,0u,0u}; *(uint4*)(buf + ((size_t)k*T + t)*16) = z; }
  };

  floatx4 acc[NT];
  #pragma unroll
  for (int b=0;b<NT;b++){ floatx4 z = {0.f,0.f,0.f,0.f}; acc[b]=z; }

  auto MFMA_PHASE = [&](const char* buf, int ky){
    int yr = y + (ky-1)*D;
    if ((unsigned)yr >= LDIM) return;    // block-uniform
    #pragma unroll
    for (int kx=0;kx<3;kx++){
      int cl = wave*16 + col16 + kx*D;
      int e = cl & 7;
      bf16x8 wf[KC][NT];
      #pragma unroll
      for (int kc=0;kc<KC;kc++){
        const __bf16* wkc = Wf + (size_t)((ky*3+kx)*KC + kc)*NT*512 + lane*8;
        #pragma unroll
        for (int nt=0;nt<NT;nt++)
          wf[kc][nt] = *(const bf16x8*)(wkc + (size_t)nt*512);
      }
      #pragma unroll
      for (int kc=0;kc<KC;kc++){
        int sh = (kc*4+q) ^ e;
        int sl = (HALF + kc*4+q) ^ e;
        bf16x8 ah = *(const bf16x8*)(buf + (size_t)cl*REC_B + sh*16);
        bf16x8 al = *(const bf16x8*)(buf + (size_t)cl*REC_B + sl*16);
        #pragma unroll
        for (int nt=0;nt<NT;nt++){
          acc[nt] = __builtin_amdgcn_mfma_f32_16x16x32_bf16(ah, wf[kc][nt], acc[nt], 0,0,0);
          acc[nt] = __builtin_amdgcn_mfma_f32_16x16x32_bf16(al, wf[kc][nt], acc[nt], 0,0,0);
        }
      }
    }
  };

  // pipeline: rows 0,1 in flight; row 2 issued after row 0 consumed
  STAGE(buf0, 0);
  STAGE(buf1, 1);
  VMCNT(NITER);              // row 0 landed (row 1 may still fly)
  ZOOB(buf0); LGKM0();
  BARS();
  MFMA_PHASE(buf0, 0);
  BARS();                    // all waves done reading buf0
  STAGE(buf0, 2);
  VMCNT(NITER);              // row 1 landed (row 2 may still fly)
  ZOOB(buf1); LGKM0();
  BARS();
  MFMA_PHASE(buf1, 1);
  VMCNT(0);                  // row 2 landed
  ZOOB(buf0); LGKM0();
  BARS();
  MFMA_PHASE(buf0, 2);

  float sAcc[NT], sqAcc[NT];
  #pragma unroll
  for (int nt=0;nt<NT;nt++){ sAcc[nt]=0.f; sqAcc[nt]=0.f; }
  #pragma unroll
  for (int nt=0; nt<NT; nt++){
    int oc = nt*16 + col16;
    float bv = (oc < OC_real) ? bias[oc] : 0.f;
    int pxb = x0 + wave*16 + q*4;
    #pragma unroll
    for (int r=0; r<4; r++){
      float vv = acc[nt][r] + bv;
      if (relu) vv = fmaxf(vv, 0.f);
      size_t pix = (size_t)y*LDIM + pxb + r;
      if (outF) outF[pix*OCS + oc] = vv;
      if (outP){
        __bf16 h = (__bf16)vv;
        __bf16* rec = outP + pix*(size_t)(OCS*2);
        rec[oc] = h; rec[OCS+oc] = (__bf16)(vv - (float)h);
      }
      sAcc[nt] += vv; sqAcc[nt] += vv*vv;
    }
  }
  if (ostats){
    float* red = (float*)smem;
    __syncthreads();           // LDS buffers free for reuse
    #pragma unroll
    for (int nt=0; nt<NT; nt++){
      int oc = nt*16 + col16;
      float s = sAcc[nt], sq = sqAcc[nt];
      s  += __shfl_xor(s, 16);  s  += __shfl_xor(s, 32);
      sq += __shfl_xor(sq, 16); sq += __shfl_xor(sq, 32);
      if (q == 0){
        red[oc*WAVES + wave] = s;
        red[OCS*WAVES + oc*WAVES + wave] = sq;
      }
    }
    __syncthreads();
    float* oslot = ostats + ((blockIdx.y & 7) << 7);
    if (t < OCS){
      float s=0.f, sq=0.f;
      #pragma unroll
      for (int w=0; w<WAVES; w++){
        s  += red[t*WAVES + w];
        sq += red[OCS*WAVES + t*WAVES + w];
      }
      atomicAdd(&oslot[t], s);
      atomicAdd(&oslot[64+t], sq);
    }
  }
}

// ---------------- input 1x1 conv: NHWC(41) -> hi/lo records(64) ----------------
__global__ __launch_bounds__(256) void in_proj_kernel(
    const float* __restrict__ feat, const float* __restrict__ w,
    const float* __restrict__ b, __bf16* __restrict__ PX){
  __shared__ float sf[16][41];
  __shared__ float sw[64*41];
  int t = threadIdx.x;
  size_t p0 = (size_t)blockIdx.x*16;
  float wv[11];
  #pragma unroll
  for (int k=0;k<11;k++){ int idx=t+k*256; wv[k] = (idx<2624) ? w[idx] : 0.f; }
  float fv[3];
  #pragma unroll
  for (int k=0;k<3;k++){ int idx=t+k*256; fv[k] = (idx<656) ? feat[p0*41 + idx] : 0.f; }
  #pragma unroll
  for (int k=0;k<11;k++){ int idx=t+k*256; if (idx<2624) sw[idx]=wv[k]; }
  #pragma unroll
  for (int k=0;k<3;k++){
    int idx=t+k*256;
    if (idx<656){ int p = idx/41, k2 = idx - p*41; sf[p][k2]=fv[k]; }
  }
  __syncthreads();
  #pragma unroll
  for (int k=0;k<4;k++){
    int item = t + k*256;
    int c = item&63, p = item>>6;
    float acc = b[c];
    #pragma unroll
    for (int kk=0;kk<41;kk++) acc += sf[p][kk]*sw[c*41+kk];
    __bf16 h = (__bf16)acc;
    __bf16* rec = PX + (p0+p)*128;
    rec[c] = h; rec[64+c] = (__bf16)(acc - (float)h);
  }
}

// norm(U records, 8-replica stats) -> ELU -> U in place (no residual)
__global__ __launch_bounds__(256) void norm_elu_planes(
    __bf16* __restrict__ U, const float* __restrict__ stats){
  size_t idx = (size_t)blockIdx.x*256 + threadIdx.x;
  size_t px = idx>>3; int c0 = (int)(idx&7)*8;
  __bf16* ur = U + px*128;
  uint4 uh = *(const uint4*)(ur + c0);
  uint4 ul = *(const uint4*)(ur + 64 + c0);
  __bf16* uhp=(__bf16*)&uh; __bf16* ulp=(__bf16*)&ul;
  float mu[8], rs[8];
  #pragma unroll
  for (int k=0;k<8;k++){
    int c = c0+k;
    float s=0.f, sq=0.f;
    #pragma unroll
    for (int rp=0;rp<8;rp++){ s += stats[rp*128 + c]; sq += stats[rp*128 + 64 + c]; }
    float m = s*(1.f/NPIX);
    mu[k]=m; rs[k]=rsqrtf(sq*(1.f/NPIX) - m*m + 1e-5f);
  }
  #pragma unroll
  for (int k=0;k<8;k++){
    float v = ((float)uhp[k] + (float)ulp[k] - mu[k])*rs[k];
    v = v>0.f ? v : expm1f(v);
    __bf16 h = (__bf16)v; uhp[k]=h; ulp[k]=(__bf16)(v-(float)h);
  }
  *(uint4*)(ur + c0) = uh;
  *(uint4*)(ur + 64 + c0) = ul;
}

// norm(conv2raw U, 8-replica stats) + residual(PX) -> ELU -> PX (records)
__global__ __launch_bounds__(256) void norm_res_elu_planes(
    const __bf16* __restrict__ U, __bf16* __restrict__ PX,
    const float* __restrict__ stats){
  size_t idx = (size_t)blockIdx.x*256 + threadIdx.x;
  size_t px = idx>>3; int c0 = (int)(idx&7)*8;
  const __bf16* ur = U + px*128;
  __bf16* xr = PX + px*128;
  uint4 uh = *(const uint4*)(ur + c0);
  uint4 ul = *(const uint4*)(ur + 64 + c0);
  uint4 xh = *(uint4*)(xr + c0);
  uint4 xl = *(uint4*)(xr + 64 + c0);
  __bf16* uhp=(__bf16*)&uh; __bf16* ulp=(__bf16*)&ul;
  __bf16* xhp=(__bf16*)&xh; __bf16* xlp=(__bf16*)&xl;
  float mu[8], rs[8];
  #pragma unroll
  for (int k=0;k<8;k++){
    int c = c0+k;
    float s=0.f, sq=0.f;
    #pragma unroll
    for (int rp=0;rp<8;rp++){ s += stats[rp*128 + c]; sq += stats[rp*128 + 64 + c]; }
    float m = s*(1.f/NPIX);
    mu[k]=m; rs[k]=rsqrtf(sq*(1.f/NPIX) - m*m + 1e-5f);
  }
  #pragma unroll
  for (int k=0;k<8;k++){
    float v = ((float)uhp[k] + (float)ulp[k] - mu[k])*rs[k]
            + ((float)xhp[k] + (float)xlp[k]);
    v = v>0.f ? v : expm1f(v);
    __bf16 h = (__bf16)v; xhp[k]=h; xlp[k]=(__bf16)(v-(float)h);
  }
  *(uint4*)(xr + c0) = xh;
  *(uint4*)(xr + 64 + c0) = xl;
}

// ---------------- attention ----------------
__global__ __launch_bounds__(256) void g_partial_kernel(
    const float* __restrict__ td, float* __restrict__ GC){
  size_t base = (size_t)blockIdx.x*256;
  float cnt = (td[base + threadIdx.x] > 0.f) ? 1.f : 0.f;
  __shared__ float red[256];
  red[threadIdx.x]=cnt; __syncthreads();
  for (int st=128; st; st>>=1){
    if (threadIdx.x<st) red[threadIdx.x]+=red[threadIdx.x+st];
    __syncthreads();
  }
  if (threadIdx.x==0) atomicAdd(GC, red[0]);
}

__global__ void g_final_kernel(
    const float* __restrict__ GC, const float* __restrict__ tq,
    const float* __restrict__ w1, const float* __restrict__ b1,
    const float* __restrict__ w2, const float* __restrict__ b2,
    float* __restrict__ G){
  if (threadIdx.x==0){
    float f0 = GC[0]*(1.f/NPIX), f1 = tq[0], f2 = (float)LDIM/512.f;
    float z = b2[0];
    for (int j=0;j<16;j++){
      float h = f0*w1[j] + f1*w1[16+j] + f2*w1[32+j] + b1[j];
      z += (h>0.f?h:0.f)*w2[j];
    }
    G[0] = sigf(z);
  }
}

// q = X @ wq via MFMA; writes Qb bf16 [i][j][32]
__global__ __launch_bounds__(256) void qproj_mfma_kernel(
    const __bf16* __restrict__ PX, const __bf16* __restrict__ WqF,
    __bf16* __restrict__ Qb){
  const int t=threadIdx.x, wave=t>>6, lane=t&63, q=lane>>4, col16=lane&15;
  const size_t p0=(size_t)blockIdx.x*128;
  __shared__ __bf16 Xhi[128*72];
  __shared__ __bf16 Xlo[128*72];
  uint4 sv[8];
  #pragma unroll
  for (int k=0;k<8;k++){
    int c=t+k*256;
    sv[k] = *(const uint4*)((const char*)PX + (p0 + (c>>4))*256 + (c&15)*16);
  }
  #pragma unroll
  for (int k=0;k<8;k++){
    int c=t+k*256; int px=c>>4, sub=c&15;
    *(uint4*)(((sub<8)?Xhi:Xlo) + px*72 + (sub&7)*8) = sv[k];
  }
  __syncthreads();
  floatx4 acc[2][2];
  #pragma unroll
  for (int a=0;a<2;a++)
    #pragma unroll
    for (int b=0;b<2;b++){ floatx4 z={0.f,0.f,0.f,0.f}; acc[a][b]=z; }
  #pragma unroll
  for (int kc=0;kc<2;kc++){
    bf16x8 ah[2], al[2];
    #pragma unroll
    for (int mt=0;mt<2;mt++){
      int row = wave*32 + mt*16 + col16;
      ah[mt] = *(const bf16x8*)(Xhi + row*72 + kc*32 + q*8);
      al[mt] = *(const bf16x8*)(Xlo + row*72 + kc*32 + q*8);
    }
    #pragma unroll
    for (int nt=0;nt<2;nt++){
      bf16x8 b = *(const bf16x8*)(WqF + (kc*2+nt)*512 + lane*8);
      acc[0][nt] = __builtin_amdgcn_mfma_f32_16x16x32_bf16(ah[0], b, acc[0][nt], 0,0,0);
      acc[1][nt] = __builtin_amdgcn_mfma_f32_16x16x32_bf16(ah[1], b, acc[1][nt], 0,0,0);
      acc[0][nt] = __builtin_amdgcn_mfma_f32_16x16x32_bf16(al[0], b, acc[0][nt], 0,0,0);
      acc[1][nt] = __builtin_amdgcn_mfma_f32_16x16x32_bf16(al[1], b, acc[1][nt], 0,0,0);
    }
  }
  #pragma unroll
  for (int mt=0;mt<2;mt++){
    size_t pxb = p0 + wave*32 + mt*16 + q*4;
    #pragma unroll
    for (int nt=0;nt<2;nt++){
      int oc = nt*16 + col16;
      #pragma unroll
      for (int r=0;r<4;r++)
        Qb[(pxb+r)*32 + oc] = (__bf16)acc[mt][nt][r];
    }
  }
}

// leftb bf16 [i][a][n]; vleftTb bf16 [i][n][a]
__global__ __launch_bounds__(256) void proj_left_kernel(
    const __bf16* __restrict__ PX, const float* __restrict__ wl, const float* __restrict__ wvl,
    __bf16* __restrict__ leftb, __bf16* __restrict__ vleftTb){
  int i = blockIdx.x;
  __shared__ float xa[32][65];
  __shared__ float w1s[2048], w2s[2048];
  int c = threadIdx.x & 63;
  for (int a = threadIdx.x>>6; a<32; a+=4){
    const __bf16* rec = PX + ((size_t)i*LDIM + 12*a)*128;
    xa[a][c] = (float)rec[c] + (float)rec[64+c];
  }
  for (int idx=threadIdx.x; idx<2048; idx+=256){ w1s[idx]=wl[idx]; w2s[idx]=wvl[idx]; }
  __syncthreads();
  #pragma unroll
  for (int k=0;k<4;k++){
    int idx = threadIdx.x + k*256;
    int a = idx>>5, n = idx&31;
    float a1=0.f, a2=0.f;
    #pragma unroll
    for (int cc=0;cc<64;cc++){ float v=xa[a][cc]; a1+=v*w1s[cc*32+n]; a2+=v*w2s[cc*32+n]; }
    leftb  [(size_t)i*1024 + a*32 + n] = (__bf16)a1;
    vleftTb[(size_t)i*1024 + n*32 + a] = (__bf16)a2;
  }
}

// grid (12, 32): j0 = bx*32, a = by ; rightb [j][a][n] ; vrightTb [j][n][a]
__global__ __launch_bounds__(256) void proj_right_kernel(
    const __bf16* __restrict__ PX, const float* __restrict__ wr, const float* __restrict__ wvr,
    __bf16* __restrict__ rightb, __bf16* __restrict__ vrightTb){
  int a = blockIdx.y; int row = 12*a;
  int j0 = blockIdx.x*32;
  __shared__ float xr[32][65];
  __shared__ float w1s[2048], w2s[2048];
  for (int idx=threadIdx.x; idx<2048; idx+=256){ w1s[idx]=wr[idx]; w2s[idx]=wvr[idx]; }
  int c = threadIdx.x & 63;
  for (int jl = threadIdx.x>>6; jl<32; jl+=4){
    const __bf16* rec = PX + ((size_t)row*LDIM + j0 + jl)*128;
    xr[jl][c] = (float)rec[c] + (float)rec[64+c];
  }
  __syncthreads();
  #pragma unroll
  for (int k=0;k<4;k++){
    int idx=threadIdx.x+k*256; int jl=idx>>5, n=idx&31;
    float a1=0.f, a2=0.f;
    #pragma unroll
    for (int cc=0;cc<64;cc++){ float v=xr[jl][cc]; a1+=v*w1s[cc*32+n]; a2+=v*w2s[cc*32+n]; }
    rightb  [(size_t)(j0+jl)*1024 + a*32 + n] = (__bf16)a1;
    vrightTb[(size_t)(j0+jl)*1024 + n*32 + a] = (__bf16)a2;
  }
}

// S1: per-i GEMM  S[i,j,a] = Q[i,j,:] . left[i,a,:]
__global__ __launch_bounds__(256) void attn_s1_kernel(
    const __bf16* __restrict__ Qb, const __bf16* __restrict__ leftb,
    float* __restrict__ S){
  const int t=threadIdx.x, wave=t>>6, lane=t&63, q=lane>>4, col16=lane&15;
  const int i = blockIdx.y, j0 = blockIdx.x*128;
  bf16x8 bfrag[2];
  #pragma unroll
  for (int nt=0;nt<2;nt++)
    bfrag[nt] = *(const bf16x8*)(leftb + (size_t)i*1024 + (nt*16+col16)*32 + q*8);
  bf16x8 ah[2];
  #pragma unroll
  for (int mt=0;mt<2;mt++){
    int row = j0 + wave*32 + mt*16 + col16;
    ah[mt] = *(const bf16x8*)(Qb + ((size_t)i*LDIM + row)*32 + q*8);
  }
  floatx4 acc[2][2];
  #pragma unroll
  for (int a=0;a<2;a++)
    #pragma unroll
    for (int b=0;b<2;b++){ floatx4 z={0.f,0.f,0.f,0.f}; acc[a][b]=z; }
  #pragma unroll
  for (int mt=0;mt<2;mt++)
    #pragma unroll
    for (int nt=0;nt<2;nt++)
      acc[mt][nt] = __builtin_amdgcn_mfma_f32_16x16x32_bf16(ah[mt], bfrag[nt], acc[mt][nt], 0,0,0);
  #pragma unroll
  for (int mt=0;mt<2;mt++){
    int jb = j0 + wave*32 + mt*16 + q*4;
    #pragma unroll
    for (int nt=0;nt<2;nt++){
      int a = nt*16 + col16;
      #pragma unroll
      for (int r=0;r<4;r++)
        S[((size_t)i*LDIM + jb + r)*32 + a] = acc[mt][nt][r];
    }
  }
}

// S2: per-j GEMM  S[i,j,a] += Q[i,j,:] . right[j,a,:]
__global__ __launch_bounds__(256) void attn_s2_kernel(
    const __bf16* __restrict__ Qb, const __bf16* __restrict__ rightb,
    float* __restrict__ S){
  const int t=threadIdx.x, wave=t>>6, lane=t&63, q=lane>>4, col16=lane&15;
  const int j = blockIdx.y, i0 = blockIdx.x*128;
  bf16x8 bfrag[2];
  #pragma unroll
  for (int nt=0;nt<2;nt++)
    bfrag[nt] = *(const bf16x8*)(rightb + (size_t)j*1024 + (nt*16+col16)*32 + q*8);
  bf16x8 ah[2];
  #pragma unroll
  for (int mt=0;mt<2;mt++){
    int row = i0 + wave*32 + mt*16 + col16;
    ah[mt] = *(const bf16x8*)(Qb + ((size_t)row*LDIM + j)*32 + q*8);
  }
  floatx4 acc[2][2];
  #pragma unroll
  for (int a=0;a<2;a++)
    #pragma unroll
    for (int b=0;b<2;b++){ floatx4 z={0.f,0.f,0.f,0.f}; acc[a][b]=z; }
  #pragma unroll
  for (int mt=0;mt<2;mt++)
    #pragma unroll
    for (int nt=0;nt<2;nt++)
      acc[mt][nt] = __builtin_amdgcn_mfma_f32_16x16x32_bf16(ah[mt], bfrag[nt], acc[mt][nt], 0,0,0);
  #pragma unroll
  for (int mt=0;mt<2;mt++){
    int ib = i0 + wave*32 + mt*16 + q*4;
    #pragma unroll
    for (int nt=0;nt<2;nt++){
      int a = nt*16 + col16;
      #pragma unroll
      for (int r=0;r<4;r++){
        size_t idx = ((size_t)(ib+r)*LDIM + j)*32 + a;
        S[idx] += acc[mt][nt][r];
      }
    }
  }
}

// softmax(S*scale + g*bias) -> attnb/attnTb
__global__ __launch_bounds__(128) void attn_soft_kernel(
    const float* __restrict__ S, const float* __restrict__ td,
    const float* __restrict__ gp, __bf16* __restrict__ attnb,
    __bf16* __restrict__ attnTb){
  int i = blockIdx.y;
  int j0 = blockIdx.x*128;
  int t = threadIdx.x;
  int j = j0 + t;
  __shared__ float tl[32];
  __shared__ float trS[32*128];
  {
    #pragma unroll
    for (int v=0; v<8; v++){
      int f = t + v*128;
      int a = f>>5, jl4 = (f&31)*4;
      *(floatx4*)(trS + a*128 + jl4) = *(const floatx4*)(td + (size_t)(12*a)*LDIM + j0 + jl4);
    }
    if (t<32) tl[t] = td[(size_t)i*LDIM + 12*t];
  }
  __syncthreads();
  float g = gp[0];
  float tdij = td[(size_t)i*LDIM+j];
  float s[32];
  const floatx4* sp4 = (const floatx4*)(S + ((size_t)i*LDIM+j)*32);
  #pragma unroll
  for (int v=0;v<8;v++){
    floatx4 sv = sp4[v];
    #pragma unroll
    for (int e=0;e<4;e++) s[v*4+e] = sv[e];
  }
  float m = -1e30f;
  #pragma unroll
  for (int a=0;a<32;a++){
    float acc = s[a]*0.17677669529663687f;
    float bias = -fabsf(tl[a] + trS[a*128 + t] - tdij) * (1.0f/12.0f);
    acc += g*bias;
    s[a]=acc;
    m = fmaxf(m, acc);
  }
  float sum=0.f;
  #pragma unroll
  for (int a=0;a<32;a++){ s[a]=expf(s[a]-m); sum+=s[a]; }
  float inv = 1.f/sum;
  bf16x8 pk[4];
  #pragma unroll
  for (int v=0;v<4;v++){
    #pragma unroll
    for (int e=0;e<8;e++) pk[v][e] = (__bf16)(s[v*8+e]*inv);
  }
  bf16x8* op = (bf16x8*)(attnb + ((size_t)i*LDIM+j)*32);
  bf16x8* opT = (bf16x8*)(attnTb + ((size_t)j*LDIM+i)*32);
  #pragma unroll
  for (int v=0;v<4;v++){ op[v]=pk[v]; opT[v]=pk[v]; }
}

// U1: per-i GEMM  UPD[i,j,c] = attn[i,j,:] . vleftT[i,c,:]
__global__ __launch_bounds__(256) void attn_u1_kernel(
    const __bf16* __restrict__ attnb, const __bf16* __restrict__ vleftTb,
    float* __restrict__ UPD){
  const int t=threadIdx.x, wave=t>>6, lane=t&63, q=lane>>4, col16=lane&15;
  const int i = blockIdx.y, j0 = blockIdx.x*128;
  bf16x8 bfrag[2];
  #pragma unroll
  for (int nt=0;nt<2;nt++)
    bfrag[nt] = *(const bf16x8*)(vleftTb + (size_t)i*1024 + (nt*16+col16)*32 + q*8);
  bf16x8 ah[2];
  #pragma unroll
  for (int mt=0;mt<2;mt++){
    int row = j0 + wave*32 + mt*16 + col16;
    ah[mt] = *(const bf16x8*)(attnb + ((size_t)i*LDIM + row)*32 + q*8);
  }
  floatx4 acc[2][2];
  #pragma unroll
  for (int a=0;a<2;a++)
    #pragma unroll
    for (int b=0;b<2;b++){ floatx4 z={0.f,0.f,0.f,0.f}; acc[a][b]=z; }
  #pragma unroll
  for (int mt=0;mt<2;mt++)
    #pragma unroll
    for (int nt=0;nt<2;nt++)
      acc[mt][nt] = __builtin_amdgcn_mfma_f32_16x16x32_bf16(ah[mt], bfrag[nt], acc[mt][nt], 0,0,0);
  #pragma unroll
  for (int mt=0;mt<2;mt++){
    int jb = j0 + wave*32 + mt*16 + q*4;
    #pragma unroll
    for (int nt=0;nt<2;nt++){
      int c = nt*16 + col16;
      #pragma unroll
      for (int r=0;r<4;r++)
        UPD[((size_t)i*LDIM + jb + r)*32 + c] = acc[mt][nt][r];
    }
  }
}

// U2: per-j GEMM  UPD[i,j,c] += attnT[j,i,:] . vrightT[j,c,:]
__global__ __launch_bounds__(256) void attn_u2_kernel(
    const __bf16* __restrict__ attnTb, const __bf16* __restrict__ vrightTb,
    float* __restrict__ UPD){
  const int t=threadIdx.x, wave=t>>6, lane=t&63, q=lane>>4, col16=lane&15;
  const int j = blockIdx.y, i0 = blockIdx.x*128;
  bf16x8 bfrag[2];
  #pragma unroll
  for (int nt=0;nt<2;nt++)
    bfrag[nt] = *(const bf16x8*)(vrightTb + (size_t)j*1024 + (nt*16+col16)*32 + q*8);
  bf16x8 ah[2];
  #pragma unroll
  for (int mt=0;mt<2;mt++){
    int row = i0 + wave*32 + mt*16 + col16;
    ah[mt] = *(const bf16x8*)(attnTb + ((size_t)j*LDIM + row)*32 + q*8);
  }
  floatx4 acc[2][2];
  #pragma unroll
  for (int a=0;a<2;a++)
    #pragma unroll
    for (int b=0;b<2;b++){ floatx4 z={0.f,0.f,0.f,0.f}; acc[a][b]=z; }
  #pragma unroll
  for (int mt=0;mt<2;mt++)
    #pragma unroll
    for (int nt=0;nt<2;nt++)
      acc[mt][nt] = __builtin_amdgcn_mfma_f32_16x16x32_bf16(ah[mt], bfrag[nt], acc[mt][nt], 0,0,0);
  #pragma unroll
  for (int mt=0;mt<2;mt++){
    int ib = i0 + wave*32 + mt*16 + q*4;
    #pragma unroll
    for (int nt=0;nt<2;nt++){
      int c = nt*16 + col16;
      #pragma unroll
      for (int r=0;r<4;r++){
        size_t idx = ((size_t)(ib+r)*LDIM + j)*32 + c;
        UPD[idx] += acc[mt][nt][r];
      }
    }
  }
}

// PX += sigmoid(X@Wg+bg) * (UPD@Wo), in-place on records, via MFMA
__global__ __launch_bounds__(256) void gate_mfma_kernel(
    __bf16* __restrict__ PX, const float* __restrict__ UPD,
    const __bf16* __restrict__ WgF, const __bf16* __restrict__ WoF,
    const float* __restrict__ bg){
  const int t=threadIdx.x, wave=t>>6, lane=t&63, q=lane>>4, col16=lane&15;
  const size_t p0=(size_t)blockIdx.x*128;
  __shared__ __bf16 Xhi[128*72];
  __shared__ __bf16 Xlo[128*72];
  __shared__ __bf16 Ub[128*40];
  uint4 sv[8];
  #pragma unroll
  for (int k=0;k<8;k++){
    int c=t+k*256;
    sv[k] = *(const uint4*)((const char*)PX + (p0 + (c>>4))*256 + (c&15)*16);
  }
  floatx4 uv[4];
  #pragma unroll
  for (int k=0;k<4;k++){
    int p = (t>>3) + k*32;
    uv[k] = *(const floatx4*)(UPD + (p0+p)*32 + (t&7)*4);
  }
  #pragma unroll
  for (int k=0;k<8;k++){
    int c=t+k*256; int px=c>>4, sub=c&15;
    *(uint4*)(((sub<8)?Xhi:Xlo) + px*72 + (sub&7)*8) = sv[k];
  }
  #pragma unroll
  for (int k=0;k<4;k++){
    int p = (t>>3) + k*32;
    __bf16* pu = Ub + p*40 + (t&7)*4;
    #pragma unroll
    for (int kk=0;kk<4;kk++) pu[kk]=(__bf16)uv[k][kk];
  }
  __syncthreads();
  floatx4 accg[2][4], accu[2][4];
  #pragma unroll
  for (int a=0;a<2;a++)
    #pragma unroll
    for (int b=0;b<4;b++){ floatx4 z={0.f,0.f,0.f,0.f}; accg[a][b]=z; accu[a][b]=z; }
  #pragma unroll
  for (int kc=0;kc<2;kc++){
    bf16x8 ah[2], al[2];
    #pragma unroll
    for (int mt=0;mt<2;mt++){
      int row = wave*32 + mt*16 + col16;
      ah[mt] = *(const bf16x8*)(Xhi + row*72 + kc*32 + q*8);
      al[mt] = *(const bf16x8*)(Xlo + row*72 + kc*32 + q*8);
    }
    #pragma unroll
    for (int nt=0;nt<4;nt++){
      bf16x8 b = *(const bf16x8*)(WgF + (kc*4+nt)*512 + lane*8);
      accg[0][nt] = __builtin_amdgcn_mfma_f32_16x16x32_bf16(ah[0], b, accg[0][nt], 0,0,0);
      accg[1][nt] = __builtin_amdgcn_mfma_f32_16x16x32_bf16(ah[1], b, accg[1][nt], 0,0,0);
      accg[0][nt] = __builtin_amdgcn_mfma_f32_16x16x32_bf16(al[0], b, accg[0][nt], 0,0,0);
      accg[1][nt] = __builtin_amdgcn_mfma_f32_16x16x32_bf16(al[1], b, accg[1][nt], 0,0,0);
    }
  }
  {
    bf16x8 au[2];
    #pragma unroll
    for (int mt=0;mt<2;mt++){
      int row = wave*32 + mt*16 + col16;
      au[mt] = *(const bf16x8*)(Ub + row*40 + q*8);
    }
    #pragma unroll
    for (int nt=0;nt<4;nt++){
      bf16x8 b = *(const bf16x8*)(WoF + nt*512 + lane*8);
      accu[0][nt] = __builtin_amdgcn_mfma_f32_16x16x32_bf16(au[0], b, accu[0][nt], 0,0,0);
      accu[1][nt] = __builtin_amdgcn_mfma_f32_16x16x32_bf16(au[1], b, accu[1][nt], 0,0,0);
    }
  }
  #pragma unroll
  for (int mt=0;mt<2;mt++){
    size_t pxb = p0 + wave*32 + mt*16 + q*4;
    #pragma unroll
    for (int nt=0;nt<4;nt++){
      int oc = nt*16 + col16;
      float bgv = bg[oc];
      #pragma unroll
      for (int r=0;r<4;r++){
        __bf16* rec = PX + (pxb+r)*128;
        float xv = (float)rec[oc] + (float)rec[64+oc];
        float g = sigf(accg[mt][nt][r] + bgv);
        float xn = xv + g*accu[mt][nt][r];
        __bf16 h = (__bf16)xn;
        rec[oc] = h; rec[64+oc] = (__bf16)(xn - (float)h);
      }
    }
  }
}

// ---------------- heads ----------------
__global__ __launch_bounds__(256) void sym_kernel(
    const float* __restrict__ lg, __bf16* __restrict__ PS, float* __restrict__ dout){
  int i = blockIdx.y;
  int j = blockIdx.x*4 + (threadIdx.x>>6);
  int o = threadIdx.x & 63;
  float v = 0.5f*(lg[((size_t)i*LDIM+j)*64+o] + lg[((size_t)j*LDIM+i)*64+o]);
  size_t pix = (size_t)i*LDIM+j;
  __bf16 h = (__bf16)v;
  __bf16* rec = PS + pix*128;
  rec[o] = h; rec[64+o] = (__bf16)(v - (float)h);
  if (o<63) dout[pix*63+o] = v;
}

__global__ __launch_bounds__(256) void conf_kernel(
    const float* __restrict__ c2, const float* __restrict__ w,
    const float* __restrict__ b, float* __restrict__ out){
  int t = threadIdx.x;
  size_t pix = (size_t)blockIdx.x*8 + (t>>5);
  int c = t&31;
  float v = c2[pix*32 + c]*w[c];
  #pragma unroll
  for (int off=16; off; off>>=1) v += __shfl_xor(v, off);
  if (c==0) out[pix] = sigf(v + b[0]);
}

extern "C" void kernel_launch(void* const* d_in, const int* in_sizes, int n_in,
                              void* d_out, int out_size, void* d_ws, size_t ws_size,
                              hipStream_t stream){
  const float* feat = (const float*)d_in[0];
  const float* td   = (const float*)d_in[1];
  const float* tq   = (const float*)d_in[2];
  const float* in_w = (const float*)d_in[3];
  const float* in_b = (const float*)d_in[4];
  const float* c1w  = (const float*)d_in[5];
  const float* c1b  = (const float*)d_in[6];
  const float* c2w  = (const float*)d_in[7];
  const float* c2b  = (const float*)d_in[8];
  const float* wq   = (const float*)d_in[9];
  const float* wl   = (const float*)d_in[10];
  const float* wr   = (const float*)d_in[11];
  const float* wvl  = (const float*)d_in[12];
  const float* wvr  = (const float*)d_in[13];
  const float* wo   = (const float*)d_in[14];
  const float* wg   = (const float*)d_in[15];
  const float* bg   = (const float*)d_in[16];
  const float* tgw1 = (const float*)d_in[17];
  const float* tgb1 = (const float*)d_in[18];
  const float* tgw2 = (const float*)d_in[19];
  const float* tgb2 = (const float*)d_in[20];
  const float* dw   = (const float*)d_in[21];
  const float* db   = (const float*)d_in[22];
  const float* cf1w = (const float*)d_in[23];
  const float* cf1b = (const float*)d_in[24];
  const float* cf2w = (const float*)d_in[25];
  const float* cf2b = (const float*)d_in[26];
  const float* cf3w = (const float*)d_in[27];
  const float* cf3b = (const float*)d_in[28];

  float* ws = (float*)d_ws;
  const size_t BUF = (size_t)64*NPIX;
  float* R1 = ws;
  float* R2 = ws + BUF;
  float* R3 = ws + 2*BUF;
  float* STATS = ws + 3*BUF;             // 12 slots x 8 replicas x 128
  float* G     = STATS + 12288;
  float* GC    = G + 1;
  __bf16* WF   = (__bf16*)(G + 16);
  __bf16* WGF  = WF + 506880;
  __bf16* WOF  = WF + 510976;
  __bf16* WQF  = WF + 513024;

  __bf16* PX = (__bf16*)R1;
  __bf16* PT = (__bf16*)R2;
  __bf16* PU = (__bf16*)R3;
  // attention buffers (R2/R3 free during attention)
  char* R2c = (char*)R2;
  __bf16* Qb       = (__bf16*)R2c;                  // 9,437,184 B
  __bf16* ATTNB    = (__bf16*)(R2c +  9437184);     // 9,437,184 B
  __bf16* ATTNTB   = (__bf16*)(R2c + 18874368);     // 9,437,184 B
  __bf16* LEFTB    = (__bf16*)(R2c + 28311552);     //   786,432 B
  __bf16* RIGHTB   = (__bf16*)(R2c + 29097984);
  __bf16* VLEFTTB  = (__bf16*)(R2c + 29884416);
  __bf16* VRIGHTTB = (__bf16*)(R2c + 30670848);
  float* S   = R3;                                  // 18.9 MB
  float* UPD = R3 + (size_t)32*NPIX;                // 18.9 MB

  hipMemsetAsync(STATS, 0, (12288 + 16)*sizeof(float), stream);
  prep_kernel<<<2012, 256, 0, stream>>>(c1w, c2w, dw, cf1w, cf2w, wg, wo, wq, WF);
  g_partial_kernel<<<576, 256, 0, stream>>>(td, GC);
  g_final_kernel<<<1, 64, 0, stream>>>(GC, tq, tgw1, tgb1, tgw2, tgb2, G);

  in_proj_kernel<<<9216, 256, 0, stream>>>(feat, in_w, in_b, PX);

  // dynamic LDS: 2 row buffers of NITER*T*16 bytes
#define CONV_SMEM(ICP_, DD, WW) \
  (2 * (((((WW)*16+2*(DD))*((ICP_)/4)) + ((WW)*64) - 1)/((WW)*64)) * ((WW)*64) * 16)

#define CONV2_NORM(i) \
  norm_elu_planes<<<4608, 256, 0, stream>>>(PT, STATS + (2*(i))*1024); \
  mfma_conv<64,4,1,4><<<dim3(6,LDIM), 256, CONV_SMEM(64,1,4), stream>>>( \
      PT, WF + (size_t)(2*(i)+1)*36864, c2b + (i)*64, 64, \
      nullptr, PU, 0, STATS + (2*(i)+1)*1024); \
  norm_res_elu_planes<<<4608, 256, 0, stream>>>(PU, PX, STATS + (2*(i)+1)*1024);

#define CONV1(i, DD) \
  mfma_conv<64,4,DD,4><<<dim3(6,LDIM), 256, CONV_SMEM(64,DD,4), stream>>>( \
      PX, WF + (size_t)(2*(i))*36864, c1b + (i)*64, 64, \
      nullptr, PT, 0, STATS + (2*(i))*1024);

#define ATTN_BLOCK \
  qproj_mfma_kernel<<<1152, 256, 0, stream>>>(PX, WQF, Qb); \
  proj_left_kernel<<<384, 256, 0, stream>>>(PX, wl, wvl, LEFTB, VLEFTTB); \
  proj_right_kernel<<<dim3(12,32), 256, 0, stream>>>(PX, wr, wvr, RIGHTB, VRIGHTTB); \
  attn_s1_kernel<<<dim3(3,LDIM), 256, 0, stream>>>(Qb, LEFTB, S); \
  attn_s2_kernel<<<dim3(3,LDIM), 256, 0, stream>>>(Qb, RIGHTB, S); \
  attn_soft_kernel<<<dim3(3,LDIM), 128, 0, stream>>>(S, td, G, ATTNB, ATTNTB); \
  attn_u1_kernel<<<dim3(3,LDIM), 256, 0, stream>>>(ATTNB, VLEFTTB, UPD); \
  attn_u2_kernel<<<dim3(3,LDIM), 256, 0, stream>>>(ATTNTB, VRIGHTTB, UPD); \
  gate_mfma_kernel<<<1152, 256, 0, stream>>>(PX, UPD, WGF, WOF, bg);

  CONV1(0, 1)   CONV2_NORM(0)
  CONV1(1, 2)   CONV2_NORM(1)  ATTN_BLOCK
  CONV1(2, 4)   CONV2_NORM(2)
  CONV1(3, 8)   CONV2_NORM(3)  ATTN_BLOCK
  CONV1(4, 16)  CONV2_NORM(4)
  CONV1(5, 1)   CONV2_NORM(5)  ATTN_BLOCK

  // distance head: PX -> fp32 logits in R3
  mfma_conv<64,4,1,4><<<dim3(6,LDIM), 256, CONV_SMEM(64,1,4), stream>>>(
      PX, WF + 442368, db, 63, R3, nullptr, 0, nullptr);
  sym_kernel<<<dim3(96,LDIM), 256, 0, stream>>>(R3, PT, (float*)d_out);
  // confidence head: PT(64rec) -> PX(32rec, relu) -> R3
  mfma_conv<64,2,1,4><<<dim3(6,LDIM), 256, CONV_SMEM(64,1,4), stream>>>(
      PT, WF + 479232, cf1b, 32, nullptr, PX, 1, nullptr);
  mfma_conv<32,2,1,4><<<dim3(6,LDIM), 256, CONV_SMEM(32,1,4), stream>>>(
      PX, WF + 497664, cf2b, 32, R3, nullptr, 1, nullptr);
  conf_kernel<<<18432, 256, 0, stream>>>(R3, cf3w, cf3b, (float*)d_out + (size_t)NPIX*NBINS);
}

// Round 9
// 1460.605 us; speedup vs baseline: 1.2381x; 1.0114x over previous
//
#include <hip/hip_runtime.h>
#include <math.h>

#define LDIM 384
#define NPIX (LDIM*LDIM)
#define NBINS 63

typedef __attribute__((ext_vector_type(8))) __bf16 bf16x8;
typedef __attribute__((ext_vector_type(4))) float floatx4;

__device__ __forceinline__ float sigf(float x){ return 1.f/(1.f+expf(-x)); }

// Prepped weight fragment layout (bf16): [tap][kc][nt][lane(64)][j(8)]
//   B-frag: n = nt*16 + (lane&15), k = kc*32 + (lane>>4)*8 + j
// WF arena offsets (bf16 units):
//   main conv slot s (0..11): s=2i conv1[i], s=2i+1 conv2[i], at s*36864
//   dist: 442368 ; cf1: 479232 ; cf2: 497664 ;
//   wg: 506880 (4096) ; wo: 510976 (2048) ; wq: 513024 (2048) ;
//   in_w hi: 515072 (4096) ; in_w lo: 519168 (4096) ; total 523264
__global__ __launch_bounds__(256) void prep_kernel(
    const float* __restrict__ c1w, const float* __restrict__ c2w,
    const float* __restrict__ dw, const float* __restrict__ cf1w,
    const float* __restrict__ cf2w, const float* __restrict__ wg,
    const float* __restrict__ wo, const float* __restrict__ wq,
    const float* __restrict__ inw, __bf16* __restrict__ Wf){
  int idx = blockIdx.x*256 + threadIdx.x;
  if (idx >= 523264) return;
  if (idx >= 515072){
    int rel = idx - 515072;
    int hi = (rel < 4096) ? 1 : 0;
    int r = rel & 4095;
    int j = r & 7, lane = (r>>3) & 63;
    int r2 = r >> 9;
    int nt = r2 & 3, kc = r2 >> 2;
    int k = kc*32 + (lane>>4)*8 + j;
    int n = nt*16 + (lane&15);
    float v = (k < 41) ? inw[(size_t)n*41 + k] : 0.f;
    __bf16 h = (__bf16)v;
    Wf[idx] = hi ? h : (__bf16)(v - (float)h);
    return;
  }
  if (idx >= 506880){
    int rel, NT, NDIM; const float* src;
    if (idx < 510976){ rel = idx - 506880; src = wg; NT=4; NDIM=64; }
    else if (idx < 513024){ rel = idx - 510976; src = wo; NT=4; NDIM=64; }
    else { rel = idx - 513024; src = wq; NT=2; NDIM=32; }
    int j = rel & 7, lane = (rel>>3) & 63;
    int r2 = rel >> 9;
    int nt = r2 % NT, kc = r2 / NT;
    int k = kc*32 + (lane>>4)*8 + j;
    int n = nt*16 + (lane&15);
    Wf[idx] = (__bf16)src[(size_t)k*NDIM + n];
    return;
  }
  const float* src; int ICreal, OCreal, ICP, NT, rel;
  if (idx < 442368){
    int layer = idx / 36864; rel = idx - layer*36864;
    int i = layer >> 1;
    src = (layer & 1) ? (c2w + (size_t)i*36864) : (c1w + (size_t)i*36864);
    ICreal=64; OCreal=64; ICP=64; NT=4;
  } else if (idx < 479232){
    rel = idx - 442368; src = dw;   ICreal=64; OCreal=63; ICP=64; NT=4;
  } else if (idx < 497664){
    rel = idx - 479232; src = cf1w; ICreal=63; OCreal=32; ICP=64; NT=2;
  } else {
    rel = idx - 497664; src = cf2w; ICreal=32; OCreal=32; ICP=32; NT=2;
  }
  int j = rel & 7, lane = (rel>>3) & 63;
  int r2 = rel >> 9;
  int nt = r2 % NT; int r3 = r2 / NT;
  int KC = ICP/32;
  int kc = r3 % KC; int tap = r3 / KC;
  int k = kc*32 + (lane>>4)*8 + j;
  int n = nt*16 + (lane&15);
  float v = 0.f;
  if (k < ICreal && n < OCreal) v = src[((size_t)n*ICreal + k)*9 + tap];
  Wf[idx] = (__bf16)v;
}

// ---------- MFMA implicit-GEMM 3x3 dilated conv, async LDS staging ----------
// ky-phase loop, 2 LDS row buffers, global_load_lds (width 16) staging,
// counted s_waitcnt vmcnt(N) + raw s_barrier (loads stay in flight across
// barriers), both-sides XOR swizzle (rule #21). NORM: after each row lands,
// an in-LDS pass applies instance-norm + ELU (hi chunk at (g^e), lo at
// +128B); OOB pixels stay zero (zero-pad AFTER norm semantics).
#define VMCNT(N) asm volatile("s_waitcnt vmcnt(%0)" :: "n"(N) : "memory")
#define LGKM0()  asm volatile("s_waitcnt lgkmcnt(0)" ::: "memory")
#define BARS()   { __builtin_amdgcn_s_barrier(); __builtin_amdgcn_sched_barrier(0); }

template<int ICP, int NT, int D, int WAVES, bool NORM>
__global__ __launch_bounds__(WAVES*64) void mfma_conv(
    const __bf16* __restrict__ Ain, const __bf16* __restrict__ Wf,
    const float* __restrict__ bias, int OC_real,
    float* __restrict__ outF, __bf16* __restrict__ outP,
    int relu, const float* __restrict__ nstats, float* __restrict__ ostats){
  constexpr int KC = ICP/32;
  constexpr int OCS = NT*16;
  constexpr int REC_B = ICP*4;          // bytes per px record (hi+lo)
  constexpr int PPX = REC_B/16;         // 16B chunks per record (16 or 8)
  constexpr int HALF = PPX/2;           // first lo chunk
  constexpr int W = WAVES*16;
  constexpr int T = WAVES*64;
  constexpr int SW = W + 2*D;
  constexpr int TOT1 = SW*PPX;          // chunks per staged row
  constexpr int NITER = (TOT1 + T - 1)/T;
  constexpr int BUFB = NITER*T*16;      // bytes per buffer (padded)
  constexpr int SWH = SW*HALF;          // norm items (px, ch-group)
  constexpr int NP = (SWH + T - 1)/T;
  extern __shared__ __align__(16) char smem[];
  char* buf0 = smem;
  char* buf1 = smem + BUFB;
  float* muS = (float*)(smem + 2*(size_t)BUFB);
  const int t = threadIdx.x;
  const int wave = t>>6, lane = t&63;
  const int q = lane>>4, col16 = lane&15;
  const int y = blockIdx.y;
  const int x0 = blockIdx.x*W;

  if (NORM){
    if (t < 64){
      float s=0.f, sq=0.f;
      #pragma unroll
      for (int rp=0;rp<8;rp++){ s += nstats[rp*128 + t]; sq += nstats[rp*128 + 64 + t]; }
      float m = s*(1.f/NPIX);
      muS[t] = m;
      muS[64+t] = rsqrtf(sq*(1.f/NPIX) - m*m + 1e-5f);
    }
  }

  // per-thread staging slots (slot s = k*T + t; LDS byte = s*16)
  int srcoff[NITER];   // byte offset within row base (record + swizzled chunk)
  bool oob[NITER];     // x-OOB -> zero after landing
  #pragma unroll
  for (int k=0;k<NITER;k++){
    int s = k*T + t;
    int px = s / PPX;
    int sub = s % PPX;
    int cg = sub ^ (px & 7);            // inverse swizzle on source chunk
    int gx = x0 - D + px;
    oob[k] = (px < SW) && ((unsigned)gx >= LDIM);
    int gxc = min(max(gx,0), LDIM-1);
    srcoff[k] = gxc*REC_B + cg*16;
  }

  auto STAGE = [&](char* buf, int ky){
    int yr = y + (ky-1)*D;
    int yc = min(max(yr,0), LDIM-1);
    const char* rb = (const char*)Ain + (size_t)yc*LDIM*REC_B;
    #pragma unroll
    for (int k=0;k<NITER;k++){
      char* ldsb = buf + ((size_t)k*T + wave*64)*16;   // wave-uniform base
      const char* src = rb + srcoff[k];
      __builtin_amdgcn_global_load_lds(
          (const __attribute__((address_space(1))) void*)src,
          (__attribute__((address_space(3))) void*)ldsb, 16, 0, 0);
    }
  };
  auto ZOOB = [&](char* buf){
    #pragma unroll
    for (int k=0;k<NITER;k++)
      if (oob[k]){ uint4 z={0u,0u,0u,0u}; *(uint4*)(buf + ((size_t)k*T + t)*16) = z; }
  };
  auto NORMPASS = [&](char* buf){
    #pragma unroll
    for (int k=0;k<NP;k++){
      int idx = t + k*T;
      if (idx < SWH){
        int px = idx / HALF, g = idx % HALF;
        int gx = x0 - D + px;
        if ((unsigned)gx < LDIM){
          int e = px & 7;
          char* hp = buf + (size_t)px*REC_B + (size_t)(g ^ e)*16;
          char* lp = hp + HALF*16;     // (g+8)^e = (g^e)+8 for HALF=8
          bf16x8 hv = *(bf16x8*)hp, lv = *(bf16x8*)lp;
          int c0 = g*8;
          #pragma unroll
          for (int j=0;j<8;j++){
            float mu = muS[c0+j], rs = muS[64+c0+j];
            float v = ((float)hv[j] + (float)lv[j] - mu)*rs;
            v = v>0.f ? v : expm1f(v);
            __bf16 h = (__bf16)v; hv[j]=h; lv[j]=(__bf16)(v-(float)h);
          }
          *(bf16x8*)hp = hv; *(bf16x8*)lp = lv;
        }
      }
    }
  };

  floatx4 acc[NT];
  #pragma unroll
  for (int b=0;b<NT;b++){ floatx4 z = {0.f,0.f,0.f,0.f}; acc[b]=z; }

  auto MFMA_PHASE = [&](const char* buf, int ky){
    int yr = y + (ky-1)*D;
    if ((unsigned)yr >= LDIM) return;    // block-uniform
    #pragma unroll
    for (int kx=0;kx<3;kx++){
      int cl = wave*16 + col16 + kx*D;
      int e = cl & 7;
      bf16x8 wf[KC][NT];
      #pragma unroll
      for (int kc=0;kc<KC;kc++){
        const __bf16* wkc = Wf + (size_t)((ky*3+kx)*KC + kc)*NT*512 + lane*8;
        #pragma unroll
        for (int nt=0;nt<NT;nt++)
          wf[kc][nt] = *(const bf16x8*)(wkc + (size_t)nt*512);
      }
      #pragma unroll
      for (int kc=0;kc<KC;kc++){
        int sh = (kc*4+q) ^ e;
        int sl = (HALF + kc*4+q) ^ e;
        bf16x8 ah = *(const bf16x8*)(buf + (size_t)cl*REC_B + sh*16);
        bf16x8 al = *(const bf16x8*)(buf + (size_t)cl*REC_B + sl*16);
        #pragma unroll
        for (int nt=0;nt<NT;nt++){
          acc[nt] = __builtin_amdgcn_mfma_f32_16x16x32_bf16(ah, wf[kc][nt], acc[nt], 0,0,0);
          acc[nt] = __builtin_amdgcn_mfma_f32_16x16x32_bf16(al, wf[kc][nt], acc[nt], 0,0,0);
        }
      }
    }
  };

  // pipeline: rows 0,1 in flight; row 2 issued after row 0 consumed
  STAGE(buf0, 0);
  STAGE(buf1, 1);
  VMCNT(NITER);              // row 0 landed (row 1 may still fly)
  ZOOB(buf0); LGKM0();
  BARS();
  if (NORM){ NORMPASS(buf0); LGKM0(); BARS(); }
  MFMA_PHASE(buf0, 0);
  BARS();                    // all waves done reading buf0
  STAGE(buf0, 2);
  VMCNT(NITER);              // row 1 landed (row 2 may still fly)
  ZOOB(buf1); LGKM0();
  BARS();
  if (NORM){ NORMPASS(buf1); LGKM0(); BARS(); }
  MFMA_PHASE(buf1, 1);
  VMCNT(0);                  // row 2 landed
  ZOOB(buf0); LGKM0();
  BARS();
  if (NORM){ NORMPASS(buf0); LGKM0(); BARS(); }
  MFMA_PHASE(buf0, 2);

  float sAcc[NT], sqAcc[NT];
  #pragma unroll
  for (int nt=0;nt<NT;nt++){ sAcc[nt]=0.f; sqAcc[nt]=0.f; }
  #pragma unroll
  for (int nt=0; nt<NT; nt++){
    int oc = nt*16 + col16;
    float bv = (oc < OC_real) ? bias[oc] : 0.f;
    int pxb = x0 + wave*16 + q*4;
    #pragma unroll
    for (int r=0; r<4; r++){
      float vv = acc[nt][r] + bv;
      if (relu) vv = fmaxf(vv, 0.f);
      size_t pix = (size_t)y*LDIM + pxb + r;
      if (outF) outF[pix*OCS + oc] = vv;
      if (outP){
        __bf16 h = (__bf16)vv;
        __bf16* rec = outP + pix*(size_t)(OCS*2);
        rec[oc] = h; rec[OCS+oc] = (__bf16)(vv - (float)h);
      }
      sAcc[nt] += vv; sqAcc[nt] += vv*vv;
    }
  }
  if (ostats){
    float* red = (float*)smem;
    __syncthreads();           // LDS buffers free for reuse
    #pragma unroll
    for (int nt=0; nt<NT; nt++){
      int oc = nt*16 + col16;
      float s = sAcc[nt], sq = sqAcc[nt];
      s  += __shfl_xor(s, 16);  s  += __shfl_xor(s, 32);
      sq += __shfl_xor(sq, 16); sq += __shfl_xor(sq, 32);
      if (q == 0){
        red[oc*WAVES + wave] = s;
        red[OCS*WAVES + oc*WAVES + wave] = sq;
      }
    }
    __syncthreads();
    float* oslot = ostats + ((blockIdx.y & 7) << 7);
    if (t < OCS){
      float s=0.f, sq=0.f;
      #pragma unroll
      for (int w=0; w<WAVES; w++){
        s  += red[t*WAVES + w];
        sq += red[OCS*WAVES + t*WAVES + w];
      }
      atomicAdd(&oslot[t], s);
      atomicAdd(&oslot[64+t], sq);
    }
  }
}

// -------- input 1x1 conv via MFMA: [147456 x 41] @ [41 x 64] --------
// A: feat fp32 read 32B contiguous per lane, split hi/lo bf16 in-register.
// B: prepped hi+lo bf16 fragments -> 3 MFMAs (ah*bh + al*bh + ah*bl),
// matching fp32-weight precision to ~2^-16. Output: hi/lo records + bias.
__global__ __launch_bounds__(256) void in_proj_mfma(
    const float* __restrict__ feat, const __bf16* __restrict__ WinF,
    const float* __restrict__ b, __bf16* __restrict__ PX){
  const int t=threadIdx.x, wave=t>>6, lane=t&63, q=lane>>4, col16=lane&15;
  const size_t p0=(size_t)blockIdx.x*128;
  floatx4 acc[2][4];
  #pragma unroll
  for (int a=0;a<2;a++)
    #pragma unroll
    for (int c=0;c<4;c++){ floatx4 z={0.f,0.f,0.f,0.f}; acc[a][c]=z; }
  #pragma unroll
  for (int kc=0;kc<2;kc++){
    bf16x8 ah[2], al[2];
    #pragma unroll
    for (int mt=0;mt<2;mt++){
      size_t row = p0 + wave*32 + mt*16 + col16;
      const float* fp = feat + row*41 + kc*32 + q*8;
      float v[8];
      #pragma unroll
      for (int j=0;j<8;j++){
        int k = kc*32 + q*8 + j;
        v[j] = (k < 41) ? fp[j] : 0.f;
      }
      #pragma unroll
      for (int j=0;j<8;j++){
        __bf16 h = (__bf16)v[j];
        ah[mt][j] = h; al[mt][j] = (__bf16)(v[j] - (float)h);
      }
    }
    #pragma unroll
    for (int nt=0;nt<4;nt++){
      bf16x8 bh = *(const bf16x8*)(WinF + (size_t)(kc*4+nt)*512 + lane*8);
      bf16x8 bl = *(const bf16x8*)(WinF + 4096 + (size_t)(kc*4+nt)*512 + lane*8);
      #pragma unroll
      for (int mt=0;mt<2;mt++){
        acc[mt][nt] = __builtin_amdgcn_mfma_f32_16x16x32_bf16(ah[mt], bh, acc[mt][nt], 0,0,0);
        acc[mt][nt] = __builtin_amdgcn_mfma_f32_16x16x32_bf16(al[mt], bh, acc[mt][nt], 0,0,0);
        acc[mt][nt] = __builtin_amdgcn_mfma_f32_16x16x32_bf16(ah[mt], bl, acc[mt][nt], 0,0,0);
      }
    }
  }
  #pragma unroll
  for (int mt=0;mt<2;mt++){
    size_t pxb = p0 + wave*32 + mt*16 + q*4;
    #pragma unroll
    for (int nt=0;nt<4;nt++){
      int oc = nt*16 + col16;
      float bv = b[oc];
      #pragma unroll
      for (int r=0;r<4;r++){
        float vv = acc[mt][nt][r] + bv;
        __bf16* rec = PX + (pxb+r)*128;
        __bf16 h = (__bf16)vv;
        rec[oc] = h; rec[64+oc] = (__bf16)(vv - (float)h);
      }
    }
  }
}

// norm(conv2raw U, 8-replica stats) + residual(PX) -> ELU -> PX (records)
__global__ __launch_bounds__(256) void norm_res_elu_planes(
    const __bf16* __restrict__ U, __bf16* __restrict__ PX,
    const float* __restrict__ stats){
  size_t idx = (size_t)blockIdx.x*256 + threadIdx.x;
  size_t px = idx>>3; int c0 = (int)(idx&7)*8;
  const __bf16* ur = U + px*128;
  __bf16* xr = PX + px*128;
  uint4 uh = *(const uint4*)(ur + c0);
  uint4 ul = *(const uint4*)(ur + 64 + c0);
  uint4 xh = *(uint4*)(xr + c0);
  uint4 xl = *(uint4*)(xr + 64 + c0);
  __bf16* uhp=(__bf16*)&uh; __bf16* ulp=(__bf16*)&ul;
  __bf16* xhp=(__bf16*)&xh; __bf16* xlp=(__bf16*)&xl;
  float mu[8], rs[8];
  #pragma unroll
  for (int k=0;k<8;k++){
    int c = c0+k;
    float s=0.f, sq=0.f;
    #pragma unroll
    for (int rp=0;rp<8;rp++){ s += stats[rp*128 + c]; sq += stats[rp*128 + 64 + c]; }
    float m = s*(1.f/NPIX);
    mu[k]=m; rs[k]=rsqrtf(sq*(1.f/NPIX) - m*m + 1e-5f);
  }
  #pragma unroll
  for (int k=0;k<8;k++){
    float v = ((float)uhp[k] + (float)ulp[k] - mu[k])*rs[k]
            + ((float)xhp[k] + (float)xlp[k]);
    v = v>0.f ? v : expm1f(v);
    __bf16 h = (__bf16)v; xhp[k]=h; xlp[k]=(__bf16)(v-(float)h);
  }
  *(uint4*)(xr + c0) = xh;
  *(uint4*)(xr + 64 + c0) = xl;
}

// ---------------- attention ----------------
__global__ __launch_bounds__(256) void g_partial_kernel(
    const float* __restrict__ td, float* __restrict__ GC){
  size_t base = (size_t)blockIdx.x*256;
  float cnt = (td[base + threadIdx.x] > 0.f) ? 1.f : 0.f;
  __shared__ float red[256];
  red[threadIdx.x]=cnt; __syncthreads();
  for (int st=128; st; st>>=1){
    if (threadIdx.x<st) red[threadIdx.x]+=red[threadIdx.x+st];
    __syncthreads();
  }
  if (threadIdx.x==0) atomicAdd(GC, red[0]);
}

__global__ void g_final_kernel(
    const float* __restrict__ GC, const float* __restrict__ tq,
    const float* __restrict__ w1, const float* __restrict__ b1,
    const float* __restrict__ w2, const float* __restrict__ b2,
    float* __restrict__ G){
  if (threadIdx.x==0){
    float f0 = GC[0]*(1.f/NPIX), f1 = tq[0], f2 = (float)LDIM/512.f;
    float z = b2[0];
    for (int j=0;j<16;j++){
      float h = f0*w1[j] + f1*w1[16+j] + f2*w1[32+j] + b1[j];
      z += (h>0.f?h:0.f)*w2[j];
    }
    G[0] = sigf(z);
  }
}

// q = X @ wq via MFMA; writes Qb bf16 [i][j][32]
__global__ __launch_bounds__(256) void qproj_mfma_kernel(
    const __bf16* __restrict__ PX, const __bf16* __restrict__ WqF,
    __bf16* __restrict__ Qb){
  const int t=threadIdx.x, wave=t>>6, lane=t&63, q=lane>>4, col16=lane&15;
  const size_t p0=(size_t)blockIdx.x*128;
  __shared__ __bf16 Xhi[128*72];
  __shared__ __bf16 Xlo[128*72];
  uint4 sv[8];
  #pragma unroll
  for (int k=0;k<8;k++){
    int c=t+k*256;
    sv[k] = *(const uint4*)((const char*)PX + (p0 + (c>>4))*256 + (c&15)*16);
  }
  #pragma unroll
  for (int k=0;k<8;k++){
    int c=t+k*256; int px=c>>4, sub=c&15;
    *(uint4*)(((sub<8)?Xhi:Xlo) + px*72 + (sub&7)*8) = sv[k];
  }
  __syncthreads();
  floatx4 acc[2][2];
  #pragma unroll
  for (int a=0;a<2;a++)
    #pragma unroll
    for (int b=0;b<2;b++){ floatx4 z={0.f,0.f,0.f,0.f}; acc[a][b]=z; }
  #pragma unroll
  for (int kc=0;kc<2;kc++){
    bf16x8 ah[2], al[2];
    #pragma unroll
    for (int mt=0;mt<2;mt++){
      int row = wave*32 + mt*16 + col16;
      ah[mt] = *(const bf16x8*)(Xhi + row*72 + kc*32 + q*8);
      al[mt] = *(const bf16x8*)(Xlo + row*72 + kc*32 + q*8);
    }
    #pragma unroll
    for (int nt=0;nt<2;nt++){
      bf16x8 b = *(const bf16x8*)(WqF + (kc*2+nt)*512 + lane*8);
      acc[0][nt] = __builtin_amdgcn_mfma_f32_16x16x32_bf16(ah[0], b, acc[0][nt], 0,0,0);
      acc[1][nt] = __builtin_amdgcn_mfma_f32_16x16x32_bf16(ah[1], b, acc[1][nt], 0,0,0);
      acc[0][nt] = __builtin_amdgcn_mfma_f32_16x16x32_bf16(al[0], b, acc[0][nt], 0,0,0);
      acc[1][nt] = __builtin_amdgcn_mfma_f32_16x16x32_bf16(al[1], b, acc[1][nt], 0,0,0);
    }
  }
  #pragma unroll
  for (int mt=0;mt<2;mt++){
    size_t pxb = p0 + wave*32 + mt*16 + q*4;
    #pragma unroll
    for (int nt=0;nt<2;nt++){
      int oc = nt*16 + col16;
      #pragma unroll
      for (int r=0;r<4;r++)
        Qb[(pxb+r)*32 + oc] = (__bf16)acc[mt][nt][r];
    }
  }
}

// leftb bf16 [i][a][n]; vleftTb bf16 [i][n][a]
__global__ __launch_bounds__(256) void proj_left_kernel(
    const __bf16* __restrict__ PX, const float* __restrict__ wl, const float* __restrict__ wvl,
    __bf16* __restrict__ leftb, __bf16* __restrict__ vleftTb){
  int i = blockIdx.x;
  __shared__ float xa[32][65];
  __shared__ float w1s[2048], w2s[2048];
  int c = threadIdx.x & 63;
  for (int a = threadIdx.x>>6; a<32; a+=4){
    const __bf16* rec = PX + ((size_t)i*LDIM + 12*a)*128;
    xa[a][c] = (float)rec[c] + (float)rec[64+c];
  }
  for (int idx=threadIdx.x; idx<2048; idx+=256){ w1s[idx]=wl[idx]; w2s[idx]=wvl[idx]; }
  __syncthreads();
  #pragma unroll
  for (int k=0;k<4;k++){
    int idx = threadIdx.x + k*256;
    int a = idx>>5, n = idx&31;
    float a1=0.f, a2=0.f;
    #pragma unroll
    for (int cc=0;cc<64;cc++){ float v=xa[a][cc]; a1+=v*w1s[cc*32+n]; a2+=v*w2s[cc*32+n]; }
    leftb  [(size_t)i*1024 + a*32 + n] = (__bf16)a1;
    vleftTb[(size_t)i*1024 + n*32 + a] = (__bf16)a2;
  }
}

// grid (12, 32): j0 = bx*32, a = by ; rightb [j][a][n] ; vrightTb [j][n][a]
__global__ __launch_bounds__(256) void proj_right_kernel(
    const __bf16* __restrict__ PX, const float* __restrict__ wr, const float* __restrict__ wvr,
    __bf16* __restrict__ rightb, __bf16* __restrict__ vrightTb){
  int a = blockIdx.y; int row = 12*a;
  int j0 = blockIdx.x*32;
  __shared__ float xr[32][65];
  __shared__ float w1s[2048], w2s[2048];
  for (int idx=threadIdx.x; idx<2048; idx+=256){ w1s[idx]=wr[idx]; w2s[idx]=wvr[idx]; }
  int c = threadIdx.x & 63;
  for (int jl = threadIdx.x>>6; jl<32; jl+=4){
    const __bf16* rec = PX + ((size_t)row*LDIM + j0 + jl)*128;
    xr[jl][c] = (float)rec[c] + (float)rec[64+c];
  }
  __syncthreads();
  #pragma unroll
  for (int k=0;k<4;k++){
    int idx=threadIdx.x+k*256; int jl=idx>>5, n=idx&31;
    float a1=0.f, a2=0.f;
    #pragma unroll
    for (int cc=0;cc<64;cc++){ float v=xr[jl][cc]; a1+=v*w1s[cc*32+n]; a2+=v*w2s[cc*32+n]; }
    rightb  [(size_t)(j0+jl)*1024 + a*32 + n] = (__bf16)a1;
    vrightTb[(size_t)(j0+jl)*1024 + n*32 + a] = (__bf16)a2;
  }
}

// S1: per-i GEMM  S[i,j,a] = Q[i,j,:] . left[i,a,:]
__global__ __launch_bounds__(256) void attn_s1_kernel(
    const __bf16* __restrict__ Qb, const __bf16* __restrict__ leftb,
    float* __restrict__ S){
  const int t=threadIdx.x, wave=t>>6, lane=t&63, q=lane>>4, col16=lane&15;
  const int i = blockIdx.y, j0 = blockIdx.x*128;
  bf16x8 bfrag[2];
  #pragma unroll
  for (int nt=0;nt<2;nt++)
    bfrag[nt] = *(const bf16x8*)(leftb + (size_t)i*1024 + (nt*16+col16)*32 + q*8);
  bf16x8 ah[2];
  #pragma unroll
  for (int mt=0;mt<2;mt++){
    int row = j0 + wave*32 + mt*16 + col16;
    ah[mt] = *(const bf16x8*)(Qb + ((size_t)i*LDIM + row)*32 + q*8);
  }
  floatx4 acc[2][2];
  #pragma unroll
  for (int a=0;a<2;a++)
    #pragma unroll
    for (int b=0;b<2;b++){ floatx4 z={0.f,0.f,0.f,0.f}; acc[a][b]=z; }
  #pragma unroll
  for (int mt=0;mt<2;mt++)
    #pragma unroll
    for (int nt=0;nt<2;nt++)
      acc[mt][nt] = __builtin_amdgcn_mfma_f32_16x16x32_bf16(ah[mt], bfrag[nt], acc[mt][nt], 0,0,0);
  #pragma unroll
  for (int mt=0;mt<2;mt++){
    int jb = j0 + wave*32 + mt*16 + q*4;
    #pragma unroll
    for (int nt=0;nt<2;nt++){
      int a = nt*16 + col16;
      #pragma unroll
      for (int r=0;r<4;r++)
        S[((size_t)i*LDIM + jb + r)*32 + a] = acc[mt][nt][r];
    }
  }
}

// S2: per-j GEMM  S[i,j,a] += Q[i,j,:] . right[j,a,:]
__global__ __launch_bounds__(256) void attn_s2_kernel(
    const __bf16* __restrict__ Qb, const __bf16* __restrict__ rightb,
    float* __restrict__ S){
  const int t=threadIdx.x, wave=t>>6, lane=t&63, q=lane>>4, col16=lane&15;
  const int j = blockIdx.y, i0 = blockIdx.x*128;
  bf16x8 bfrag[2];
  #pragma unroll
  for (int nt=0;nt<2;nt++)
    bfrag[nt] = *(const bf16x8*)(rightb + (size_t)j*1024 + (nt*16+col16)*32 + q*8);
  bf16x8 ah[2];
  #pragma unroll
  for (int mt=0;mt<2;mt++){
    int row = i0 + wave*32 + mt*16 + col16;
    ah[mt] = *(const bf16x8*)(Qb + ((size_t)row*LDIM + j)*32 + q*8);
  }
  floatx4 acc[2][2];
  #pragma unroll
  for (int a=0;a<2;a++)
    #pragma unroll
    for (int b=0;b<2;b++){ floatx4 z={0.f,0.f,0.f,0.f}; acc[a][b]=z; }
  #pragma unroll
  for (int mt=0;mt<2;mt++)
    #pragma unroll
    for (int nt=0;nt<2;nt++)
      acc[mt][nt] = __builtin_amdgcn_mfma_f32_16x16x32_bf16(ah[mt], bfrag[nt], acc[mt][nt], 0,0,0);
  #pragma unroll
  for (int mt=0;mt<2;mt++){
    int ib = i0 + wave*32 + mt*16 + q*4;
    #pragma unroll
    for (int nt=0;nt<2;nt++){
      int a = nt*16 + col16;
      #pragma unroll
      for (int r=0;r<4;r++){
        size_t idx = ((size_t)(ib+r)*LDIM + j)*32 + a;
        S[idx] += acc[mt][nt][r];
      }
    }
  }
}

// softmax(S*scale + g*bias) -> attnb/attnTb
__global__ __launch_bounds__(128) void attn_soft_kernel(
    const float* __restrict__ S, const float* __restrict__ td,
    const float* __restrict__ gp, __bf16* __restrict__ attnb,
    __bf16* __restrict__ attnTb){
  int i = blockIdx.y;
  int j0 = blockIdx.x*128;
  int t = threadIdx.x;
  int j = j0 + t;
  __shared__ float tl[32];
  __shared__ float trS[32*128];
  {
    #pragma unroll
    for (int v=0; v<8; v++){
      int f = t + v*128;
      int a = f>>5, jl4 = (f&31)*4;
      *(floatx4*)(trS + a*128 + jl4) = *(const floatx4*)(td + (size_t)(12*a)*LDIM + j0 + jl4);
    }
    if (t<32) tl[t] = td[(size_t)i*LDIM + 12*t];
  }
  __syncthreads();
  float g = gp[0];
  float tdij = td[(size_t)i*LDIM+j];
  float s[32];
  const floatx4* sp4 = (const floatx4*)(S + ((size_t)i*LDIM+j)*32);
  #pragma unroll
  for (int v=0;v<8;v++){
    floatx4 sv = sp4[v];
    #pragma unroll
    for (int e=0;e<4;e++) s[v*4+e] = sv[e];
  }
  float m = -1e30f;
  #pragma unroll
  for (int a=0;a<32;a++){
    float acc = s[a]*0.17677669529663687f;
    float bias = -fabsf(tl[a] + trS[a*128 + t] - tdij) * (1.0f/12.0f);
    acc += g*bias;
    s[a]=acc;
    m = fmaxf(m, acc);
  }
  float sum=0.f;
  #pragma unroll
  for (int a=0;a<32;a++){ s[a]=expf(s[a]-m); sum+=s[a]; }
  float inv = 1.f/sum;
  bf16x8 pk[4];
  #pragma unroll
  for (int v=0;v<4;v++){
    #pragma unroll
    for (int e=0;e<8;e++) pk[v][e] = (__bf16)(s[v*8+e]*inv);
  }
  bf16x8* op = (bf16x8*)(attnb + ((size_t)i*LDIM+j)*32);
  bf16x8* opT = (bf16x8*)(attnTb + ((size_t)j*LDIM+i)*32);
  #pragma unroll
  for (int v=0;v<4;v++){ op[v]=pk[v]; opT[v]=pk[v]; }
}

// U1: per-i GEMM  UPD[i,j,c] = attn[i,j,:] . vleftT[i,c,:]
__global__ __launch_bounds__(256) void attn_u1_kernel(
    const __bf16* __restrict__ attnb, const __bf16* __restrict__ vleftTb,
    float* __restrict__ UPD){
  const int t=threadIdx.x, wave=t>>6, lane=t&63, q=lane>>4, col16=lane&15;
  const int i = blockIdx.y, j0 = blockIdx.x*128;
  bf16x8 bfrag[2];
  #pragma unroll
  for (int nt=0;nt<2;nt++)
    bfrag[nt] = *(const bf16x8*)(vleftTb + (size_t)i*1024 + (nt*16+col16)*32 + q*8);
  bf16x8 ah[2];
  #pragma unroll
  for (int mt=0;mt<2;mt++){
    int row = j0 + wave*32 + mt*16 + col16;
    ah[mt] = *(const bf16x8*)(attnb + ((size_t)i*LDIM + row)*32 + q*8);
  }
  floatx4 acc[2][2];
  #pragma unroll
  for (int a=0;a<2;a++)
    #pragma unroll
    for (int b=0;b<2;b++){ floatx4 z={0.f,0.f,0.f,0.f}; acc[a][b]=z; }
  #pragma unroll
  for (int mt=0;mt<2;mt++)
    #pragma unroll
    for (int nt=0;nt<2;nt++)
      acc[mt][nt] = __builtin_amdgcn_mfma_f32_16x16x32_bf16(ah[mt], bfrag[nt], acc[mt][nt], 0,0,0);
  #pragma unroll
  for (int mt=0;mt<2;mt++){
    int jb = j0 + wave*32 + mt*16 + q*4;
    #pragma unroll
    for (int nt=0;nt<2;nt++){
      int c = nt*16 + col16;
      #pragma unroll
      for (int r=0;r<4;r++)
        UPD[((size_t)i*LDIM + jb + r)*32 + c] = acc[mt][nt][r];
    }
  }
}

// U2: per-j GEMM  UPD[i,j,c] += attnT[j,i,:] . vrightT[j,c,:]
__global__ __launch_bounds__(256) void attn_u2_kernel(
    const __bf16* __restrict__ attnTb, const __bf16* __restrict__ vrightTb,
    float* __restrict__ UPD){
  const int t=threadIdx.x, wave=t>>6, lane=t&63, q=lane>>4, col16=lane&15;
  const int j = blockIdx.y, i0 = blockIdx.x*128;
  bf16x8 bfrag[2];
  #pragma unroll
  for (int nt=0;nt<2;nt++)
    bfrag[nt] = *(const bf16x8*)(vrightTb + (size_t)j*1024 + (nt*16+col16)*32 + q*8);
  bf16x8 ah[2];
  #pragma unroll
  for (int mt=0;mt<2;mt++){
    int row = i0 + wave*32 + mt*16 + col16;
    ah[mt] = *(const bf16x8*)(attnTb + ((size_t)j*LDIM + row)*32 + q*8);
  }
  floatx4 acc[2][2];
  #pragma unroll
  for (int a=0;a<2;a++)
    #pragma unroll
    for (int b=0;b<2;b++){ floatx4 z={0.f,0.f,0.f,0.f}; acc[a][b]=z; }
  #pragma unroll
  for (int mt=0;mt<2;mt++)
    #pragma unroll
    for (int nt=0;nt<2;nt++)
      acc[mt][nt] = __builtin_amdgcn_mfma_f32_16x16x32_bf16(ah[mt], bfrag[nt], acc[mt][nt], 0,0,0);
  #pragma unroll
  for (int mt=0;mt<2;mt++){
    int ib = i0 + wave*32 + mt*16 + q*4;
    #pragma unroll
    for (int nt=0;nt<2;nt++){
      int c = nt*16 + col16;
      #pragma unroll
      for (int r=0;r<4;r++){
        size_t idx = ((size_t)(ib+r)*LDIM + j)*32 + c;
        UPD[idx] += acc[mt][nt][r];
      }
    }
  }
}

// PX += sigmoid(X@Wg+bg) * (UPD@Wo), in-place on records, via MFMA
__global__ __launch_bounds__(256) void gate_mfma_kernel(
    __bf16* __restrict__ PX, const float* __restrict__ UPD,
    const __bf16* __restrict__ WgF, const __bf16* __restrict__ WoF,
    const float* __restrict__ bg){
  const int t=threadIdx.x, wave=t>>6, lane=t&63, q=lane>>4, col16=lane&15;
  const size_t p0=(size_t)blockIdx.x*128;
  __shared__ __bf16 Xhi[128*72];
  __shared__ __bf16 Xlo[128*72];
  __shared__ __bf16 Ub[128*40];
  uint4 sv[8];
  #pragma unroll
  for (int k=0;k<8;k++){
    int c=t+k*256;
    sv[k] = *(const uint4*)((const char*)PX + (p0 + (c>>4))*256 + (c&15)*16);
  }
  floatx4 uv[4];
  #pragma unroll
  for (int k=0;k<4;k++){
    int p = (t>>3) + k*32;
    uv[k] = *(const floatx4*)(UPD + (p0+p)*32 + (t&7)*4);
  }
  #pragma unroll
  for (int k=0;k<8;k++){
    int c=t+k*256; int px=c>>4, sub=c&15;
    *(uint4*)(((sub<8)?Xhi:Xlo) + px*72 + (sub&7)*8) = sv[k];
  }
  #pragma unroll
  for (int k=0;k<4;k++){
    int p = (t>>3) + k*32;
    __bf16* pu = Ub + p*40 + (t&7)*4;
    #pragma unroll
    for (int kk=0;kk<4;kk++) pu[kk]=(__bf16)uv[k][kk];
  }
  __syncthreads();
  floatx4 accg[2][4], accu[2][4];
  #pragma unroll
  for (int a=0;a<2;a++)
    #pragma unroll
    for (int b=0;b<4;b++){ floatx4 z={0.f,0.f,0.f,0.f}; accg[a][b]=z; accu[a][b]=z; }
  #pragma unroll
  for (int kc=0;kc<2;kc++){
    bf16x8 ah[2], al[2];
    #pragma unroll
    for (int mt=0;mt<2;mt++){
      int row = wave*32 + mt*16 + col16;
      ah[mt] = *(const bf16x8*)(Xhi + row*72 + kc*32 + q*8);
      al[mt] = *(const bf16x8*)(Xlo + row*72 + kc*32 + q*8);
    }
    #pragma unroll
    for (int nt=0;nt<4;nt++){
      bf16x8 b = *(const bf16x8*)(WgF + (kc*4+nt)*512 + lane*8);
      accg[0][nt] = __builtin_amdgcn_mfma_f32_16x16x32_bf16(ah[0], b, accg[0][nt], 0,0,0);
      accg[1][nt] = __builtin_amdgcn_mfma_f32_16x16x32_bf16(ah[1], b, accg[1][nt], 0,0,0);
      accg[0][nt] = __builtin_amdgcn_mfma_f32_16x16x32_bf16(al[0], b, accg[0][nt], 0,0,0);
      accg[1][nt] = __builtin_amdgcn_mfma_f32_16x16x32_bf16(al[1], b, accg[1][nt], 0,0,0);
    }
  }
  {
    bf16x8 au[2];
    #pragma unroll
    for (int mt=0;mt<2;mt++){
      int row = wave*32 + mt*16 + col16;
      au[mt] = *(const bf16x8*)(Ub + row*40 + q*8);
    }
    #pragma unroll
    for (int nt=0;nt<4;nt++){
      bf16x8 b = *(const bf16x8*)(WoF + nt*512 + lane*8);
      accu[0][nt] = __builtin_amdgcn_mfma_f32_16x16x32_bf16(au[0], b, accu[0][nt], 0,0,0);
      accu[1][nt] = __builtin_amdgcn_mfma_f32_16x16x32_bf16(au[1], b, accu[1][nt], 0,0,0);
    }
  }
  #pragma unroll
  for (int mt=0;mt<2;mt++){
    size_t pxb = p0 + wave*32 + mt*16 + q*4;
    #pragma unroll
    for (int nt=0;nt<4;nt++){
      int oc = nt*16 + col16;
      float bgv = bg[oc];
      #pragma unroll
      for (int r=0;r<4;r++){
        __bf16* rec = PX + (pxb+r)*128;
        float xv = (float)rec[oc] + (float)rec[64+oc];
        float g = sigf(accg[mt][nt][r] + bgv);
        float xn = xv + g*accu[mt][nt][r];
        __bf16 h = (__bf16)xn;
        rec[oc] = h; rec[64+oc] = (__bf16)(xn - (float)h);
      }
    }
  }
}

// ---------------- heads ----------------
__global__ __launch_bounds__(256) void sym_kernel(
    const float* __restrict__ lg, __bf16* __restrict__ PS, float* __restrict__ dout){
  int i = blockIdx.y;
  int j = blockIdx.x*4 + (threadIdx.x>>6);
  int o = threadIdx.x & 63;
  float v = 0.5f*(lg[((size_t)i*LDIM+j)*64+o] + lg[((size_t)j*LDIM+i)*64+o]);
  size_t pix = (size_t)i*LDIM+j;
  __bf16 h = (__bf16)v;
  __bf16* rec = PS + pix*128;
  rec[o] = h; rec[64+o] = (__bf16)(v - (float)h);
  if (o<63) dout[pix*63+o] = v;
}

__global__ __launch_bounds__(256) void conf_kernel(
    const float* __restrict__ c2, const float* __restrict__ w,
    const float* __restrict__ b, float* __restrict__ out){
  int t = threadIdx.x;
  size_t pix = (size_t)blockIdx.x*8 + (t>>5);
  int c = t&31;
  float v = c2[pix*32 + c]*w[c];
  #pragma unroll
  for (int off=16; off; off>>=1) v += __shfl_xor(v, off);
  if (c==0) out[pix] = sigf(v + b[0]);
}

extern "C" void kernel_launch(void* const* d_in, const int* in_sizes, int n_in,
                              void* d_out, int out_size, void* d_ws, size_t ws_size,
                              hipStream_t stream){
  const float* feat = (const float*)d_in[0];
  const float* td   = (const float*)d_in[1];
  const float* tq   = (const float*)d_in[2];
  const float* in_w = (const float*)d_in[3];
  const float* in_b = (const float*)d_in[4];
  const float* c1w  = (const float*)d_in[5];
  const float* c1b  = (const float*)d_in[6];
  const float* c2w  = (const float*)d_in[7];
  const float* c2b  = (const float*)d_in[8];
  const float* wq   = (const float*)d_in[9];
  const float* wl   = (const float*)d_in[10];
  const float* wr   = (const float*)d_in[11];
  const float* wvl  = (const float*)d_in[12];
  const float* wvr  = (const float*)d_in[13];
  const float* wo   = (const float*)d_in[14];
  const float* wg   = (const float*)d_in[15];
  const float* bg   = (const float*)d_in[16];
  const float* tgw1 = (const float*)d_in[17];
  const float* tgb1 = (const float*)d_in[18];
  const float* tgw2 = (const float*)d_in[19];
  const float* tgb2 = (const float*)d_in[20];
  const float* dw   = (const float*)d_in[21];
  const float* db   = (const float*)d_in[22];
  const float* cf1w = (const float*)d_in[23];
  const float* cf1b = (const float*)d_in[24];
  const float* cf2w = (const float*)d_in[25];
  const float* cf2b = (const float*)d_in[26];
  const float* cf3w = (const float*)d_in[27];
  const float* cf3b = (const float*)d_in[28];

  float* ws = (float*)d_ws;
  const size_t BUF = (size_t)64*NPIX;
  float* R1 = ws;
  float* R2 = ws + BUF;
  float* R3 = ws + 2*BUF;
  float* STATS = ws + 3*BUF;             // 12 slots x 8 replicas x 128
  float* G     = STATS + 12288;
  float* GC    = G + 1;
  __bf16* WF   = (__bf16*)(G + 16);
  __bf16* WGF  = WF + 506880;
  __bf16* WOF  = WF + 510976;
  __bf16* WQF  = WF + 513024;
  __bf16* WINF = WF + 515072;

  __bf16* PX = (__bf16*)R1;
  __bf16* PT = (__bf16*)R2;
  __bf16* PU = (__bf16*)R3;
  // attention buffers (R2/R3 free during attention)
  char* R2c = (char*)R2;
  __bf16* Qb       = (__bf16*)R2c;                  // 9,437,184 B
  __bf16* ATTNB    = (__bf16*)(R2c +  9437184);     // 9,437,184 B
  __bf16* ATTNTB   = (__bf16*)(R2c + 18874368);     // 9,437,184 B
  __bf16* LEFTB    = (__bf16*)(R2c + 28311552);     //   786,432 B
  __bf16* RIGHTB   = (__bf16*)(R2c + 29097984);
  __bf16* VLEFTTB  = (__bf16*)(R2c + 29884416);
  __bf16* VRIGHTTB = (__bf16*)(R2c + 30670848);
  float* S   = R3;                                  // 18.9 MB
  float* UPD = R3 + (size_t)32*NPIX;                // 18.9 MB

  hipMemsetAsync(STATS, 0, (12288 + 16)*sizeof(float), stream);
  prep_kernel<<<2044, 256, 0, stream>>>(c1w, c2w, dw, cf1w, cf2w, wg, wo, wq, in_w, WF);
  g_partial_kernel<<<576, 256, 0, stream>>>(td, GC);
  g_final_kernel<<<1, 64, 0, stream>>>(GC, tq, tgw1, tgb1, tgw2, tgb2, G);

  in_proj_mfma<<<1152, 256, 0, stream>>>(feat, WINF, in_b, PX);

  // dynamic LDS: 2 row buffers of NITER*T*16 bytes (+512 for fused norm muS)
#define CONV_SMEM(ICP_, DD, WW) \
  (2 * (((((WW)*16+2*(DD))*((ICP_)/4)) + ((WW)*64) - 1)/((WW)*64)) * ((WW)*64) * 16)

#define CONV2_NORM(i) \
  mfma_conv<64,4,1,4,true><<<dim3(6,LDIM), 256, CONV_SMEM(64,1,4)+512, stream>>>( \
      PT, WF + (size_t)(2*(i)+1)*36864, c2b + (i)*64, 64, \
      nullptr, PU, 0, STATS + (2*(i))*1024, STATS + (2*(i)+1)*1024); \
  norm_res_elu_planes<<<4608, 256, 0, stream>>>(PU, PX, STATS + (2*(i)+1)*1024);

#define CONV1(i, DD) \
  mfma_conv<64,4,DD,4,false><<<dim3(6,LDIM), 256, CONV_SMEM(64,DD,4), stream>>>( \
      PX, WF + (size_t)(2*(i))*36864, c1b + (i)*64, 64, \
      nullptr, PT, 0, nullptr, STATS + (2*(i))*1024);

#define ATTN_BLOCK \
  qproj_mfma_kernel<<<1152, 256, 0, stream>>>(PX, WQF, Qb); \
  proj_left_kernel<<<384, 256, 0, stream>>>(PX, wl, wvl, LEFTB, VLEFTTB); \
  proj_right_kernel<<<dim3(12,32), 256, 0, stream>>>(PX, wr, wvr, RIGHTB, VRIGHTTB); \
  attn_s1_kernel<<<dim3(3,LDIM), 256, 0, stream>>>(Qb, LEFTB, S); \
  attn_s2_kernel<<<dim3(3,LDIM), 256, 0, stream>>>(Qb, RIGHTB, S); \
  attn_soft_kernel<<<dim3(3,LDIM), 128, 0, stream>>>(S, td, G, ATTNB, ATTNTB); \
  attn_u1_kernel<<<dim3(3,LDIM), 256, 0, stream>>>(ATTNB, VLEFTTB, UPD); \
  attn_u2_kernel<<<dim3(3,LDIM), 256, 0, stream>>>(ATTNTB, VRIGHTTB, UPD); \
  gate_mfma_kernel<<<1152, 256, 0, stream>>>(PX, UPD, WGF, WOF, bg);

  CONV1(0, 1)   CONV2_NORM(0)
  CONV1(1, 2)   CONV2_NORM(1)  ATTN_BLOCK
  CONV1(2, 4)   CONV2_NORM(2)
  CONV1(3, 8)   CONV2_NORM(3)  ATTN_BLOCK
  CONV1(4, 16)  CONV2_NORM(4)
  CONV1(5, 1)   CONV2_NORM(5)  ATTN_BLOCK

  // distance head: PX -> fp32 logits in R3
  mfma_conv<64,4,1,4,false><<<dim3(6,LDIM), 256, CONV_SMEM(64,1,4), stream>>>(
      PX, WF + 442368, db, 63, R3, nullptr, 0, nullptr, nullptr);
  sym_kernel<<<dim3(96,LDIM), 256, 0, stream>>>(R3, PT, (float*)d_out);
  // confidence head: PT(64rec) -> PX(32rec, relu) -> R3
  mfma_conv<64,2,1,4,false><<<dim3(6,LDIM), 256, CONV_SMEM(64,1,4), stream>>>(
      PT, WF + 479232, cf1b, 32, nullptr, PX, 1, nullptr, nullptr);
  mfma_conv<32,2,1,4,false><<<dim3(6,LDIM), 256, CONV_SMEM(32,1,4), stream>>>(
      PX, WF + 497664, cf2b, 32, R3, nullptr, 1, nullptr, nullptr);
  conf_kernel<<<18432, 256, 0, stream>>>(R3, cf3w, cf3b, (float*)d_out + (size_t)NPIX*NBINS);
}

// Round 10
// 1418.540 us; speedup vs baseline: 1.2748x; 1.0297x over previous
//
#include <hip/hip_runtime.h>
#include <math.h>

#define LDIM 384
#define NPIX (LDIM*LDIM)
#define NBINS 63

typedef __attribute__((ext_vector_type(8))) __bf16 bf16x8;
typedef __attribute__((ext_vector_type(4))) float floatx4;

__device__ __forceinline__ float sigf(float x){ return 1.f/(1.f+expf(-x)); }
__device__ __forceinline__ float elu_neg(float v){ return __expf(v) - 1.f; }

// Prepped weight fragment layout (bf16): [tap][kc][nt][lane(64)][j(8)]
//   B-frag: n = nt*16 + (lane&15), k = kc*32 + (lane>>4)*8 + j
// WF arena offsets (bf16 units):
//   main conv slot s (0..11): s=2i conv1[i], s=2i+1 conv2[i], at s*36864
//   dist: 442368 ; cf1: 479232 ; cf2: 497664 ;
//   wg: 506880 (4096) ; wo: 510976 (2048) ; wq: 513024 (2048) ;
//   in_w hi: 515072 (4096) ; in_w lo: 519168 (4096) ; total 523264
__global__ __launch_bounds__(256) void prep_kernel(
    const float* __restrict__ c1w, const float* __restrict__ c2w,
    const float* __restrict__ dw, const float* __restrict__ cf1w,
    const float* __restrict__ cf2w, const float* __restrict__ wg,
    const float* __restrict__ wo, const float* __restrict__ wq,
    const float* __restrict__ inw, __bf16* __restrict__ Wf){
  int idx = blockIdx.x*256 + threadIdx.x;
  if (idx >= 523264) return;
  if (idx >= 515072){
    int rel = idx - 515072;
    int hi = (rel < 4096) ? 1 : 0;
    int r = rel & 4095;
    int j = r & 7, lane = (r>>3) & 63;
    int r2 = r >> 9;
    int nt = r2 & 3, kc = r2 >> 2;
    int k = kc*32 + (lane>>4)*8 + j;
    int n = nt*16 + (lane&15);
    float v = (k < 41) ? inw[(size_t)n*41 + k] : 0.f;
    __bf16 h = (__bf16)v;
    Wf[idx] = hi ? h : (__bf16)(v - (float)h);
    return;
  }
  if (idx >= 506880){
    int rel, NT, NDIM; const float* src;
    if (idx < 510976){ rel = idx - 506880; src = wg; NT=4; NDIM=64; }
    else if (idx < 513024){ rel = idx - 510976; src = wo; NT=4; NDIM=64; }
    else { rel = idx - 513024; src = wq; NT=2; NDIM=32; }
    int j = rel & 7, lane = (rel>>3) & 63;
    int r2 = rel >> 9;
    int nt = r2 % NT, kc = r2 / NT;
    int k = kc*32 + (lane>>4)*8 + j;
    int n = nt*16 + (lane&15);
    Wf[idx] = (__bf16)src[(size_t)k*NDIM + n];
    return;
  }
  const float* src; int ICreal, OCreal, ICP, NT, rel;
  if (idx < 442368){
    int layer = idx / 36864; rel = idx - layer*36864;
    int i = layer >> 1;
    src = (layer & 1) ? (c2w + (size_t)i*36864) : (c1w + (size_t)i*36864);
    ICreal=64; OCreal=64; ICP=64; NT=4;
  } else if (idx < 479232){
    rel = idx - 442368; src = dw;   ICreal=64; OCreal=63; ICP=64; NT=4;
  } else if (idx < 497664){
    rel = idx - 479232; src = cf1w; ICreal=63; OCreal=32; ICP=64; NT=2;
  } else {
    rel = idx - 497664; src = cf2w; ICreal=32; OCreal=32; ICP=32; NT=2;
  }
  int j = rel & 7, lane = (rel>>3) & 63;
  int r2 = rel >> 9;
  int nt = r2 % NT; int r3 = r2 / NT;
  int KC = ICP/32;
  int kc = r3 % KC; int tap = r3 / KC;
  int k = kc*32 + (lane>>4)*8 + j;
  int n = nt*16 + (lane&15);
  float v = 0.f;
  if (k < ICreal && n < OCreal) v = src[((size_t)n*ICreal + k)*9 + tap];
  Wf[idx] = (__bf16)v;
}

// ---------- MFMA implicit-GEMM 3x3 dilated conv, async LDS staging ----------
// ky-phase loop, 2 LDS row buffers. Staging via global_load_lds (width 16):
// coalesced 1KB/wave-instruction, no staging VGPRs, no ds_writes. Counted
// s_waitcnt vmcnt(N) + raw s_barrier keep the next row's loads in flight
// across barriers (guide T3/T4). XOR swizzle (both-sides, rule #21): LDS dest
// linear, global source chunk = sub^(px&7), read applies the same XOR ->
// 256B-stride record reads go from 16-way bank conflict to free 2-way.
#define VMCNT(N) asm volatile("s_waitcnt vmcnt(%0)" :: "n"(N) : "memory")
#define LGKM0()  asm volatile("s_waitcnt lgkmcnt(0)" ::: "memory")
#define BARS()   { __builtin_amdgcn_s_barrier(); __builtin_amdgcn_sched_barrier(0); }

template<int ICP, int NT, int D, int WAVES>
__global__ __launch_bounds__(WAVES*64) void mfma_conv(
    const __bf16* __restrict__ Ain, const __bf16* __restrict__ Wf,
    const float* __restrict__ bias, int OC_real,
    float* __restrict__ outF, __bf16* __restrict__ outP,
    int relu, float* __restrict__ ostats){
  constexpr int KC = ICP/32;
  constexpr int OCS = NT*16;
  constexpr int REC_B = ICP*4;          // bytes per px record (hi+lo)
  constexpr int PPX = REC_B/16;         // 16B chunks per record (16 or 8)
  constexpr int HALF = PPX/2;           // first lo chunk
  constexpr int W = WAVES*16;
  constexpr int T = WAVES*64;
  constexpr int SW = W + 2*D;
  constexpr int TOT1 = SW*PPX;          // chunks per staged row
  constexpr int NITER = (TOT1 + T - 1)/T;
  constexpr int BUFB = NITER*T*16;      // bytes per buffer (padded)
  extern __shared__ __align__(16) char smem[];
  char* buf0 = smem;
  char* buf1 = smem + BUFB;
  const int t = threadIdx.x;
  const int wave = t>>6, lane = t&63;
  const int q = lane>>4, col16 = lane&15;
  const int y = blockIdx.y;
  const int x0 = blockIdx.x*W;

  // per-thread staging slots (slot s = k*T + t; LDS byte = s*16)
  int srcoff[NITER];   // byte offset within row base (record + swizzled chunk)
  bool oob[NITER];     // x-OOB -> zero after landing
  #pragma unroll
  for (int k=0;k<NITER;k++){
    int s = k*T + t;
    int px = s / PPX;
    int sub = s % PPX;
    int cg = sub ^ (px & 7);            // inverse swizzle on source chunk
    int gx = x0 - D + px;
    oob[k] = (px < SW) && ((unsigned)gx >= LDIM);
    int gxc = min(max(gx,0), LDIM-1);
    srcoff[k] = gxc*REC_B + cg*16;
  }

  auto STAGE = [&](char* buf, int ky){
    int yr = y + (ky-1)*D;
    int yc = min(max(yr,0), LDIM-1);
    const char* rb = (const char*)Ain + (size_t)yc*LDIM*REC_B;
    #pragma unroll
    for (int k=0;k<NITER;k++){
      char* ldsb = buf + ((size_t)k*T + wave*64)*16;   // wave-uniform base
      const char* src = rb + srcoff[k];
      __builtin_amdgcn_global_load_lds(
          (const __attribute__((address_space(1))) void*)src,
          (__attribute__((address_space(3))) void*)ldsb, 16, 0, 0);
    }
  };
  auto ZOOB = [&](char* buf){
    #pragma unroll
    for (int k=0;k<NITER;k++)
      if (oob[k]){ uint4 z={0u,0u,0u,0u}; *(uint4*)(buf + ((size_t)k*T + t)*16) = z; }
  };

  floatx4 acc[NT];
  #pragma unroll
  for (int b=0;b<NT;b++){ floatx4 z = {0.f,0.f,0.f,0.f}; acc[b]=z; }

  auto MFMA_PHASE = [&](const char* buf, int ky){
    int yr = y + (ky-1)*D;
    if ((unsigned)yr >= LDIM) return;    // block-uniform
    #pragma unroll
    for (int kx=0;kx<3;kx++){
      int cl = wave*16 + col16 + kx*D;
      int e = cl & 7;
      bf16x8 wf[KC][NT];
      #pragma unroll
      for (int kc=0;kc<KC;kc++){
        const __bf16* wkc = Wf + (size_t)((ky*3+kx)*KC + kc)*NT*512 + lane*8;
        #pragma unroll
        for (int nt=0;nt<NT;nt++)
          wf[kc][nt] = *(const bf16x8*)(wkc + (size_t)nt*512);
      }
      #pragma unroll
      for (int kc=0;kc<KC;kc++){
        int sh = (kc*4+q) ^ e;
        int sl = (HALF + kc*4+q) ^ e;
        bf16x8 ah = *(const bf16x8*)(buf + (size_t)cl*REC_B + sh*16);
        bf16x8 al = *(const bf16x8*)(buf + (size_t)cl*REC_B + sl*16);
        #pragma unroll
        for (int nt=0;nt<NT;nt++){
          acc[nt] = __builtin_amdgcn_mfma_f32_16x16x32_bf16(ah, wf[kc][nt], acc[nt], 0,0,0);
          acc[nt] = __builtin_amdgcn_mfma_f32_16x16x32_bf16(al, wf[kc][nt], acc[nt], 0,0,0);
        }
      }
    }
  };

  // pipeline: rows 0,1 in flight; row 2 issued after row 0 consumed
  STAGE(buf0, 0);
  STAGE(buf1, 1);
  VMCNT(NITER);              // row 0 landed (row 1 may still fly)
  ZOOB(buf0); LGKM0();
  BARS();
  MFMA_PHASE(buf0, 0);
  BARS();                    // all waves done reading buf0
  STAGE(buf0, 2);
  VMCNT(NITER);              // row 1 landed (row 2 may still fly)
  ZOOB(buf1); LGKM0();
  BARS();
  MFMA_PHASE(buf1, 1);
  VMCNT(0);                  // row 2 landed
  ZOOB(buf0); LGKM0();
  BARS();
  MFMA_PHASE(buf0, 2);

  float sAcc[NT], sqAcc[NT];
  #pragma unroll
  for (int nt=0;nt<NT;nt++){ sAcc[nt]=0.f; sqAcc[nt]=0.f; }
  #pragma unroll
  for (int nt=0; nt<NT; nt++){
    int oc = nt*16 + col16;
    float bv = (oc < OC_real) ? bias[oc] : 0.f;
    int pxb = x0 + wave*16 + q*4;
    #pragma unroll
    for (int r=0; r<4; r++){
      float vv = acc[nt][r] + bv;
      if (relu) vv = fmaxf(vv, 0.f);
      size_t pix = (size_t)y*LDIM + pxb + r;
      if (outF) outF[pix*OCS + oc] = vv;
      if (outP){
        __bf16 h = (__bf16)vv;
        __bf16* rec = outP + pix*(size_t)(OCS*2);
        rec[oc] = h; rec[OCS+oc] = (__bf16)(vv - (float)h);
      }
      sAcc[nt] += vv; sqAcc[nt] += vv*vv;
    }
  }
  if (ostats){
    float* red = (float*)smem;
    __syncthreads();           // LDS buffers free for reuse
    #pragma unroll
    for (int nt=0; nt<NT; nt++){
      int oc = nt*16 + col16;
      float s = sAcc[nt], sq = sqAcc[nt];
      s  += __shfl_xor(s, 16);  s  += __shfl_xor(s, 32);
      sq += __shfl_xor(sq, 16); sq += __shfl_xor(sq, 32);
      if (q == 0){
        red[oc*WAVES + wave] = s;
        red[OCS*WAVES + oc*WAVES + wave] = sq;
      }
    }
    __syncthreads();
    float* oslot = ostats + ((blockIdx.y & 7) << 7);
    if (t < OCS){
      float s=0.f, sq=0.f;
      #pragma unroll
      for (int w=0; w<WAVES; w++){
        s  += red[t*WAVES + w];
        sq += red[OCS*WAVES + t*WAVES + w];
      }
      atomicAdd(&oslot[t], s);
      atomicAdd(&oslot[64+t], sq);
    }
  }
}

// -------- input 1x1 conv via MFMA: [147456 x 41] @ [41 x 64] --------
__global__ __launch_bounds__(256) void in_proj_mfma(
    const float* __restrict__ feat, const __bf16* __restrict__ WinF,
    const float* __restrict__ b, __bf16* __restrict__ PX){
  const int t=threadIdx.x, wave=t>>6, lane=t&63, q=lane>>4, col16=lane&15;
  const size_t p0=(size_t)blockIdx.x*128;
  floatx4 acc[2][4];
  #pragma unroll
  for (int a=0;a<2;a++)
    #pragma unroll
    for (int c=0;c<4;c++){ floatx4 z={0.f,0.f,0.f,0.f}; acc[a][c]=z; }
  #pragma unroll
  for (int kc=0;kc<2;kc++){
    bf16x8 ah[2], al[2];
    #pragma unroll
    for (int mt=0;mt<2;mt++){
      size_t row = p0 + wave*32 + mt*16 + col16;
      const float* fp = feat + row*41 + kc*32 + q*8;
      float v[8];
      #pragma unroll
      for (int j=0;j<8;j++){
        int k = kc*32 + q*8 + j;
        v[j] = (k < 41) ? fp[j] : 0.f;
      }
      #pragma unroll
      for (int j=0;j<8;j++){
        __bf16 h = (__bf16)v[j];
        ah[mt][j] = h; al[mt][j] = (__bf16)(v[j] - (float)h);
      }
    }
    #pragma unroll
    for (int nt=0;nt<4;nt++){
      bf16x8 bh = *(const bf16x8*)(WinF + (size_t)(kc*4+nt)*512 + lane*8);
      bf16x8 bl = *(const bf16x8*)(WinF + 4096 + (size_t)(kc*4+nt)*512 + lane*8);
      #pragma unroll
      for (int mt=0;mt<2;mt++){
        acc[mt][nt] = __builtin_amdgcn_mfma_f32_16x16x32_bf16(ah[mt], bh, acc[mt][nt], 0,0,0);
        acc[mt][nt] = __builtin_amdgcn_mfma_f32_16x16x32_bf16(al[mt], bh, acc[mt][nt], 0,0,0);
        acc[mt][nt] = __builtin_amdgcn_mfma_f32_16x16x32_bf16(ah[mt], bl, acc[mt][nt], 0,0,0);
      }
    }
  }
  #pragma unroll
  for (int mt=0;mt<2;mt++){
    size_t pxb = p0 + wave*32 + mt*16 + q*4;
    #pragma unroll
    for (int nt=0;nt<4;nt++){
      int oc = nt*16 + col16;
      float bv = b[oc];
      #pragma unroll
      for (int r=0;r<4;r++){
        float vv = acc[mt][nt][r] + bv;
        __bf16* rec = PX + (pxb+r)*128;
        __bf16 h = (__bf16)vv;
        rec[oc] = h; rec[64+oc] = (__bf16)(vv - (float)h);
      }
    }
  }
}

// norm(U records, 8-replica stats) -> ELU -> U in place (no residual)
__global__ __launch_bounds__(256) void norm_elu_planes(
    __bf16* __restrict__ U, const float* __restrict__ stats){
  size_t idx = (size_t)blockIdx.x*256 + threadIdx.x;
  size_t px = idx>>3; int c0 = (int)(idx&7)*8;
  __bf16* ur = U + px*128;
  uint4 uh = *(const uint4*)(ur + c0);
  uint4 ul = *(const uint4*)(ur + 64 + c0);
  __bf16* uhp=(__bf16*)&uh; __bf16* ulp=(__bf16*)&ul;
  float mu[8], rs[8];
  #pragma unroll
  for (int k=0;k<8;k++){
    int c = c0+k;
    float s=0.f, sq=0.f;
    #pragma unroll
    for (int rp=0;rp<8;rp++){ s += stats[rp*128 + c]; sq += stats[rp*128 + 64 + c]; }
    float m = s*(1.f/NPIX);
    mu[k]=m; rs[k]=rsqrtf(sq*(1.f/NPIX) - m*m + 1e-5f);
  }
  #pragma unroll
  for (int k=0;k<8;k++){
    float v = ((float)uhp[k] + (float)ulp[k] - mu[k])*rs[k];
    v = v>0.f ? v : elu_neg(v);
    __bf16 h = (__bf16)v; uhp[k]=h; ulp[k]=(__bf16)(v-(float)h);
  }
  *(uint4*)(ur + c0) = uh;
  *(uint4*)(ur + 64 + c0) = ul;
}

// norm(conv2raw U, 8-replica stats) + residual(PX) -> ELU -> PX (records)
__global__ __launch_bounds__(256) void norm_res_elu_planes(
    const __bf16* __restrict__ U, __bf16* __restrict__ PX,
    const float* __restrict__ stats){
  size_t idx = (size_t)blockIdx.x*256 + threadIdx.x;
  size_t px = idx>>3; int c0 = (int)(idx&7)*8;
  const __bf16* ur = U + px*128;
  __bf16* xr = PX + px*128;
  uint4 uh = *(const uint4*)(ur + c0);
  uint4 ul = *(const uint4*)(ur + 64 + c0);
  uint4 xh = *(uint4*)(xr + c0);
  uint4 xl = *(uint4*)(xr + 64 + c0);
  __bf16* uhp=(__bf16*)&uh; __bf16* ulp=(__bf16*)&ul;
  __bf16* xhp=(__bf16*)&xh; __bf16* xlp=(__bf16*)&xl;
  float mu[8], rs[8];
  #pragma unroll
  for (int k=0;k<8;k++){
    int c = c0+k;
    float s=0.f, sq=0.f;
    #pragma unroll
    for (int rp=0;rp<8;rp++){ s += stats[rp*128 + c]; sq += stats[rp*128 + 64 + c]; }
    float m = s*(1.f/NPIX);
    mu[k]=m; rs[k]=rsqrtf(sq*(1.f/NPIX) - m*m + 1e-5f);
  }
  #pragma unroll
  for (int k=0;k<8;k++){
    float v = ((float)uhp[k] + (float)ulp[k] - mu[k])*rs[k]
            + ((float)xhp[k] + (float)xlp[k]);
    v = v>0.f ? v : elu_neg(v);
    __bf16 h = (__bf16)v; xhp[k]=h; xlp[k]=(__bf16)(v-(float)h);
  }
  *(uint4*)(xr + c0) = xh;
  *(uint4*)(xr + 64 + c0) = xl;
}

// ---------------- attention ----------------
__global__ __launch_bounds__(256) void g_partial_kernel(
    const float* __restrict__ td, float* __restrict__ GC){
  size_t base = (size_t)blockIdx.x*256;
  float cnt = (td[base + threadIdx.x] > 0.f) ? 1.f : 0.f;
  __shared__ float red[256];
  red[threadIdx.x]=cnt; __syncthreads();
  for (int st=128; st; st>>=1){
    if (threadIdx.x<st) red[threadIdx.x]+=red[threadIdx.x+st];
    __syncthreads();
  }
  if (threadIdx.x==0) atomicAdd(GC, red[0]);
}

__global__ void g_final_kernel(
    const float* __restrict__ GC, const float* __restrict__ tq,
    const float* __restrict__ w1, const float* __restrict__ b1,
    const float* __restrict__ w2, const float* __restrict__ b2,
    float* __restrict__ G){
  if (threadIdx.x==0){
    float f0 = GC[0]*(1.f/NPIX), f1 = tq[0], f2 = (float)LDIM/512.f;
    float z = b2[0];
    for (int j=0;j<16;j++){
      float h = f0*w1[j] + f1*w1[16+j] + f2*w1[32+j] + b1[j];
      z += (h>0.f?h:0.f)*w2[j];
    }
    G[0] = sigf(z);
  }
}

// q = X @ wq via MFMA; writes Qb bf16 [i][j][32]
__global__ __launch_bounds__(256) void qproj_mfma_kernel(
    const __bf16* __restrict__ PX, const __bf16* __restrict__ WqF,
    __bf16* __restrict__ Qb){
  const int t=threadIdx.x, wave=t>>6, lane=t&63, q=lane>>4, col16=lane&15;
  const size_t p0=(size_t)blockIdx.x*128;
  __shared__ __bf16 Xhi[128*72];
  __shared__ __bf16 Xlo[128*72];
  uint4 sv[8];
  #pragma unroll
  for (int k=0;k<8;k++){
    int c=t+k*256;
    sv[k] = *(const uint4*)((const char*)PX + (p0 + (c>>4))*256 + (c&15)*16);
  }
  #pragma unroll
  for (int k=0;k<8;k++){
    int c=t+k*256; int px=c>>4, sub=c&15;
    *(uint4*)(((sub<8)?Xhi:Xlo) + px*72 + (sub&7)*8) = sv[k];
  }
  __syncthreads();
  floatx4 acc[2][2];
  #pragma unroll
  for (int a=0;a<2;a++)
    #pragma unroll
    for (int b=0;b<2;b++){ floatx4 z={0.f,0.f,0.f,0.f}; acc[a][b]=z; }
  #pragma unroll
  for (int kc=0;kc<2;kc++){
    bf16x8 ah[2], al[2];
    #pragma unroll
    for (int mt=0;mt<2;mt++){
      int row = wave*32 + mt*16 + col16;
      ah[mt] = *(const bf16x8*)(Xhi + row*72 + kc*32 + q*8);
      al[mt] = *(const bf16x8*)(Xlo + row*72 + kc*32 + q*8);
    }
    #pragma unroll
    for (int nt=0;nt<2;nt++){
      bf16x8 b = *(const bf16x8*)(WqF + (kc*2+nt)*512 + lane*8);
      acc[0][nt] = __builtin_amdgcn_mfma_f32_16x16x32_bf16(ah[0], b, acc[0][nt], 0,0,0);
      acc[1][nt] = __builtin_amdgcn_mfma_f32_16x16x32_bf16(ah[1], b, acc[1][nt], 0,0,0);
      acc[0][nt] = __builtin_amdgcn_mfma_f32_16x16x32_bf16(al[0], b, acc[0][nt], 0,0,0);
      acc[1][nt] = __builtin_amdgcn_mfma_f32_16x16x32_bf16(al[1], b, acc[1][nt], 0,0,0);
    }
  }
  #pragma unroll
  for (int mt=0;mt<2;mt++){
    size_t pxb = p0 + wave*32 + mt*16 + q*4;
    #pragma unroll
    for (int nt=0;nt<2;nt++){
      int oc = nt*16 + col16;
      #pragma unroll
      for (int r=0;r<4;r++)
        Qb[(pxb+r)*32 + oc] = (__bf16)acc[mt][nt][r];
    }
  }
}

// leftb bf16 [i][a][n]; vleftTb bf16 [i][n][a]
__global__ __launch_bounds__(256) void proj_left_kernel(
    const __bf16* __restrict__ PX, const float* __restrict__ wl, const float* __restrict__ wvl,
    __bf16* __restrict__ leftb, __bf16* __restrict__ vleftTb){
  int i = blockIdx.x;
  __shared__ float xa[32][65];
  __shared__ float w1s[2048], w2s[2048];
  int c = threadIdx.x & 63;
  for (int a = threadIdx.x>>6; a<32; a+=4){
    const __bf16* rec = PX + ((size_t)i*LDIM + 12*a)*128;
    xa[a][c] = (float)rec[c] + (float)rec[64+c];
  }
  for (int idx=threadIdx.x; idx<2048; idx+=256){ w1s[idx]=wl[idx]; w2s[idx]=wvl[idx]; }
  __syncthreads();
  #pragma unroll
  for (int k=0;k<4;k++){
    int idx = threadIdx.x + k*256;
    int a = idx>>5, n = idx&31;
    float a1=0.f, a2=0.f;
    #pragma unroll
    for (int cc=0;cc<64;cc++){ float v=xa[a][cc]; a1+=v*w1s[cc*32+n]; a2+=v*w2s[cc*32+n]; }
    leftb  [(size_t)i*1024 + a*32 + n] = (__bf16)a1;
    vleftTb[(size_t)i*1024 + n*32 + a] = (__bf16)a2;
  }
}

// grid (12, 32): j0 = bx*32, a = by ; rightb [j][a][n] ; vrightTb [j][n][a]
__global__ __launch_bounds__(256) void proj_right_kernel(
    const __bf16* __restrict__ PX, const float* __restrict__ wr, const float* __restrict__ wvr,
    __bf16* __restrict__ rightb, __bf16* __restrict__ vrightTb){
  int a = blockIdx.y; int row = 12*a;
  int j0 = blockIdx.x*32;
  __shared__ float xr[32][65];
  __shared__ float w1s[2048], w2s[2048];
  for (int idx=threadIdx.x; idx<2048; idx+=256){ w1s[idx]=wr[idx]; w2s[idx]=wvr[idx]; }
  int c = threadIdx.x & 63;
  for (int jl = threadIdx.x>>6; jl<32; jl+=4){
    const __bf16* rec = PX + ((size_t)row*LDIM + j0 + jl)*128;
    xr[jl][c] = (float)rec[c] + (float)rec[64+c];
  }
  __syncthreads();
  #pragma unroll
  for (int k=0;k<4;k++){
    int idx=threadIdx.x+k*256; int jl=idx>>5, n=idx&31;
    float a1=0.f, a2=0.f;
    #pragma unroll
    for (int cc=0;cc<64;cc++){ float v=xr[jl][cc]; a1+=v*w1s[cc*32+n]; a2+=v*w2s[cc*32+n]; }
    rightb  [(size_t)(j0+jl)*1024 + a*32 + n] = (__bf16)a1;
    vrightTb[(size_t)(j0+jl)*1024 + n*32 + a] = (__bf16)a2;
  }
}

// S1: per-i GEMM  S[i,j,a] = Q[i,j,:] . left[i,a,:]
__global__ __launch_bounds__(256) void attn_s1_kernel(
    const __bf16* __restrict__ Qb, const __bf16* __restrict__ leftb,
    float* __restrict__ S){
  const int t=threadIdx.x, wave=t>>6, lane=t&63, q=lane>>4, col16=lane&15;
  const int i = blockIdx.y, j0 = blockIdx.x*128;
  bf16x8 bfrag[2];
  #pragma unroll
  for (int nt=0;nt<2;nt++)
    bfrag[nt] = *(const bf16x8*)(leftb + (size_t)i*1024 + (nt*16+col16)*32 + q*8);
  bf16x8 ah[2];
  #pragma unroll
  for (int mt=0;mt<2;mt++){
    int row = j0 + wave*32 + mt*16 + col16;
    ah[mt] = *(const bf16x8*)(Qb + ((size_t)i*LDIM + row)*32 + q*8);
  }
  floatx4 acc[2][2];
  #pragma unroll
  for (int a=0;a<2;a++)
    #pragma unroll
    for (int b=0;b<2;b++){ floatx4 z={0.f,0.f,0.f,0.f}; acc[a][b]=z; }
  #pragma unroll
  for (int mt=0;mt<2;mt++)
    #pragma unroll
    for (int nt=0;nt<2;nt++)
      acc[mt][nt] = __builtin_amdgcn_mfma_f32_16x16x32_bf16(ah[mt], bfrag[nt], acc[mt][nt], 0,0,0);
  #pragma unroll
  for (int mt=0;mt<2;mt++){
    int jb = j0 + wave*32 + mt*16 + q*4;
    #pragma unroll
    for (int nt=0;nt<2;nt++){
      int a = nt*16 + col16;
      #pragma unroll
      for (int r=0;r<4;r++)
        S[((size_t)i*LDIM + jb + r)*32 + a] = acc[mt][nt][r];
    }
  }
}

// S2: per-j GEMM  S[i,j,a] += Q[i,j,:] . right[j,a,:]
__global__ __launch_bounds__(256) void attn_s2_kernel(
    const __bf16* __restrict__ Qb, const __bf16* __restrict__ rightb,
    float* __restrict__ S){
  const int t=threadIdx.x, wave=t>>6, lane=t&63, q=lane>>4, col16=lane&15;
  const int j = blockIdx.y, i0 = blockIdx.x*128;
  bf16x8 bfrag[2];
  #pragma unroll
  for (int nt=0;nt<2;nt++)
    bfrag[nt] = *(const bf16x8*)(rightb + (size_t)j*1024 + (nt*16+col16)*32 + q*8);
  bf16x8 ah[2];
  #pragma unroll
  for (int mt=0;mt<2;mt++){
    int row = i0 + wave*32 + mt*16 + col16;
    ah[mt] = *(const bf16x8*)(Qb + ((size_t)row*LDIM + j)*32 + q*8);
  }
  floatx4 acc[2][2];
  #pragma unroll
  for (int a=0;a<2;a++)
    #pragma unroll
    for (int b=0;b<2;b++){ floatx4 z={0.f,0.f,0.f,0.f}; acc[a][b]=z; }
  #pragma unroll
  for (int mt=0;mt<2;mt++)
    #pragma unroll
    for (int nt=0;nt<2;nt++)
      acc[mt][nt] = __builtin_amdgcn_mfma_f32_16x16x32_bf16(ah[mt], bfrag[nt], acc[mt][nt], 0,0,0);
  #pragma unroll
  for (int mt=0;mt<2;mt++){
    int ib = i0 + wave*32 + mt*16 + q*4;
    #pragma unroll
    for (int nt=0;nt<2;nt++){
      int a = nt*16 + col16;
      #pragma unroll
      for (int r=0;r<4;r++){
        size_t idx = ((size_t)(ib+r)*LDIM + j)*32 + a;
        S[idx] += acc[mt][nt][r];
      }
    }
  }
}

// softmax(S*scale + g*bias) -> attnb/attnTb
__global__ __launch_bounds__(128) void attn_soft_kernel(
    const float* __restrict__ S, const float* __restrict__ td,
    const float* __restrict__ gp, __bf16* __restrict__ attnb,
    __bf16* __restrict__ attnTb){
  int i = blockIdx.y;
  int j0 = blockIdx.x*128;
  int t = threadIdx.x;
  int j = j0 + t;
  __shared__ float tl[32];
  __shared__ float trS[32*128];
  {
    #pragma unroll
    for (int v=0; v<8; v++){
      int f = t + v*128;
      int a = f>>5, jl4 = (f&31)*4;
      *(floatx4*)(trS + a*128 + jl4) = *(const floatx4*)(td + (size_t)(12*a)*LDIM + j0 + jl4);
    }
    if (t<32) tl[t] = td[(size_t)i*LDIM + 12*t];
  }
  __syncthreads();
  float g = gp[0];
  float tdij = td[(size_t)i*LDIM+j];
  float s[32];
  const floatx4* sp4 = (const floatx4*)(S + ((size_t)i*LDIM+j)*32);
  #pragma unroll
  for (int v=0;v<8;v++){
    floatx4 sv = sp4[v];
    #pragma unroll
    for (int e=0;e<4;e++) s[v*4+e] = sv[e];
  }
  float m = -1e30f;
  #pragma unroll
  for (int a=0;a<32;a++){
    float acc = s[a]*0.17677669529663687f;
    float bias = -fabsf(tl[a] + trS[a*128 + t] - tdij) * (1.0f/12.0f);
    acc += g*bias;
    s[a]=acc;
    m = fmaxf(m, acc);
  }
  float sum=0.f;
  #pragma unroll
  for (int a=0;a<32;a++){ s[a]=expf(s[a]-m); sum+=s[a]; }
  float inv = 1.f/sum;
  bf16x8 pk[4];
  #pragma unroll
  for (int v=0;v<4;v++){
    #pragma unroll
    for (int e=0;e<8;e++) pk[v][e] = (__bf16)(s[v*8+e]*inv);
  }
  bf16x8* op = (bf16x8*)(attnb + ((size_t)i*LDIM+j)*32);
  bf16x8* opT = (bf16x8*)(attnTb + ((size_t)j*LDIM+i)*32);
  #pragma unroll
  for (int v=0;v<4;v++){ op[v]=pk[v]; opT[v]=pk[v]; }
}

// U1: per-i GEMM  UPD[i,j,c] = attn[i,j,:] . vleftT[i,c,:]
__global__ __launch_bounds__(256) void attn_u1_kernel(
    const __bf16* __restrict__ attnb, const __bf16* __restrict__ vleftTb,
    float* __restrict__ UPD){
  const int t=threadIdx.x, wave=t>>6, lane=t&63, q=lane>>4, col16=lane&15;
  const int i = blockIdx.y, j0 = blockIdx.x*128;
  bf16x8 bfrag[2];
  #pragma unroll
  for (int nt=0;nt<2;nt++)
    bfrag[nt] = *(const bf16x8*)(vleftTb + (size_t)i*1024 + (nt*16+col16)*32 + q*8);
  bf16x8 ah[2];
  #pragma unroll
  for (int mt=0;mt<2;mt++){
    int row = j0 + wave*32 + mt*16 + col16;
    ah[mt] = *(const bf16x8*)(attnb + ((size_t)i*LDIM + row)*32 + q*8);
  }
  floatx4 acc[2][2];
  #pragma unroll
  for (int a=0;a<2;a++)
    #pragma unroll
    for (int b=0;b<2;b++){ floatx4 z={0.f,0.f,0.f,0.f}; acc[a][b]=z; }
  #pragma unroll
  for (int mt=0;mt<2;mt++)
    #pragma unroll
    for (int nt=0;nt<2;nt++)
      acc[mt][nt] = __builtin_amdgcn_mfma_f32_16x16x32_bf16(ah[mt], bfrag[nt], acc[mt][nt], 0,0,0);
  #pragma unroll
  for (int mt=0;mt<2;mt++){
    int jb = j0 + wave*32 + mt*16 + q*4;
    #pragma unroll
    for (int nt=0;nt<2;nt++){
      int c = nt*16 + col16;
      #pragma unroll
      for (int r=0;r<4;r++)
        UPD[((size_t)i*LDIM + jb + r)*32 + c] = acc[mt][nt][r];
    }
  }
}

// U2: per-j GEMM  UPD[i,j,c] += attnT[j,i,:] . vrightT[j,c,:]
__global__ __launch_bounds__(256) void attn_u2_kernel(
    const __bf16* __restrict__ attnTb, const __bf16* __restrict__ vrightTb,
    float* __restrict__ UPD){
  const int t=threadIdx.x, wave=t>>6, lane=t&63, q=lane>>4, col16=lane&15;
  const int j = blockIdx.y, i0 = blockIdx.x*128;
  bf16x8 bfrag[2];
  #pragma unroll
  for (int nt=0;nt<2;nt++)
    bfrag[nt] = *(const bf16x8*)(vrightTb + (size_t)j*1024 + (nt*16+col16)*32 + q*8);
  bf16x8 ah[2];
  #pragma unroll
  for (int mt=0;mt<2;mt++){
    int row = i0 + wave*32 + mt*16 + col16;
    ah[mt] = *(const bf16x8*)(attnTb + ((size_t)j*LDIM + row)*32 + q*8);
  }
  floatx4 acc[2][2];
  #pragma unroll
  for (int a=0;a<2;a++)
    #pragma unroll
    for (int b=0;b<2;b++){ floatx4 z={0.f,0.f,0.f,0.f}; acc[a][b]=z; }
  #pragma unroll
  for (int mt=0;mt<2;mt++)
    #pragma unroll
    for (int nt=0;nt<2;nt++)
      acc[mt][nt] = __builtin_amdgcn_mfma_f32_16x16x32_bf16(ah[mt], bfrag[nt], acc[mt][nt], 0,0,0);
  #pragma unroll
  for (int mt=0;mt<2;mt++){
    int ib = i0 + wave*32 + mt*16 + q*4;
    #pragma unroll
    for (int nt=0;nt<2;nt++){
      int c = nt*16 + col16;
      #pragma unroll
      for (int r=0;r<4;r++){
        size_t idx = ((size_t)(ib+r)*LDIM + j)*32 + c;
        UPD[idx] += acc[mt][nt][r];
      }
    }
  }
}

// PX += sigmoid(X@Wg+bg) * (UPD@Wo), in-place on records, via MFMA
__global__ __launch_bounds__(256) void gate_mfma_kernel(
    __bf16* __restrict__ PX, const float* __restrict__ UPD,
    const __bf16* __restrict__ WgF, const __bf16* __restrict__ WoF,
    const float* __restrict__ bg){
  const int t=threadIdx.x, wave=t>>6, lane=t&63, q=lane>>4, col16=lane&15;
  const size_t p0=(size_t)blockIdx.x*128;
  __shared__ __bf16 Xhi[128*72];
  __shared__ __bf16 Xlo[128*72];
  __shared__ __bf16 Ub[128*40];
  uint4 sv[8];
  #pragma unroll
  for (int k=0;k<8;k++){
    int c=t+k*256;
    sv[k] = *(const uint4*)((const char*)PX + (p0 + (c>>4))*256 + (c&15)*16);
  }
  floatx4 uv[4];
  #pragma unroll
  for (int k=0;k<4;k++){
    int p = (t>>3) + k*32;
    uv[k] = *(const floatx4*)(UPD + (p0+p)*32 + (t&7)*4);
  }
  #pragma unroll
  for (int k=0;k<8;k++){
    int c=t+k*256; int px=c>>4, sub=c&15;
    *(uint4*)(((sub<8)?Xhi:Xlo) + px*72 + (sub&7)*8) = sv[k];
  }
  #pragma unroll
  for (int k=0;k<4;k++){
    int p = (t>>3) + k*32;
    __bf16* pu = Ub + p*40 + (t&7)*4;
    #pragma unroll
    for (int kk=0;kk<4;kk++) pu[kk]=(__bf16)uv[k][kk];
  }
  __syncthreads();
  floatx4 accg[2][4], accu[2][4];
  #pragma unroll
  for (int a=0;a<2;a++)
    #pragma unroll
    for (int b=0;b<4;b++){ floatx4 z={0.f,0.f,0.f,0.f}; accg[a][b]=z; accu[a][b]=z; }
  #pragma unroll
  for (int kc=0;kc<2;kc++){
    bf16x8 ah[2], al[2];
    #pragma unroll
    for (int mt=0;mt<2;mt++){
      int row = wave*32 + mt*16 + col16;
      ah[mt] = *(const bf16x8*)(Xhi + row*72 + kc*32 + q*8);
      al[mt] = *(const bf16x8*)(Xlo + row*72 + kc*32 + q*8);
    }
    #pragma unroll
    for (int nt=0;nt<4;nt++){
      bf16x8 b = *(const bf16x8*)(WgF + (kc*4+nt)*512 + lane*8);
      accg[0][nt] = __builtin_amdgcn_mfma_f32_16x16x32_bf16(ah[0], b, accg[0][nt], 0,0,0);
      accg[1][nt] = __builtin_amdgcn_mfma_f32_16x16x32_bf16(ah[1], b, accg[1][nt], 0,0,0);
      accg[0][nt] = __builtin_amdgcn_mfma_f32_16x16x32_bf16(al[0], b, accg[0][nt], 0,0,0);
      accg[1][nt] = __builtin_amdgcn_mfma_f32_16x16x32_bf16(al[1], b, accg[1][nt], 0,0,0);
    }
  }
  {
    bf16x8 au[2];
    #pragma unroll
    for (int mt=0;mt<2;mt++){
      int row = wave*32 + mt*16 + col16;
      au[mt] = *(const bf16x8*)(Ub + row*40 + q*8);
    }
    #pragma unroll
    for (int nt=0;nt<4;nt++){
      bf16x8 b = *(const bf16x8*)(WoF + nt*512 + lane*8);
      accu[0][nt] = __builtin_amdgcn_mfma_f32_16x16x32_bf16(au[0], b, accu[0][nt], 0,0,0);
      accu[1][nt] = __builtin_amdgcn_mfma_f32_16x16x32_bf16(au[1], b, accu[1][nt], 0,0,0);
    }
  }
  #pragma unroll
  for (int mt=0;mt<2;mt++){
    size_t pxb = p0 + wave*32 + mt*16 + q*4;
    #pragma unroll
    for (int nt=0;nt<4;nt++){
      int oc = nt*16 + col16;
      float bgv = bg[oc];
      #pragma unroll
      for (int r=0;r<4;r++){
        __bf16* rec = PX + (pxb+r)*128;
        float xv = (float)rec[oc] + (float)rec[64+oc];
        float g = sigf(accg[mt][nt][r] + bgv);
        float xn = xv + g*accu[mt][nt][r];
        __bf16 h = (__bf16)xn;
        rec[oc] = h; rec[64+oc] = (__bf16)(xn - (float)h);
      }
    }
  }
}

// ---------------- heads ----------------
__global__ __launch_bounds__(256) void sym_kernel(
    const float* __restrict__ lg, __bf16* __restrict__ PS, float* __restrict__ dout){
  int i = blockIdx.y;
  int j = blockIdx.x*4 + (threadIdx.x>>6);
  int o = threadIdx.x & 63;
  float v = 0.5f*(lg[((size_t)i*LDIM+j)*64+o] + lg[((size_t)j*LDIM+i)*64+o]);
  size_t pix = (size_t)i*LDIM+j;
  __bf16 h = (__bf16)v;
  __bf16* rec = PS + pix*128;
  rec[o] = h; rec[64+o] = (__bf16)(v - (float)h);
  if (o<63) dout[pix*63+o] = v;
}

__global__ __launch_bounds__(256) void conf_kernel(
    const float* __restrict__ c2, const float* __restrict__ w,
    const float* __restrict__ b, float* __restrict__ out){
  int t = threadIdx.x;
  size_t pix = (size_t)blockIdx.x*8 + (t>>5);
  int c = t&31;
  float v = c2[pix*32 + c]*w[c];
  #pragma unroll
  for (int off=16; off; off>>=1) v += __shfl_xor(v, off);
  if (c==0) out[pix] = sigf(v + b[0]);
}

extern "C" void kernel_launch(void* const* d_in, const int* in_sizes, int n_in,
                              void* d_out, int out_size, void* d_ws, size_t ws_size,
                              hipStream_t stream){
  const float* feat = (const float*)d_in[0];
  const float* td   = (const float*)d_in[1];
  const float* tq   = (const float*)d_in[2];
  const float* in_w = (const float*)d_in[3];
  const float* in_b = (const float*)d_in[4];
  const float* c1w  = (const float*)d_in[5];
  const float* c1b  = (const float*)d_in[6];
  const float* c2w  = (const float*)d_in[7];
  const float* c2b  = (const float*)d_in[8];
  const float* wq   = (const float*)d_in[9];
  const float* wl   = (const float*)d_in[10];
  const float* wr   = (const float*)d_in[11];
  const float* wvl  = (const float*)d_in[12];
  const float* wvr  = (const float*)d_in[13];
  const float* wo   = (const float*)d_in[14];
  const float* wg   = (const float*)d_in[15];
  const float* bg   = (const float*)d_in[16];
  const float* tgw1 = (const float*)d_in[17];
  const float* tgb1 = (const float*)d_in[18];
  const float* tgw2 = (const float*)d_in[19];
  const float* tgb2 = (const float*)d_in[20];
  const float* dw   = (const float*)d_in[21];
  const float* db   = (const float*)d_in[22];
  const float* cf1w = (const float*)d_in[23];
  const float* cf1b = (const float*)d_in[24];
  const float* cf2w = (const float*)d_in[25];
  const float* cf2b = (const float*)d_in[26];
  const float* cf3w = (const float*)d_in[27];
  const float* cf3b = (const float*)d_in[28];

  float* ws = (float*)d_ws;
  const size_t BUF = (size_t)64*NPIX;
  float* R1 = ws;
  float* R2 = ws + BUF;
  float* R3 = ws + 2*BUF;
  float* STATS = ws + 3*BUF;             // 12 slots x 8 replicas x 128
  float* G     = STATS + 12288;
  float* GC    = G + 1;
  __bf16* WF   = (__bf16*)(G + 16);
  __bf16* WGF  = WF + 506880;
  __bf16* WOF  = WF + 510976;
  __bf16* WQF  = WF + 513024;
  __bf16* WINF = WF + 515072;

  __bf16* PX = (__bf16*)R1;
  __bf16* PT = (__bf16*)R2;
  __bf16* PU = (__bf16*)R3;
  // attention buffers (R2/R3 free during attention)
  char* R2c = (char*)R2;
  __bf16* Qb       = (__bf16*)R2c;                  // 9,437,184 B
  __bf16* ATTNB    = (__bf16*)(R2c +  9437184);     // 9,437,184 B
  __bf16* ATTNTB   = (__bf16*)(R2c + 18874368);     // 9,437,184 B
  __bf16* LEFTB    = (__bf16*)(R2c + 28311552);     //   786,432 B
  __bf16* RIGHTB   = (__bf16*)(R2c + 29097984);
  __bf16* VLEFTTB  = (__bf16*)(R2c + 29884416);
  __bf16* VRIGHTTB = (__bf16*)(R2c + 30670848);
  float* S   = R3;                                  // 18.9 MB
  float* UPD = R3 + (size_t)32*NPIX;                // 18.9 MB

  hipMemsetAsync(STATS, 0, (12288 + 16)*sizeof(float), stream);
  prep_kernel<<<2044, 256, 0, stream>>>(c1w, c2w, dw, cf1w, cf2w, wg, wo, wq, in_w, WF);
  g_partial_kernel<<<576, 256, 0, stream>>>(td, GC);
  g_final_kernel<<<1, 64, 0, stream>>>(GC, tq, tgw1, tgb1, tgw2, tgb2, G);

  in_proj_mfma<<<1152, 256, 0, stream>>>(feat, WINF, in_b, PX);

  // dynamic LDS: 2 row buffers of NITER*T*16 bytes
#define CONV_SMEM(ICP_, DD, WW) \
  (2 * (((((WW)*16+2*(DD))*((ICP_)/4)) + ((WW)*64) - 1)/((WW)*64)) * ((WW)*64) * 16)

#define CONV2_NORM(i) \
  norm_elu_planes<<<4608, 256, 0, stream>>>(PT, STATS + (2*(i))*1024); \
  mfma_conv<64,4,1,4><<<dim3(6,LDIM), 256, CONV_SMEM(64,1,4), stream>>>( \
      PT, WF + (size_t)(2*(i)+1)*36864, c2b + (i)*64, 64, \
      nullptr, PU, 0, STATS + (2*(i)+1)*1024); \
  norm_res_elu_planes<<<4608, 256, 0, stream>>>(PU, PX, STATS + (2*(i)+1)*1024);

#define CONV1(i, DD) \
  mfma_conv<64,4,DD,4><<<dim3(6,LDIM), 256, CONV_SMEM(64,DD,4), stream>>>( \
      PX, WF + (size_t)(2*(i))*36864, c1b + (i)*64, 64, \
      nullptr, PT, 0, STATS + (2*(i))*1024);

#define ATTN_BLOCK \
  qproj_mfma_kernel<<<1152, 256, 0, stream>>>(PX, WQF, Qb); \
  proj_left_kernel<<<384, 256, 0, stream>>>(PX, wl, wvl, LEFTB, VLEFTTB); \
  proj_right_kernel<<<dim3(12,32), 256, 0, stream>>>(PX, wr, wvr, RIGHTB, VRIGHTTB); \
  attn_s1_kernel<<<dim3(3,LDIM), 256, 0, stream>>>(Qb, LEFTB, S); \
  attn_s2_kernel<<<dim3(3,LDIM), 256, 0, stream>>>(Qb, RIGHTB, S); \
  attn_soft_kernel<<<dim3(3,LDIM), 128, 0, stream>>>(S, td, G, ATTNB, ATTNTB); \
  attn_u1_kernel<<<dim3(3,LDIM), 256, 0, stream>>>(ATTNB, VLEFTTB, UPD); \
  attn_u2_kernel<<<dim3(3,LDIM), 256, 0, stream>>>(ATTNTB, VRIGHTTB, UPD); \
  gate_mfma_kernel<<<1152, 256, 0, stream>>>(PX, UPD, WGF, WOF, bg);

  CONV1(0, 1)   CONV2_NORM(0)
  CONV1(1, 2)   CONV2_NORM(1)  ATTN_BLOCK
  CONV1(2, 4)   CONV2_NORM(2)
  CONV1(3, 8)   CONV2_NORM(3)  ATTN_BLOCK
  CONV1(4, 16)  CONV2_NORM(4)
  CONV1(5, 1)   CONV2_NORM(5)  ATTN_BLOCK

  // distance head: PX -> fp32 logits in R3
  mfma_conv<64,4,1,4><<<dim3(6,LDIM), 256, CONV_SMEM(64,1,4), stream>>>(
      PX, WF + 442368, db, 63, R3, nullptr, 0, nullptr);
  sym_kernel<<<dim3(96,LDIM), 256, 0, stream>>>(R3, PT, (float*)d_out);
  // confidence head: PT(64rec) -> PX(32rec, relu) -> R3
  mfma_conv<64,2,1,4><<<dim3(6,LDIM), 256, CONV_SMEM(64,1,4), stream>>>(
      PT, WF + 479232, cf1b, 32, nullptr, PX, 1, nullptr);
  mfma_conv<32,2,1,4><<<dim3(6,LDIM), 256, CONV_SMEM(32,1,4), stream>>>(
      PX, WF + 497664, cf2b, 32, R3, nullptr, 1, nullptr);
  conf_kernel<<<18432, 256, 0, stream>>>(R3, cf3w, cf3b, (float*)d_out + (size_t)NPIX*NBINS);
}